// Round 2
// baseline (9204.203 us; speedup 1.0000x reference)
//
#include <hip/hip_runtime.h>
#include <hip/hip_bf16.h>
#include <math.h>

#define S_LEN 64
#define T_LEN 32
#define BATCH 512
#define IN_DIM 66
#define INP 128         // IN_DIM zero-padded to multiple of 64
#define H_DIM 1024
#define O_DIM 1024
#define H3 3072
#define NB 256          // persistent grid size (= CU count / LDS-limited 1 block/CU)

typedef __attribute__((ext_vector_type(8))) short short8;
typedef __attribute__((ext_vector_type(4))) float f32x4;
typedef __attribute__((ext_vector_type(4))) unsigned short us4;

__device__ __forceinline__ unsigned short f2b(float f) {
    union { float f; unsigned u; } x; x.f = f;
    unsigned r = x.u + 0x7FFF + ((x.u >> 16) & 1);
    return (unsigned short)(r >> 16);
}
__device__ __forceinline__ float b2f(unsigned short s) {
    union { unsigned u; float f; } x; x.u = ((unsigned)s) << 16;
    return x.f;
}
// async global->LDS, 16B per lane; lds base must be wave-uniform
__device__ __forceinline__ void gll16(const void* g, const void* l) {
    __builtin_amdgcn_global_load_lds(
        (const __attribute__((address_space(1))) unsigned int*)g,
        (__attribute__((address_space(3))) unsigned int*)l, 16, 0, 0);
}

// ---- device-scope grid barrier pieces (all blocks co-resident by design) ----
__device__ __forceinline__ void gbar_arrive(unsigned* bar) {
    // call AFTER __syncthreads(); tid0 only
    __threadfence();   // flush epilogue stores to coherence point
    __hip_atomic_fetch_add(bar, 1u, __ATOMIC_RELEASE, __HIP_MEMORY_SCOPE_AGENT);
}
__device__ __forceinline__ void gbar_wait(unsigned* bar, unsigned target) {
    while (__hip_atomic_load(bar, __ATOMIC_RELAXED, __HIP_MEMORY_SCOPE_AGENT) < target)
        __builtin_amdgcn_s_sleep(1);
    __threadfence();   // acquire: invalidate caches before reading peers' data
}
__device__ __forceinline__ void gsync(unsigned* bar, unsigned target) {
    __syncthreads();
    if (threadIdx.x == 0) {
        gbar_arrive(bar);
        gbar_wait(bar, target);
    }
    __syncthreads();
}

// ---------------------------------------------------------------------------
// MFMA GEMM, bf16: C[M,N] = A@W^T, tile TM x TN. lda/ldw mult of 8, K mult 32.
// Double-buffered: stage tile t+1 while computing tile t, ONE barrier/tile.
// flags: 1 bias, 2 add fp32, 4 add bf16, 8 relu, 16 store f32, 32 store bf16
// ---------------------------------------------------------------------------
template<int TM, int TN>
__global__ __launch_bounds__(256) void gemm_k(
    const unsigned short* __restrict__ A, int lda,
    const unsigned short* __restrict__ W, int ldw,
    const float* __restrict__ bias,
    const float* __restrict__ addf, const unsigned short* __restrict__ addb,
    int ldadd,
    float* __restrict__ Cf,
    unsigned short* __restrict__ Cb, int ldc,
    int K, int flags)
{
    constexpr int IF = TM / 16;   // A frags per wave
    constexpr int JF = TN / 64;   // B frags per wave
    constexpr int NW = TN / 4;    // cols per wave
    constexpr int CA = TM * 4;    // 16B chunks in A tile
    constexpr int CW = TN * 4;
    __shared__ __align__(16) unsigned short As[2][TM * 32];
    __shared__ __align__(16) unsigned short Bs[2][TN * 32];

    const int bm = blockIdx.y * TM;
    const int bn = blockIdx.x * TN;
    const int t = threadIdx.x;
    const int lane = t & 63;
    const int wv = t >> 6;
    const int ln = lane & 15;
    const int quad = lane >> 4;

    f32x4 acc[IF][JF];
    #pragma unroll
    for (int i = 0; i < IF; i++)
        #pragma unroll
        for (int j = 0; j < JF; j++) {
            f32x4 z = {0.f, 0.f, 0.f, 0.f};
            acc[i][j] = z;
        }

    auto stage = [&](int buf, int k0) {
        if constexpr (CA >= 256) {
            #pragma unroll
            for (int j = 0; j < CA / 256; j++) {
                int ch = j * 256 + t;
                gll16(A + (size_t)(bm + (ch >> 2)) * lda + k0 + (ch & 3) * 8,
                      (const char*)As[buf] + (j * 4 + wv) * 1024);
            }
        } else {
            if (t < CA)
                gll16(A + (size_t)(bm + (t >> 2)) * lda + k0 + (t & 3) * 8,
                      (const char*)As[buf] + wv * 1024);
        }
        if constexpr (CW >= 256) {
            #pragma unroll
            for (int j = 0; j < CW / 256; j++) {
                int ch = j * 256 + t;
                gll16(W + (size_t)(bn + (ch >> 2)) * ldw + k0 + (ch & 3) * 8,
                      (const char*)Bs[buf] + (j * 4 + wv) * 1024);
            }
        } else {
            if (t < CW)
                gll16(W + (size_t)(bn + (t >> 2)) * ldw + k0 + (t & 3) * 8,
                      (const char*)Bs[buf] + wv * 1024);
        }
    };

    const int nt = K >> 5;
    stage(0, 0);
    __syncthreads();
    for (int i = 0; i < nt; ++i) {
        const int cur = i & 1;
        if (i + 1 < nt) stage(cur ^ 1, (i + 1) << 5);
        short8 af[IF], bf[JF];
        #pragma unroll
        for (int ii = 0; ii < IF; ii++)
            af[ii] = *(const short8*)&As[cur][(ii * 16 + ln) * 32 + quad * 8];
        #pragma unroll
        for (int j = 0; j < JF; j++)
            bf[j] = *(const short8*)&Bs[cur][(wv * NW + j * 16 + ln) * 32 + quad * 8];
        #pragma unroll
        for (int ii = 0; ii < IF; ii++)
            #pragma unroll
            for (int j = 0; j < JF; j++)
                acc[ii][j] = __builtin_amdgcn_mfma_f32_16x16x32_bf16(
                    af[ii], bf[j], acc[ii][j], 0, 0, 0);
        __syncthreads();   // drains next-tile loads; guards buffer reuse
    }

    #pragma unroll
    for (int i = 0; i < IF; i++) {
        #pragma unroll
        for (int j = 0; j < JF; j++) {
            #pragma unroll
            for (int r = 0; r < 4; r++) {
                int m = bm + i * 16 + quad * 4 + r;
                int n = bn + wv * NW + j * 16 + ln;
                float v = acc[i][j][r];
                if (flags & 1) v += bias[n];
                if (flags & 2) v += addf[(size_t)m * ldadd + n];
                if (flags & 4) v += b2f(addb[(size_t)m * ldadd + n]);
                if (flags & 8) v = fmaxf(v, 0.f);
                if (flags & 16) Cf[(size_t)m * ldc + n] = v;
                if (flags & 32) Cb[(size_t)m * ldc + n] = f2b(v);
            }
        }
    }
}

// ---------------------------------------------------------------------------
// Tile stage/compute helpers for the 32x64, 512-thread, 2-group K-split GEMM.
// Per buffer: As_g 2*32*32 shorts (4 KB), Ws_g NG*2*64*32 shorts.
// ---------------------------------------------------------------------------
__device__ __forceinline__ void stage3(
    const unsigned short* __restrict__ A, int lda,
    const unsigned short* __restrict__ W, int ldw, int kb,
    unsigned short* As_g, unsigned short* Ws_g,
    int bm, int bn, int gt, int gwv)
{
    {
        int s = gt >> 7, r = (gt >> 2) & 31, c = gt & 3;
        gll16(A + (size_t)(bm + r) * lda + kb + s * 32 + c * 8,
              (const char*)As_g + gwv * 1024);
    }
    #pragma unroll
    for (int j = 0; j < 6; j++) {
        int ch = j * 256 + gt;
        int g2 = ch >> 9, ch2 = ch & 511;
        int s = ch2 >> 8, r = (ch2 >> 2) & 63, c = ch2 & 3;
        gll16(W + (size_t)(g2 * H_DIM + bn + r) * ldw + kb + s * 32 + c * 8,
              (const char*)Ws_g + j * 4096 + gwv * 1024);
    }
}

__device__ __forceinline__ void stage1(
    const unsigned short* __restrict__ A, int lda,
    const unsigned short* __restrict__ W, int ldw, int kb,
    unsigned short* As_g, unsigned short* Ws_g,
    int bm, int bn, int gt, int gwv)
{
    {
        int s = gt >> 7, r = (gt >> 2) & 31, c = gt & 3;
        gll16(A + (size_t)(bm + r) * lda + kb + s * 32 + c * 8,
              (const char*)As_g + gwv * 1024);
    }
    #pragma unroll
    for (int j = 0; j < 2; j++) {
        int ch = j * 256 + gt;
        int s = ch >> 8, r = (ch >> 2) & 63, c = ch & 3;
        gll16(W + (size_t)(bn + r) * ldw + kb + s * 32 + c * 8,
              (const char*)Ws_g + j * 4096 + gwv * 1024);
    }
}

__device__ __forceinline__ void compute3(
    const unsigned short* As_g, const unsigned short* Ws_g,
    int gwv, int ln, int quad,
    f32x4 (&accR)[2], f32x4 (&accZ)[2], f32x4 (&accN)[2])
{
    #pragma unroll
    for (int sub = 0; sub < 2; sub++) {
        short8 a[2], bw[3];
        #pragma unroll
        for (int i = 0; i < 2; i++)
            a[i] = *(const short8*)&As_g[sub * 1024 + (i * 16 + ln) * 32 + quad * 8];
        #pragma unroll
        for (int g = 0; g < 3; g++)
            bw[g] = *(const short8*)&Ws_g[g * 4096 + sub * 2048 + (gwv * 16 + ln) * 32 + quad * 8];
        #pragma unroll
        for (int i = 0; i < 2; i++) {
            accR[i] = __builtin_amdgcn_mfma_f32_16x16x32_bf16(a[i], bw[0], accR[i], 0, 0, 0);
            accZ[i] = __builtin_amdgcn_mfma_f32_16x16x32_bf16(a[i], bw[1], accZ[i], 0, 0, 0);
            accN[i] = __builtin_amdgcn_mfma_f32_16x16x32_bf16(a[i], bw[2], accN[i], 0, 0, 0);
        }
    }
}

__device__ __forceinline__ void compute1(
    const unsigned short* As_g, const unsigned short* Ws_g,
    int gwv, int ln, int quad, f32x4 (&accC)[2])
{
    #pragma unroll
    for (int sub = 0; sub < 2; sub++) {
        short8 a[2], bw;
        #pragma unroll
        for (int i = 0; i < 2; i++)
            a[i] = *(const short8*)&As_g[sub * 1024 + (i * 16 + ln) * 32 + quad * 8];
        bw = *(const short8*)&Ws_g[sub * 2048 + (gwv * 16 + ln) * 32 + quad * 8];
        #pragma unroll
        for (int i = 0; i < 2; i++)
            accC[i] = __builtin_amdgcn_mfma_f32_16x16x32_bf16(a[i], bw, accC[i], 0, 0, 0);
    }
}

// cross-group reduction + GRU elementwise epilogue (writes h fp32, hb bf16, slot)
__device__ __forceinline__ void gru_finish(
    f32x4 (&accR)[2], f32x4 (&accZ)[2], f32x4 (&accN0)[2], f32x4 (&accN1)[2],
    float* red, int wg, int gwv, int lane, int ln, int quad, int bm, int bn,
    const float* __restrict__ bih, const float* __restrict__ bhh,
    float* __restrict__ h,
    unsigned short* __restrict__ hb_out, unsigned short* __restrict__ slot)
{
    const int rb = (gwv * 64 + lane) * 33;
    if (wg == 1) {
        #pragma unroll
        for (int i = 0; i < 2; i++)
            #pragma unroll
            for (int r = 0; r < 4; r++) {
                red[rb + i * 4 + r]      = accR[i][r];
                red[rb + 8 + i * 4 + r]  = accZ[i][r];
                red[rb + 16 + i * 4 + r] = accN0[i][r];
                red[rb + 24 + i * 4 + r] = accN1[i][r];
            }
    }
    __syncthreads();
    if (wg == 0) {
        #pragma unroll
        for (int i = 0; i < 2; i++)
            #pragma unroll
            for (int r = 0; r < 4; r++) {
                accR[i][r]  += red[rb + i * 4 + r];
                accZ[i][r]  += red[rb + 8 + i * 4 + r];
                accN0[i][r] += red[rb + 16 + i * 4 + r];
                accN1[i][r] += red[rb + 24 + i * 4 + r];
            }
        const int n = bn + gwv * 16 + ln;
        const float br = bih[n] + bhh[n];
        const float bz = bih[H_DIM + n] + bhh[H_DIM + n];
        const float bi_n = bih[2 * H_DIM + n];
        const float bh_n = bhh[2 * H_DIM + n];
        #pragma unroll
        for (int i = 0; i < 2; i++) {
            #pragma unroll
            for (int r = 0; r < 4; r++) {
                const int m = bm + i * 16 + quad * 4 + r;
                const size_t idx = (size_t)m * H_DIM + n;
                float rg = 1.f / (1.f + __expf(-(accR[i][r] + br)));
                float zg = 1.f / (1.f + __expf(-(accZ[i][r] + bz)));
                float av = accN0[i][r] + bi_n + rg * (accN1[i][r] + bh_n);
                float e2 = __expf(-2.f * fabsf(av));
                float th = (1.f - e2) / (1.f + e2);
                th = av < 0.f ? -th : th;
                float o = (1.f - zg) * th + zg * h[idx];
                h[idx] = o;
                unsigned short ob = f2b(o);
                hb_out[idx] = ob;
                if (slot) slot[idx] = ob;
            }
        }
    }
}

// ---------------------------------------------------------------------------
// Persistent encoder: 64 GRU steps in one launch, device-scope grid barrier
// between steps. grid = NB blocks x 512 threads, 1 block/CU (112 KB LDS).
// Per step: phase0 (x_s@Wih, h-independent, overlaps barrier wait), wait,
// phase1 (h@Whh, 8 dbuf tiles), epilogue, arrive.
// ---------------------------------------------------------------------------
__global__ __launch_bounds__(512) void enc_persist(
    const unsigned short* __restrict__ xbp,   // [64,512,INP]
    const unsigned short* __restrict__ wIhp,  // [3072,INP]
    const unsigned short* __restrict__ wWhh,  // [3072,1024]
    const float* __restrict__ bih, const float* __restrict__ bhh,
    float* __restrict__ h,                    // [512,1024] fp32 in/out
    unsigned short* __restrict__ hb0,
    unsigned short* __restrict__ hb1,
    unsigned short* __restrict__ encb,        // [64,512,1024]
    unsigned* __restrict__ bar)
{
    __shared__ __align__(16) unsigned short As2[2][2][2048];      // 16 KB
    __shared__ __align__(16) unsigned short Ws2[2][2][12288];     // 96 KB

    const int bid = blockIdx.x;
    const int xcd = bid & 7, sb = bid >> 3;
    const int bn = (xcd * 2 + (sb >> 4)) * 64;   // XCD-chunked: weight slice/L2
    const int bm = (sb & 15) * 32;
    const int t = threadIdx.x;
    const int wg = t >> 8;
    const int gt = t & 255;
    const int lane = t & 63;
    const int gwv = gt >> 6;
    const int ln = lane & 15;
    const int quad = lane >> 4;

    unsigned short* hb[2] = {hb0, hb1};

    for (int s = 0; s < S_LEN; ++s) {
        f32x4 accR[2], accZ[2], accN0[2], accN1[2];
        #pragma unroll
        for (int i = 0; i < 2; i++) {
            f32x4 z = {0.f, 0.f, 0.f, 0.f};
            accR[i] = z; accZ[i] = z; accN0[i] = z; accN1[i] = z;
        }
        // phase0: x_s @ Wih^T (K=128, 64 per group) -> buf0; h-independent
        stage3(xbp + (size_t)s * BATCH * INP, INP, wIhp, INP, wg * 64,
               As2[wg][0], Ws2[wg][0], bm, bn, gt, gwv);
        __syncthreads();
        compute3(As2[wg][0], Ws2[wg][0], gwv, ln, quad, accR, accZ, accN0);
        // wait for h of step s (released at end of step s-1)
        if (t == 0 && s > 0) gbar_wait(bar, (unsigned)(s * NB));
        __syncthreads();
        // phase1: h @ Whh^T, 8 tiles double-buffered starting buf1
        const unsigned short* A1 = hb[s & 1];
        stage3(A1, H_DIM, wWhh, H_DIM, wg * 512, As2[wg][1], Ws2[wg][1],
               bm, bn, gt, gwv);
        __syncthreads();
        for (int i = 0; i < 8; ++i) {
            const int cur = (i + 1) & 1;
            if (i + 1 < 8)
                stage3(A1, H_DIM, wWhh, H_DIM, wg * 512 + ((i + 1) << 6),
                       As2[wg][cur ^ 1], Ws2[wg][cur ^ 1], bm, bn, gt, gwv);
            compute3(As2[wg][cur], Ws2[wg][cur], gwv, ln, quad, accR, accZ, accN1);
            __syncthreads();
        }
        gru_finish(accR, accZ, accN0, accN1, (float*)Ws2, wg, gwv, lane, ln,
                   quad, bm, bn, bih, bhh, h, hb[(s + 1) & 1],
                   encb + (size_t)s * BATCH * H_DIM);
        __syncthreads();
        if (t == 0 && s < S_LEN - 1) gbar_arrive(bar);
    }
}

// ---------------------------------------------------------------------------
// Persistent decoder: per step: attention (2 batch rows/block) -> gsync ->
// comb GEMM (relu(ctx@Wcc^T + combx)) -> gsync -> GRU (comb@Dih + h@Dhh)
// -> gsync. 31 steps, one launch.
// ---------------------------------------------------------------------------
__global__ __launch_bounds__(512) void dec_persist(
    const unsigned short* __restrict__ wAhT,   // [1024][64]
    const unsigned short* __restrict__ attnx,  // [31,512,64]
    const unsigned short* __restrict__ encb,   // [64,512,1024]
    const unsigned short* __restrict__ combx,  // [31,512,1024]
    const unsigned short* __restrict__ wCc,    // [1024,1024]
    const unsigned short* __restrict__ wDih,   // [3072,1024]
    const unsigned short* __restrict__ wDhh,   // [3072,1024]
    const float* __restrict__ bih, const float* __restrict__ bhh,
    float* __restrict__ h,
    unsigned short* __restrict__ hb0, unsigned short* __restrict__ hb1,
    unsigned short* __restrict__ ctx, unsigned short* __restrict__ comb,
    unsigned* __restrict__ bar)
{
    __shared__ __align__(16) unsigned short As2[2][2][2048];      // 16 KB
    __shared__ __align__(16) unsigned short Ws2[2][2][12288];     // 96 KB
    float* hfs  = (float*)Ws2;        // [2][1024] attention h rows (overlay)
    float* part = hfs + 2048;         // [2][4][64]
    float* awl  = part + 512;         // [2][64]

    const int bid = blockIdx.x;
    const int xcd = bid & 7, sb = bid >> 3;
    const int bn = (xcd * 2 + (sb >> 4)) * 64;
    const int bm = (sb & 15) * 32;
    const int t = threadIdx.x;
    const int wg = t >> 8;
    const int gt = t & 255;
    const int lane = t & 63;
    const int gwv = gt >> 6;
    const int ln = lane & 15;
    const int quad = lane >> 4;

    unsigned short* hb[2] = {hb0, hb1};
    unsigned tgt = 0;

    for (int td = 0; td < T_LEN - 1; ++td) {
        const unsigned short* hc = hb[td & 1];
        // ---------------- attention: rows b0=2*bid, b1=2*bid+1 ----------------
        {
            const int tt = t & 255, r2 = t >> 8;
            const int b = bid * 2 + r2;
            {
                us4 u = *(const us4*)(hc + ((size_t)b << 10) + tt * 4);
                #pragma unroll
                for (int j = 0; j < 4; j++) hfs[r2 * 1024 + tt * 4 + j] = b2f(u[j]);
            }
            __syncthreads();
            {
                const int c = tt & 63, ks = (tt >> 6) * 256;
                float sc = 0.f;
                #pragma unroll 8
                for (int k = 0; k < 256; k++)
                    sc += hfs[r2 * 1024 + ks + k] * b2f(wAhT[(size_t)(ks + k) * S_LEN + c]);
                part[(r2 * 4 + (tt >> 6)) * 64 + c] = sc;
            }
            __syncthreads();
            if (tt < 64) {
                float v = part[r2 * 256 + tt] + part[r2 * 256 + 64 + tt]
                        + part[r2 * 256 + 128 + tt] + part[r2 * 256 + 192 + tt]
                        + b2f(attnx[((size_t)td * BATCH + b) * S_LEN + tt]);
                float m = v;
                #pragma unroll
                for (int off = 32; off; off >>= 1) m = fmaxf(m, __shfl_xor(m, off));
                float e = __expf(v - m);
                float ss = e;
                #pragma unroll
                for (int off = 32; off; off >>= 1) ss += __shfl_xor(ss, off);
                awl[r2 * 64 + tt] = e / ss;
            }
            __syncthreads();
            const int hq = tt * 4;
            float s0 = 0.f, s1 = 0.f, s2 = 0.f, s3 = 0.f;
            #pragma unroll 4
            for (int l = 0; l < S_LEN; l++) {
                us4 u = *(const us4*)(encb + (((size_t)l * BATCH + b) << 10) + hq);
                float w = awl[r2 * 64 + l];
                s0 += w * b2f(u[0]); s1 += w * b2f(u[1]);
                s2 += w * b2f(u[2]); s3 += w * b2f(u[3]);
            }
            us4 o; o[0] = f2b(s0); o[1] = f2b(s1); o[2] = f2b(s2); o[3] = f2b(s3);
            *(us4*)(ctx + ((size_t)b << 10) + hq) = o;
        }
        tgt += NB; gsync(bar, tgt);
        // ---------------- comb = relu(ctx @ wCc^T + combx[td]) ----------------
        {
            f32x4 accC[2];
            {
                f32x4 z = {0.f, 0.f, 0.f, 0.f};
                accC[0] = z; accC[1] = z;
            }
            stage1(ctx, H_DIM, wCc, H_DIM, wg * 512,
                   As2[wg][0], Ws2[wg][0], bm, bn, gt, gwv);
            __syncthreads();
            for (int i = 0; i < 8; ++i) {
                const int cur = i & 1;
                if (i + 1 < 8)
                    stage1(ctx, H_DIM, wCc, H_DIM, wg * 512 + ((i + 1) << 6),
                           As2[wg][cur ^ 1], Ws2[wg][cur ^ 1], bm, bn, gt, gwv);
                compute1(As2[wg][cur], Ws2[wg][cur], gwv, ln, quad, accC);
                __syncthreads();
            }
            float* red = (float*)Ws2;
            const int rb = (gwv * 64 + lane) * 33;
            if (wg == 1) {
                #pragma unroll
                for (int i = 0; i < 2; i++)
                    #pragma unroll
                    for (int r = 0; r < 4; r++)
                        red[rb + i * 4 + r] = accC[i][r];
            }
            __syncthreads();
            if (wg == 0) {
                const int n = bn + gwv * 16 + ln;
                #pragma unroll
                for (int i = 0; i < 2; i++) {
                    #pragma unroll
                    for (int r = 0; r < 4; r++) {
                        const int m = bm + i * 16 + quad * 4 + r;
                        float v = accC[i][r] + red[rb + i * 4 + r]
                                + b2f(combx[(size_t)td * BATCH * H_DIM + (size_t)m * H_DIM + n]);
                        v = fmaxf(v, 0.f);
                        comb[(size_t)m * H_DIM + n] = f2b(v);
                    }
                }
            }
        }
        tgt += NB; gsync(bar, tgt);
        // ---------------- GRU: comb@wDih (N0) + hc@wDhh (N1) ----------------
        {
            f32x4 accR[2], accZ[2], accN0[2], accN1[2];
            #pragma unroll
            for (int i = 0; i < 2; i++) {
                f32x4 z = {0.f, 0.f, 0.f, 0.f};
                accR[i] = z; accZ[i] = z; accN0[i] = z; accN1[i] = z;
            }
            auto stgd = [&](int i, int buf) {
                if (i < 8)
                    stage3(comb, H_DIM, wDih, H_DIM, wg * 512 + (i << 6),
                           As2[wg][buf], Ws2[wg][buf], bm, bn, gt, gwv);
                else
                    stage3(hc, H_DIM, wDhh, H_DIM, wg * 512 + ((i - 8) << 6),
                           As2[wg][buf], Ws2[wg][buf], bm, bn, gt, gwv);
            };
            stgd(0, 0);
            __syncthreads();
            for (int i = 0; i < 16; ++i) {
                const int cur = i & 1;
                if (i + 1 < 16) stgd(i + 1, cur ^ 1);
                if (i < 8)
                    compute3(As2[wg][cur], Ws2[wg][cur], gwv, ln, quad, accR, accZ, accN0);
                else
                    compute3(As2[wg][cur], Ws2[wg][cur], gwv, ln, quad, accR, accZ, accN1);
                __syncthreads();
            }
            gru_finish(accR, accZ, accN0, accN1, (float*)Ws2, wg, gwv, lane, ln,
                       quad, bm, bn, bih, bhh, h, hb[(td + 1) & 1], nullptr);
        }
        if (td < T_LEN - 2) { tgt += NB; gsync(bar, tgt); }
    }
}

// strided fp32 -> compact bf16 weight convert, 4 elems/thread (cols % 4 == 0)
__global__ void cvt_w4(const float* __restrict__ src, int ld,
                       unsigned short* __restrict__ dst, int rows, int cols)
{
    int idx = blockIdx.x * blockDim.x + threadIdx.x;
    int total4 = rows * cols / 4;
    if (idx >= total4) return;
    int e = idx * 4;
    int r = e / cols, c = e - r * cols;
    const float* s = src + (size_t)r * ld + c;
    us4 o;
    #pragma unroll
    for (int j = 0; j < 4; j++) o[j] = f2b(s[j]);
    *(us4*)(dst + e) = o;
}

// contiguous fp32 -> bf16, 4 elems/thread
__global__ void cvt_plain4(const float* __restrict__ src,
                           unsigned short* __restrict__ dst, int total4)
{
    int idx = blockIdx.x * blockDim.x + threadIdx.x;
    if (idx >= total4) return;
    f32x4 v = *(const f32x4*)(src + (size_t)idx * 4);
    us4 o;
    #pragma unroll
    for (int j = 0; j < 4; j++) o[j] = f2b(v[j]);
    *(us4*)(dst + (size_t)idx * 4) = o;
}

// fp32 [rows, scols] -> bf16 [rows, dcols] zero-padded
__global__ void cvt_pad(const float* __restrict__ src, int scols,
                        unsigned short* __restrict__ dst, int dcols, int total)
{
    int idx = blockIdx.x * blockDim.x + threadIdx.x;
    if (idx >= total) return;
    int r = idx / dcols, c = idx - r * dcols;
    dst[idx] = (c < scols) ? f2b(src[(size_t)r * scols + c]) : (unsigned short)0;
}

// attn_W[:, H:2H] fp32 [64, ld 2048] -> wAhT bf16 [k][c]
__global__ void cvt_attT(const float* __restrict__ attn_W,
                         unsigned short* __restrict__ dst)
{
    int idx = blockIdx.x * blockDim.x + threadIdx.x;
    if (idx >= S_LEN * H_DIM) return;
    int k = idx >> 6, c = idx & 63;
    dst[idx] = f2b(attn_W[(size_t)c * 2 * H_DIM + H_DIM + k]);
}

__global__ void log_softmax1024(float* __restrict__ x)
{
    __shared__ float red[256];
    float* xr = x + (size_t)blockIdx.x * O_DIM;
    int t = threadIdx.x;
    float m = -1e30f;
    for (int i = t; i < O_DIM; i += 256) m = fmaxf(m, xr[i]);
    red[t] = m; __syncthreads();
    for (int s2 = 128; s2 > 0; s2 >>= 1) {
        if (t < s2) red[t] = fmaxf(red[t], red[t + s2]);
        __syncthreads();
    }
    m = red[0];
    __syncthreads();
    float s = 0.f;
    for (int i = t; i < O_DIM; i += 256) s += expf(xr[i] - m);
    red[t] = s; __syncthreads();
    for (int s2 = 128; s2 > 0; s2 >>= 1) {
        if (t < s2) red[t] += red[t + s2];
        __syncthreads();
    }
    float lse = m + logf(red[0]);
    __syncthreads();
    for (int i = t; i < O_DIM; i += 256) xr[i] = xr[i] - lse;
}

// ---------------------------------------------------------------------------
extern "C" void kernel_launch(void* const* d_in, const int* in_sizes, int n_in,
                              void* d_out, int out_size, void* d_ws, size_t ws_size,
                              hipStream_t stream)
{
    const float* input   = (const float*)d_in[0];   // [S,B,IN]
    const float* target  = (const float*)d_in[1];   // [T,B,H]
    const float* enc_Wih = (const float*)d_in[2];
    const float* enc_Whh = (const float*)d_in[3];
    const float* enc_bih = (const float*)d_in[4];
    const float* enc_bhh = (const float*)d_in[5];
    const float* attn_W  = (const float*)d_in[6];   // [S,2H]
    const float* attn_b  = (const float*)d_in[7];
    const float* comb_W  = (const float*)d_in[8];   // [H,2H]
    const float* comb_b  = (const float*)d_in[9];
    const float* dec_Wih = (const float*)d_in[10];
    const float* dec_Whh = (const float*)d_in[11];
    const float* dec_bih = (const float*)d_in[12];
    const float* dec_bhh = (const float*)d_in[13];
    const float* out_W   = (const float*)d_in[14];
    const float* out_b   = (const float*)d_in[15];
    float* out = (float*)d_out;                     // [B,O] fp32

    // ---- workspace layout ----
    char* p = (char*)d_ws;
    auto alloc = [&](size_t bytes) {
        char* r = p; p += (bytes + 255) & ~(size_t)255; return r;
    };
    unsigned short* wWhh  = (unsigned short*)alloc((size_t)H3 * H_DIM * 2);
    unsigned short* wDih  = (unsigned short*)alloc((size_t)H3 * H_DIM * 2);
    unsigned short* wDhh  = (unsigned short*)alloc((size_t)H3 * H_DIM * 2);
    unsigned short* wCc   = (unsigned short*)alloc((size_t)H_DIM * H_DIM * 2);
    unsigned short* wCx   = (unsigned short*)alloc((size_t)H_DIM * H_DIM * 2);
    unsigned short* wO    = (unsigned short*)alloc((size_t)O_DIM * H_DIM * 2);
    unsigned short* wAhT  = (unsigned short*)alloc((size_t)H_DIM * S_LEN * 2);
    unsigned short* wAx   = (unsigned short*)alloc((size_t)S_LEN * H_DIM * 2);
    unsigned short* wIhp  = (unsigned short*)alloc((size_t)H3 * INP * 2);
    unsigned short* xbp   = (unsigned short*)alloc((size_t)S_LEN * BATCH * INP * 2);
    unsigned short* encb  = (unsigned short*)alloc((size_t)S_LEN * BATCH * H_DIM * 2);
    unsigned short* combx = (unsigned short*)alloc((size_t)(T_LEN - 1) * BATCH * H_DIM * 2);
    unsigned short* attnx = (unsigned short*)alloc((size_t)(T_LEN - 1) * BATCH * S_LEN * 2);
    float*          h     = (float*)alloc((size_t)BATCH * H_DIM * 4);
    unsigned short* hbA   = (unsigned short*)alloc((size_t)BATCH * H_DIM * 2);
    unsigned short* hbB   = (unsigned short*)alloc((size_t)BATCH * H_DIM * 2);
    unsigned short* ctx   = (unsigned short*)alloc((size_t)BATCH * H_DIM * 2);
    unsigned short* comb  = (unsigned short*)alloc((size_t)BATCH * H_DIM * 2);
    unsigned*       bar   = (unsigned*)alloc(512);
    // targetb overlays encb: consumed (attnx/combx gemms) before encoder
    // writes encb. [32*512, 1024] bf16 = 33.5 MB inside encb's 64 MB.
    unsigned short* targetb = encb;

    const dim3 blk(256);

    hipMemsetAsync(h,   0, (size_t)BATCH * H_DIM * 4, stream);
    hipMemsetAsync(hbA, 0, (size_t)BATCH * H_DIM * 2, stream);
    hipMemsetAsync(bar, 0, 512, stream);

    // ---- one-time converts (all bf16) ----
    cvt_w4<<<(H3 * H_DIM / 4 + 255) / 256, blk, 0, stream>>>(enc_Whh, H_DIM, wWhh, H3, H_DIM);
    cvt_w4<<<(H3 * H_DIM / 4 + 255) / 256, blk, 0, stream>>>(dec_Wih, H_DIM, wDih, H3, H_DIM);
    cvt_w4<<<(H3 * H_DIM / 4 + 255) / 256, blk, 0, stream>>>(dec_Whh, H_DIM, wDhh, H3, H_DIM);
    cvt_w4<<<(H_DIM * H_DIM / 4 + 255) / 256, blk, 0, stream>>>(comb_W + H_DIM, 2 * H_DIM, wCc, H_DIM, H_DIM);
    cvt_w4<<<(H_DIM * H_DIM / 4 + 255) / 256, blk, 0, stream>>>(comb_W, 2 * H_DIM, wCx, H_DIM, H_DIM);
    cvt_w4<<<(O_DIM * H_DIM / 4 + 255) / 256, blk, 0, stream>>>(out_W, H_DIM, wO, O_DIM, H_DIM);
    cvt_w4<<<(S_LEN * H_DIM / 4 + 255) / 256, blk, 0, stream>>>(attn_W, 2 * H_DIM, wAx, S_LEN, H_DIM);
    cvt_attT<<<(S_LEN * H_DIM + 255) / 256, blk, 0, stream>>>(attn_W, wAhT);
    cvt_pad<<<((S_LEN * BATCH * INP) + 255) / 256, blk, 0, stream>>>(
        input, IN_DIM, xbp, INP, S_LEN * BATCH * INP);
    cvt_pad<<<((H3 * INP) + 255) / 256, blk, 0, stream>>>(
        enc_Wih, IN_DIM, wIhp, INP, H3 * INP);
    cvt_plain4<<<((T_LEN * BATCH * H_DIM / 4) + 255) / 256, blk, 0, stream>>>(
        target, targetb, T_LEN * BATCH * H_DIM / 4);

    const int MT = (T_LEN - 1) * BATCH;  // 15872
    // attnx = target @ attn_W[:, :H]^T + attn_b
    gemm_k<64, 64><<<dim3(1, MT / 64), blk, 0, stream>>>(
        targetb, H_DIM, wAx, H_DIM, attn_b,
        nullptr, nullptr, 0, nullptr, attnx, S_LEN, H_DIM, 1 | 32);
    // combx = target @ comb_W[:, :H]^T + comb_b  (128x128 tile, 992 blocks)
    gemm_k<128, 128><<<dim3(H_DIM / 128, MT / 128), blk, 0, stream>>>(
        targetb, H_DIM, wCx, H_DIM, comb_b,
        nullptr, nullptr, 0, nullptr, combx, H_DIM, H_DIM, 1 | 32);

    // ---------------- persistent encoder (64 steps, 1 launch) ----------------
    enc_persist<<<NB, 512, 0, stream>>>(
        xbp, wIhp, wWhh, enc_bih, enc_bhh, h, hbA, hbB, encb, bar);

    // ---------------- persistent decoder (31 steps, 1 launch) ----------------
    dec_persist<<<NB, 512, 0, stream>>>(
        wAhT, attnx, encb, combx, wCc, wDih, wDhh, dec_bih, dec_bhh,
        h, hbA, hbB, ctx, comb, bar + 64);

    // ---------------- output (final h is hbB after 31 decoder steps) --------
    gemm_k<32, 64><<<dim3(O_DIM / 64, BATCH / 32), blk, 0, stream>>>(
        hbB, H_DIM, wO, H_DIM, out_b,
        nullptr, nullptr, 0, out, nullptr, O_DIM, H_DIM, 1 | 16);
    log_softmax1024<<<BATCH, blk, 0, stream>>>(out);
}

// Round 3
// 5904.456 us; speedup vs baseline: 1.5589x; 1.5589x over previous
//
#include <hip/hip_runtime.h>
#include <hip/hip_bf16.h>
#include <math.h>

#define S_LEN 64
#define T_LEN 32
#define BATCH 512
#define IN_DIM 66
#define INP 128         // IN_DIM zero-padded to multiple of 64
#define H_DIM 1024
#define O_DIM 1024
#define H3 3072
#define NB 256          // persistent grid size (1 block/CU, LDS-limited)
#define AUX_SC 17       // cpol sc0|sc1: device-coherent, bypass L1/L2, LLC point

typedef __attribute__((ext_vector_type(8))) short short8;
typedef __attribute__((ext_vector_type(4))) float f32x4;
typedef __attribute__((ext_vector_type(4))) unsigned short us4;

__device__ __forceinline__ unsigned short f2b(float f) {
    union { float f; unsigned u; } x; x.f = f;
    unsigned r = x.u + 0x7FFF + ((x.u >> 16) & 1);
    return (unsigned short)(r >> 16);
}
__device__ __forceinline__ float b2f(unsigned short s) {
    union { unsigned u; float f; } x; x.u = ((unsigned)s) << 16;
    return x.f;
}
// async global->LDS, 16B per lane; lds base must be wave-uniform. AUX = cpol.
template<int AUX>
__device__ __forceinline__ void gll16x(const void* g, const void* l) {
    __builtin_amdgcn_global_load_lds(
        (const __attribute__((address_space(1))) unsigned int*)g,
        (__attribute__((address_space(3))) unsigned int*)l, 16, 0, AUX);
}
__device__ __forceinline__ void gll16(const void* g, const void* l) {
    gll16x<0>(g, l);
}
// device-coherent (LLC) scalar/vector access for cross-block data
__device__ __forceinline__ void store_b16_sc(unsigned short* p, unsigned v) {
    asm volatile("global_store_short %0, %1, off sc0 sc1" :: "v"(p), "v"(v) : "memory");
}
__device__ __forceinline__ void store_us4_sc(unsigned short* p, us4 v) {
    asm volatile("global_store_dwordx2 %0, %1, off sc0 sc1" :: "v"(p), "v"(v) : "memory");
}
__device__ __forceinline__ us4 load_us4_sc(const unsigned short* p) {
    us4 r;
    asm volatile("global_load_dwordx2 %0, %1, off sc0 sc1\n\ts_waitcnt vmcnt(0)"
                 : "=v"(r) : "v"(p) : "memory");
    return r;
}

// ---- fence-free grid barrier: relaxed agent atomics; visibility is carried
// ---- by sc0/sc1 data ops + the vmcnt(0) drain inside __syncthreads().
__device__ __forceinline__ void gbar_arrive(unsigned* bar) {
    __hip_atomic_fetch_add(bar, 1u, __ATOMIC_RELAXED, __HIP_MEMORY_SCOPE_AGENT);
}
__device__ __forceinline__ void gbar_wait(unsigned* bar, unsigned target) {
    while (__hip_atomic_load(bar, __ATOMIC_RELAXED, __HIP_MEMORY_SCOPE_AGENT) < target)
        __builtin_amdgcn_s_sleep(2);
}
__device__ __forceinline__ void gsync(unsigned* bar, unsigned target) {
    __syncthreads();                 // emits s_waitcnt vmcnt(0) before s_barrier
    if (threadIdx.x == 0) {
        gbar_arrive(bar);
        gbar_wait(bar, target);
    }
    __syncthreads();
}

// ---------------------------------------------------------------------------
// MFMA GEMM, bf16: C[M,N] = A@W^T, tile TM x TN. lda/ldw mult of 8, K mult 32.
// Double-buffered: stage tile t+1 while computing tile t, ONE barrier/tile.
// flags: 1 bias, 2 add fp32, 4 add bf16, 8 relu, 16 store f32, 32 store bf16
// ---------------------------------------------------------------------------
template<int TM, int TN>
__global__ __launch_bounds__(256) void gemm_k(
    const unsigned short* __restrict__ A, int lda,
    const unsigned short* __restrict__ W, int ldw,
    const float* __restrict__ bias,
    const float* __restrict__ addf, const unsigned short* __restrict__ addb,
    int ldadd,
    float* __restrict__ Cf,
    unsigned short* __restrict__ Cb, int ldc,
    int K, int flags)
{
    constexpr int IF = TM / 16;   // A frags per wave
    constexpr int JF = TN / 64;   // B frags per wave
    constexpr int NW = TN / 4;    // cols per wave
    constexpr int CA = TM * 4;    // 16B chunks in A tile
    constexpr int CW = TN * 4;
    __shared__ __align__(16) unsigned short As[2][TM * 32];
    __shared__ __align__(16) unsigned short Bs[2][TN * 32];

    const int bm = blockIdx.y * TM;
    const int bn = blockIdx.x * TN;
    const int t = threadIdx.x;
    const int lane = t & 63;
    const int wv = t >> 6;
    const int ln = lane & 15;
    const int quad = lane >> 4;

    f32x4 acc[IF][JF];
    #pragma unroll
    for (int i = 0; i < IF; i++)
        #pragma unroll
        for (int j = 0; j < JF; j++) {
            f32x4 z = {0.f, 0.f, 0.f, 0.f};
            acc[i][j] = z;
        }

    auto stage = [&](int buf, int k0) {
        if constexpr (CA >= 256) {
            #pragma unroll
            for (int j = 0; j < CA / 256; j++) {
                int ch = j * 256 + t;
                gll16(A + (size_t)(bm + (ch >> 2)) * lda + k0 + (ch & 3) * 8,
                      (const char*)As[buf] + (j * 4 + wv) * 1024);
            }
        } else {
            if (t < CA)
                gll16(A + (size_t)(bm + (t >> 2)) * lda + k0 + (t & 3) * 8,
                      (const char*)As[buf] + wv * 1024);
        }
        if constexpr (CW >= 256) {
            #pragma unroll
            for (int j = 0; j < CW / 256; j++) {
                int ch = j * 256 + t;
                gll16(W + (size_t)(bn + (ch >> 2)) * ldw + k0 + (ch & 3) * 8,
                      (const char*)Bs[buf] + (j * 4 + wv) * 1024);
            }
        } else {
            if (t < CW)
                gll16(W + (size_t)(bn + (t >> 2)) * ldw + k0 + (t & 3) * 8,
                      (const char*)Bs[buf] + wv * 1024);
        }
    };

    const int nt = K >> 5;
    stage(0, 0);
    __syncthreads();
    for (int i = 0; i < nt; ++i) {
        const int cur = i & 1;
        if (i + 1 < nt) stage(cur ^ 1, (i + 1) << 5);
        short8 af[IF], bf[JF];
        #pragma unroll
        for (int ii = 0; ii < IF; ii++)
            af[ii] = *(const short8*)&As[cur][(ii * 16 + ln) * 32 + quad * 8];
        #pragma unroll
        for (int j = 0; j < JF; j++)
            bf[j] = *(const short8*)&Bs[cur][(wv * NW + j * 16 + ln) * 32 + quad * 8];
        #pragma unroll
        for (int ii = 0; ii < IF; ii++)
            #pragma unroll
            for (int j = 0; j < JF; j++)
                acc[ii][j] = __builtin_amdgcn_mfma_f32_16x16x32_bf16(
                    af[ii], bf[j], acc[ii][j], 0, 0, 0);
        __syncthreads();   // drains next-tile loads; guards buffer reuse
    }

    #pragma unroll
    for (int i = 0; i < IF; i++) {
        #pragma unroll
        for (int j = 0; j < JF; j++) {
            #pragma unroll
            for (int r = 0; r < 4; r++) {
                int m = bm + i * 16 + quad * 4 + r;
                int n = bn + wv * NW + j * 16 + ln;
                float v = acc[i][j][r];
                if (flags & 1) v += bias[n];
                if (flags & 2) v += addf[(size_t)m * ldadd + n];
                if (flags & 4) v += b2f(addb[(size_t)m * ldadd + n]);
                if (flags & 8) v = fmaxf(v, 0.f);
                if (flags & 16) Cf[(size_t)m * ldc + n] = v;
                if (flags & 32) Cb[(size_t)m * ldc + n] = f2b(v);
            }
        }
    }
}

// ---------------------------------------------------------------------------
// Tile stage/compute helpers for the 32x64, 512-thread, 2-group K-split GEMM.
// AAUX: cpol for the A-operand staging (AUX_SC when A was written by peer
// blocks inside this persistent kernel). Weights always cached (aux 0).
// ---------------------------------------------------------------------------
template<int AAUX>
__device__ __forceinline__ void stage3(
    const unsigned short* __restrict__ A, int lda,
    const unsigned short* __restrict__ W, int ldw, int kb,
    unsigned short* As_g, unsigned short* Ws_g,
    int bm, int bn, int gt, int gwv)
{
    {
        int s = gt >> 7, r = (gt >> 2) & 31, c = gt & 3;
        gll16x<AAUX>(A + (size_t)(bm + r) * lda + kb + s * 32 + c * 8,
                     (const char*)As_g + gwv * 1024);
    }
    #pragma unroll
    for (int j = 0; j < 6; j++) {
        int ch = j * 256 + gt;
        int g2 = ch >> 9, ch2 = ch & 511;
        int s = ch2 >> 8, r = (ch2 >> 2) & 63, c = ch2 & 3;
        gll16(W + (size_t)(g2 * H_DIM + bn + r) * ldw + kb + s * 32 + c * 8,
              (const char*)Ws_g + j * 4096 + gwv * 1024);
    }
}

template<int AAUX>
__device__ __forceinline__ void stage1(
    const unsigned short* __restrict__ A, int lda,
    const unsigned short* __restrict__ W, int ldw, int kb,
    unsigned short* As_g, unsigned short* Ws_g,
    int bm, int bn, int gt, int gwv)
{
    {
        int s = gt >> 7, r = (gt >> 2) & 31, c = gt & 3;
        gll16x<AAUX>(A + (size_t)(bm + r) * lda + kb + s * 32 + c * 8,
                     (const char*)As_g + gwv * 1024);
    }
    #pragma unroll
    for (int j = 0; j < 2; j++) {
        int ch = j * 256 + gt;
        int s = ch >> 8, r = (ch >> 2) & 63, c = ch & 3;
        gll16(W + (size_t)(bn + r) * ldw + kb + s * 32 + c * 8,
              (const char*)Ws_g + j * 4096 + gwv * 1024);
    }
}

__device__ __forceinline__ void compute3(
    const unsigned short* As_g, const unsigned short* Ws_g,
    int gwv, int ln, int quad,
    f32x4 (&accR)[2], f32x4 (&accZ)[2], f32x4 (&accN)[2])
{
    #pragma unroll
    for (int sub = 0; sub < 2; sub++) {
        short8 a[2], bw[3];
        #pragma unroll
        for (int i = 0; i < 2; i++)
            a[i] = *(const short8*)&As_g[sub * 1024 + (i * 16 + ln) * 32 + quad * 8];
        #pragma unroll
        for (int g = 0; g < 3; g++)
            bw[g] = *(const short8*)&Ws_g[g * 4096 + sub * 2048 + (gwv * 16 + ln) * 32 + quad * 8];
        #pragma unroll
        for (int i = 0; i < 2; i++) {
            accR[i] = __builtin_amdgcn_mfma_f32_16x16x32_bf16(a[i], bw[0], accR[i], 0, 0, 0);
            accZ[i] = __builtin_amdgcn_mfma_f32_16x16x32_bf16(a[i], bw[1], accZ[i], 0, 0, 0);
            accN[i] = __builtin_amdgcn_mfma_f32_16x16x32_bf16(a[i], bw[2], accN[i], 0, 0, 0);
        }
    }
}

__device__ __forceinline__ void compute1(
    const unsigned short* As_g, const unsigned short* Ws_g,
    int gwv, int ln, int quad, f32x4 (&accC)[2])
{
    #pragma unroll
    for (int sub = 0; sub < 2; sub++) {
        short8 a[2], bw;
        #pragma unroll
        for (int i = 0; i < 2; i++)
            a[i] = *(const short8*)&As_g[sub * 1024 + (i * 16 + ln) * 32 + quad * 8];
        bw = *(const short8*)&Ws_g[sub * 2048 + (gwv * 16 + ln) * 32 + quad * 8];
        #pragma unroll
        for (int i = 0; i < 2; i++)
            accC[i] = __builtin_amdgcn_mfma_f32_16x16x32_bf16(a[i], bw, accC[i], 0, 0, 0);
    }
}

// cross-group reduction + GRU elementwise epilogue.
// h: block-private fp32 (cached). hb_out: cross-block -> sc0/sc1 stores.
// slot: consumed only by later kernels -> plain stores.
__device__ __forceinline__ void gru_finish(
    f32x4 (&accR)[2], f32x4 (&accZ)[2], f32x4 (&accN0)[2], f32x4 (&accN1)[2],
    float* red, int wg, int gwv, int lane, int ln, int quad, int bm, int bn,
    const float* __restrict__ bih, const float* __restrict__ bhh,
    float* __restrict__ h,
    unsigned short* __restrict__ hb_out, unsigned short* __restrict__ slot)
{
    const int rb = (gwv * 64 + lane) * 33;
    if (wg == 1) {
        #pragma unroll
        for (int i = 0; i < 2; i++)
            #pragma unroll
            for (int r = 0; r < 4; r++) {
                red[rb + i * 4 + r]      = accR[i][r];
                red[rb + 8 + i * 4 + r]  = accZ[i][r];
                red[rb + 16 + i * 4 + r] = accN0[i][r];
                red[rb + 24 + i * 4 + r] = accN1[i][r];
            }
    }
    __syncthreads();
    if (wg == 0) {
        #pragma unroll
        for (int i = 0; i < 2; i++)
            #pragma unroll
            for (int r = 0; r < 4; r++) {
                accR[i][r]  += red[rb + i * 4 + r];
                accZ[i][r]  += red[rb + 8 + i * 4 + r];
                accN0[i][r] += red[rb + 16 + i * 4 + r];
                accN1[i][r] += red[rb + 24 + i * 4 + r];
            }
        const int n = bn + gwv * 16 + ln;
        const float br = bih[n] + bhh[n];
        const float bz = bih[H_DIM + n] + bhh[H_DIM + n];
        const float bi_n = bih[2 * H_DIM + n];
        const float bh_n = bhh[2 * H_DIM + n];
        #pragma unroll
        for (int i = 0; i < 2; i++) {
            #pragma unroll
            for (int r = 0; r < 4; r++) {
                const int m = bm + i * 16 + quad * 4 + r;
                const size_t idx = (size_t)m * H_DIM + n;
                float rg = 1.f / (1.f + __expf(-(accR[i][r] + br)));
                float zg = 1.f / (1.f + __expf(-(accZ[i][r] + bz)));
                float av = accN0[i][r] + bi_n + rg * (accN1[i][r] + bh_n);
                float e2 = __expf(-2.f * fabsf(av));
                float th = (1.f - e2) / (1.f + e2);
                th = av < 0.f ? -th : th;
                float o = (1.f - zg) * th + zg * h[idx];
                h[idx] = o;
                unsigned short ob = f2b(o);
                store_b16_sc(hb_out + idx, (unsigned)ob);
                if (slot) slot[idx] = ob;
            }
        }
    }
}

// ---------------------------------------------------------------------------
// Persistent encoder: 64 GRU steps in one launch, fence-free grid barrier.
// grid = NB blocks x 512 threads, 1 block/CU (112 KB LDS).
// ---------------------------------------------------------------------------
__global__ __launch_bounds__(512) void enc_persist(
    const unsigned short* __restrict__ xbp,   // [64,512,INP]
    const unsigned short* __restrict__ wIhp,  // [3072,INP]
    const unsigned short* __restrict__ wWhh,  // [3072,1024]
    const float* __restrict__ bih, const float* __restrict__ bhh,
    float* __restrict__ h,                    // [512,1024] fp32 (block-private)
    unsigned short* __restrict__ hb0,
    unsigned short* __restrict__ hb1,
    unsigned short* __restrict__ encb,        // [64,512,1024]
    unsigned* __restrict__ bar)
{
    __shared__ __align__(16) unsigned short As2[2][2][2048];      // 16 KB
    __shared__ __align__(16) unsigned short Ws2[2][2][12288];     // 96 KB

    const int bid = blockIdx.x;
    const int xcd = bid & 7, sb = bid >> 3;
    const int bn = (xcd * 2 + (sb >> 4)) * 64;   // XCD-chunked: weight slice/L2
    const int bm = (sb & 15) * 32;
    const int t = threadIdx.x;
    const int wg = t >> 8;
    const int gt = t & 255;
    const int lane = t & 63;
    const int gwv = gt >> 6;
    const int ln = lane & 15;
    const int quad = lane >> 4;

    unsigned short* hb[2] = {hb0, hb1};

    for (int s = 0; s < S_LEN; ++s) {
        f32x4 accR[2], accZ[2], accN0[2], accN1[2];
        #pragma unroll
        for (int i = 0; i < 2; i++) {
            f32x4 z = {0.f, 0.f, 0.f, 0.f};
            accR[i] = z; accZ[i] = z; accN0[i] = z; accN1[i] = z;
        }
        // phase0: x_s @ Wih^T (K=128, 64 per group) -> buf0; h-independent
        stage3<0>(xbp + (size_t)s * BATCH * INP, INP, wIhp, INP, wg * 64,
                  As2[wg][0], Ws2[wg][0], bm, bn, gt, gwv);
        __syncthreads();
        compute3(As2[wg][0], Ws2[wg][0], gwv, ln, quad, accR, accZ, accN0);
        // wait for h of step s (released at end of step s-1)
        if (t == 0 && s > 0) gbar_wait(bar, (unsigned)(s * NB));
        __syncthreads();
        // phase1: h @ Whh^T, 8 tiles double-buffered starting buf1
        const unsigned short* A1 = hb[s & 1];
        stage3<AUX_SC>(A1, H_DIM, wWhh, H_DIM, wg * 512, As2[wg][1], Ws2[wg][1],
                       bm, bn, gt, gwv);
        __syncthreads();
        for (int i = 0; i < 8; ++i) {
            const int cur = (i + 1) & 1;
            if (i + 1 < 8)
                stage3<AUX_SC>(A1, H_DIM, wWhh, H_DIM, wg * 512 + ((i + 1) << 6),
                               As2[wg][cur ^ 1], Ws2[wg][cur ^ 1], bm, bn, gt, gwv);
            compute3(As2[wg][cur], Ws2[wg][cur], gwv, ln, quad, accR, accZ, accN1);
            __syncthreads();
        }
        gru_finish(accR, accZ, accN0, accN1, (float*)Ws2, wg, gwv, lane, ln,
                   quad, bm, bn, bih, bhh, h, hb[(s + 1) & 1],
                   encb + (size_t)s * BATCH * H_DIM);
        __syncthreads();   // vmcnt(0) drain: sc1 stores committed to LLC
        if (t == 0 && s < S_LEN - 1) gbar_arrive(bar);
    }
}

// ---------------------------------------------------------------------------
// Persistent decoder: per step: attention (2 rows/block) -> gsync ->
// comb GEMM -> gsync -> GRU -> gsync. 31 steps, one launch.
// ---------------------------------------------------------------------------
__global__ __launch_bounds__(512) void dec_persist(
    const unsigned short* __restrict__ wAhT,   // [1024][64]
    const unsigned short* __restrict__ attnx,  // [31,512,64]
    const unsigned short* __restrict__ encb,   // [64,512,1024]
    const unsigned short* __restrict__ combx,  // [31,512,1024]
    const unsigned short* __restrict__ wCc,    // [1024,1024]
    const unsigned short* __restrict__ wDih,   // [3072,1024]
    const unsigned short* __restrict__ wDhh,   // [3072,1024]
    const float* __restrict__ bih, const float* __restrict__ bhh,
    float* __restrict__ h,
    unsigned short* __restrict__ hb0, unsigned short* __restrict__ hb1,
    unsigned short* __restrict__ ctx, unsigned short* __restrict__ comb,
    unsigned* __restrict__ bar)
{
    __shared__ __align__(16) unsigned short As2[2][2][2048];      // 16 KB
    __shared__ __align__(16) unsigned short Ws2[2][2][12288];     // 96 KB
    float* hfs  = (float*)Ws2;        // [2][1024] attention h rows (overlay)
    float* part = hfs + 2048;         // [2][4][64]
    float* awl  = part + 512;         // [2][64]

    const int bid = blockIdx.x;
    const int xcd = bid & 7, sb = bid >> 3;
    const int bn = (xcd * 2 + (sb >> 4)) * 64;
    const int bm = (sb & 15) * 32;
    const int t = threadIdx.x;
    const int wg = t >> 8;
    const int gt = t & 255;
    const int lane = t & 63;
    const int gwv = gt >> 6;
    const int ln = lane & 15;
    const int quad = lane >> 4;

    unsigned short* hb[2] = {hb0, hb1};
    unsigned tgt = 0;

    for (int td = 0; td < T_LEN - 1; ++td) {
        const unsigned short* hc = hb[td & 1];
        // ---------------- attention: rows b0=2*bid, b1=2*bid+1 ----------------
        {
            const int tt = t & 255, r2 = t >> 8;
            const int b = bid * 2 + r2;
            {
                us4 u = load_us4_sc(hc + ((size_t)b << 10) + tt * 4);
                #pragma unroll
                for (int j = 0; j < 4; j++) hfs[r2 * 1024 + tt * 4 + j] = b2f(u[j]);
            }
            __syncthreads();
            {
                const int c = tt & 63, ks = (tt >> 6) * 256;
                float sc = 0.f;
                #pragma unroll 8
                for (int k = 0; k < 256; k++)
                    sc += hfs[r2 * 1024 + ks + k] * b2f(wAhT[(size_t)(ks + k) * S_LEN + c]);
                part[(r2 * 4 + (tt >> 6)) * 64 + c] = sc;
            }
            __syncthreads();
            if (tt < 64) {
                float v = part[r2 * 256 + tt] + part[r2 * 256 + 64 + tt]
                        + part[r2 * 256 + 128 + tt] + part[r2 * 256 + 192 + tt]
                        + b2f(attnx[((size_t)td * BATCH + b) * S_LEN + tt]);
                float m = v;
                #pragma unroll
                for (int off = 32; off; off >>= 1) m = fmaxf(m, __shfl_xor(m, off));
                float e = __expf(v - m);
                float ss = e;
                #pragma unroll
                for (int off = 32; off; off >>= 1) ss += __shfl_xor(ss, off);
                awl[r2 * 64 + tt] = e / ss;
            }
            __syncthreads();
            const int hq = tt * 4;
            float s0 = 0.f, s1 = 0.f, s2 = 0.f, s3 = 0.f;
            #pragma unroll 4
            for (int l = 0; l < S_LEN; l++) {
                us4 u = *(const us4*)(encb + (((size_t)l * BATCH + b) << 10) + hq);
                float w = awl[r2 * 64 + l];
                s0 += w * b2f(u[0]); s1 += w * b2f(u[1]);
                s2 += w * b2f(u[2]); s3 += w * b2f(u[3]);
            }
            us4 o; o[0] = f2b(s0); o[1] = f2b(s1); o[2] = f2b(s2); o[3] = f2b(s3);
            store_us4_sc(ctx + ((size_t)b << 10) + hq, o);
        }
        tgt += NB; gsync(bar, tgt);
        // ---------------- comb = relu(ctx @ wCc^T + combx[td]) ----------------
        {
            f32x4 accC[2];
            {
                f32x4 z = {0.f, 0.f, 0.f, 0.f};
                accC[0] = z; accC[1] = z;
            }
            stage1<AUX_SC>(ctx, H_DIM, wCc, H_DIM, wg * 512,
                           As2[wg][0], Ws2[wg][0], bm, bn, gt, gwv);
            __syncthreads();
            for (int i = 0; i < 8; ++i) {
                const int cur = i & 1;
                if (i + 1 < 8)
                    stage1<AUX_SC>(ctx, H_DIM, wCc, H_DIM, wg * 512 + ((i + 1) << 6),
                                   As2[wg][cur ^ 1], Ws2[wg][cur ^ 1], bm, bn, gt, gwv);
                compute1(As2[wg][cur], Ws2[wg][cur], gwv, ln, quad, accC);
                __syncthreads();
            }
            float* red = (float*)Ws2;
            const int rb = (gwv * 64 + lane) * 33;
            if (wg == 1) {
                #pragma unroll
                for (int i = 0; i < 2; i++)
                    #pragma unroll
                    for (int r = 0; r < 4; r++)
                        red[rb + i * 4 + r] = accC[i][r];
            }
            __syncthreads();
            if (wg == 0) {
                const int n = bn + gwv * 16 + ln;
                #pragma unroll
                for (int i = 0; i < 2; i++) {
                    #pragma unroll
                    for (int r = 0; r < 4; r++) {
                        const int m = bm + i * 16 + quad * 4 + r;
                        float v = accC[i][r] + red[rb + i * 4 + r]
                                + b2f(combx[(size_t)td * BATCH * H_DIM + (size_t)m * H_DIM + n]);
                        v = fmaxf(v, 0.f);
                        store_b16_sc(comb + (size_t)m * H_DIM + n, (unsigned)f2b(v));
                    }
                }
            }
        }
        tgt += NB; gsync(bar, tgt);
        // ---------------- GRU: comb@wDih (N0) + hc@wDhh (N1) ----------------
        {
            f32x4 accR[2], accZ[2], accN0[2], accN1[2];
            #pragma unroll
            for (int i = 0; i < 2; i++) {
                f32x4 z = {0.f, 0.f, 0.f, 0.f};
                accR[i] = z; accZ[i] = z; accN0[i] = z; accN1[i] = z;
            }
            auto stgd = [&](int i, int buf) {
                if (i < 8)
                    stage3<AUX_SC>(comb, H_DIM, wDih, H_DIM, wg * 512 + (i << 6),
                                   As2[wg][buf], Ws2[wg][buf], bm, bn, gt, gwv);
                else
                    stage3<AUX_SC>(hc, H_DIM, wDhh, H_DIM, wg * 512 + ((i - 8) << 6),
                                   As2[wg][buf], Ws2[wg][buf], bm, bn, gt, gwv);
            };
            stgd(0, 0);
            __syncthreads();
            for (int i = 0; i < 16; ++i) {
                const int cur = i & 1;
                if (i + 1 < 16) stgd(i + 1, cur ^ 1);
                if (i < 8)
                    compute3(As2[wg][cur], Ws2[wg][cur], gwv, ln, quad, accR, accZ, accN0);
                else
                    compute3(As2[wg][cur], Ws2[wg][cur], gwv, ln, quad, accR, accZ, accN1);
                __syncthreads();
            }
            gru_finish(accR, accZ, accN0, accN1, (float*)Ws2, wg, gwv, lane, ln,
                       quad, bm, bn, bih, bhh, h, hb[(td + 1) & 1], nullptr);
        }
        if (td < T_LEN - 2) { tgt += NB; gsync(bar, tgt); }
    }
}

// strided fp32 -> compact bf16 weight convert, 4 elems/thread (cols % 4 == 0)
__global__ void cvt_w4(const float* __restrict__ src, int ld,
                       unsigned short* __restrict__ dst, int rows, int cols)
{
    int idx = blockIdx.x * blockDim.x + threadIdx.x;
    int total4 = rows * cols / 4;
    if (idx >= total4) return;
    int e = idx * 4;
    int r = e / cols, c = e - r * cols;
    const float* s = src + (size_t)r * ld + c;
    us4 o;
    #pragma unroll
    for (int j = 0; j < 4; j++) o[j] = f2b(s[j]);
    *(us4*)(dst + e) = o;
}

// contiguous fp32 -> bf16, 4 elems/thread
__global__ void cvt_plain4(const float* __restrict__ src,
                           unsigned short* __restrict__ dst, int total4)
{
    int idx = blockIdx.x * blockDim.x + threadIdx.x;
    if (idx >= total4) return;
    f32x4 v = *(const f32x4*)(src + (size_t)idx * 4);
    us4 o;
    #pragma unroll
    for (int j = 0; j < 4; j++) o[j] = f2b(v[j]);
    *(us4*)(dst + (size_t)idx * 4) = o;
}

// fp32 [rows, scols] -> bf16 [rows, dcols] zero-padded
__global__ void cvt_pad(const float* __restrict__ src, int scols,
                        unsigned short* __restrict__ dst, int dcols, int total)
{
    int idx = blockIdx.x * blockDim.x + threadIdx.x;
    if (idx >= total) return;
    int r = idx / dcols, c = idx - r * dcols;
    dst[idx] = (c < scols) ? f2b(src[(size_t)r * scols + c]) : (unsigned short)0;
}

// attn_W[:, H:2H] fp32 [64, ld 2048] -> wAhT bf16 [k][c]
__global__ void cvt_attT(const float* __restrict__ attn_W,
                         unsigned short* __restrict__ dst)
{
    int idx = blockIdx.x * blockDim.x + threadIdx.x;
    if (idx >= S_LEN * H_DIM) return;
    int k = idx >> 6, c = idx & 63;
    dst[idx] = f2b(attn_W[(size_t)c * 2 * H_DIM + H_DIM + k]);
}

__global__ void log_softmax1024(float* __restrict__ x)
{
    __shared__ float red[256];
    float* xr = x + (size_t)blockIdx.x * O_DIM;
    int t = threadIdx.x;
    float m = -1e30f;
    for (int i = t; i < O_DIM; i += 256) m = fmaxf(m, xr[i]);
    red[t] = m; __syncthreads();
    for (int s2 = 128; s2 > 0; s2 >>= 1) {
        if (t < s2) red[t] = fmaxf(red[t], red[t + s2]);
        __syncthreads();
    }
    m = red[0];
    __syncthreads();
    float s = 0.f;
    for (int i = t; i < O_DIM; i += 256) s += expf(xr[i] - m);
    red[t] = s; __syncthreads();
    for (int s2 = 128; s2 > 0; s2 >>= 1) {
        if (t < s2) red[t] += red[t + s2];
        __syncthreads();
    }
    float lse = m + logf(red[0]);
    __syncthreads();
    for (int i = t; i < O_DIM; i += 256) xr[i] = xr[i] - lse;
}

// ---------------------------------------------------------------------------
extern "C" void kernel_launch(void* const* d_in, const int* in_sizes, int n_in,
                              void* d_out, int out_size, void* d_ws, size_t ws_size,
                              hipStream_t stream)
{
    const float* input   = (const float*)d_in[0];   // [S,B,IN]
    const float* target  = (const float*)d_in[1];   // [T,B,H]
    const float* enc_Wih = (const float*)d_in[2];
    const float* enc_Whh = (const float*)d_in[3];
    const float* enc_bih = (const float*)d_in[4];
    const float* enc_bhh = (const float*)d_in[5];
    const float* attn_W  = (const float*)d_in[6];   // [S,2H]
    const float* attn_b  = (const float*)d_in[7];
    const float* comb_W  = (const float*)d_in[8];   // [H,2H]
    const float* comb_b  = (const float*)d_in[9];
    const float* dec_Wih = (const float*)d_in[10];
    const float* dec_Whh = (const float*)d_in[11];
    const float* dec_bih = (const float*)d_in[12];
    const float* dec_bhh = (const float*)d_in[13];
    const float* out_W   = (const float*)d_in[14];
    const float* out_b   = (const float*)d_in[15];
    float* out = (float*)d_out;                     // [B,O] fp32

    // ---- workspace layout ----
    char* p = (char*)d_ws;
    auto alloc = [&](size_t bytes) {
        char* r = p; p += (bytes + 255) & ~(size_t)255; return r;
    };
    unsigned short* wWhh  = (unsigned short*)alloc((size_t)H3 * H_DIM * 2);
    unsigned short* wDih  = (unsigned short*)alloc((size_t)H3 * H_DIM * 2);
    unsigned short* wDhh  = (unsigned short*)alloc((size_t)H3 * H_DIM * 2);
    unsigned short* wCc   = (unsigned short*)alloc((size_t)H_DIM * H_DIM * 2);
    unsigned short* wCx   = (unsigned short*)alloc((size_t)H_DIM * H_DIM * 2);
    unsigned short* wO    = (unsigned short*)alloc((size_t)O_DIM * H_DIM * 2);
    unsigned short* wAhT  = (unsigned short*)alloc((size_t)H_DIM * S_LEN * 2);
    unsigned short* wAx   = (unsigned short*)alloc((size_t)S_LEN * H_DIM * 2);
    unsigned short* wIhp  = (unsigned short*)alloc((size_t)H3 * INP * 2);
    unsigned short* xbp   = (unsigned short*)alloc((size_t)S_LEN * BATCH * INP * 2);
    unsigned short* encb  = (unsigned short*)alloc((size_t)S_LEN * BATCH * H_DIM * 2);
    unsigned short* combx = (unsigned short*)alloc((size_t)(T_LEN - 1) * BATCH * H_DIM * 2);
    unsigned short* attnx = (unsigned short*)alloc((size_t)(T_LEN - 1) * BATCH * S_LEN * 2);
    float*          h     = (float*)alloc((size_t)BATCH * H_DIM * 4);
    unsigned short* hbA   = (unsigned short*)alloc((size_t)BATCH * H_DIM * 2);
    unsigned short* hbB   = (unsigned short*)alloc((size_t)BATCH * H_DIM * 2);
    unsigned short* ctx   = (unsigned short*)alloc((size_t)BATCH * H_DIM * 2);
    unsigned short* comb  = (unsigned short*)alloc((size_t)BATCH * H_DIM * 2);
    unsigned*       bar   = (unsigned*)alloc(512);
    // targetb overlays encb: consumed (attnx/combx gemms) before encoder
    // writes encb. [32*512, 1024] bf16 = 33.5 MB inside encb's 64 MB.
    unsigned short* targetb = encb;

    const dim3 blk(256);

    hipMemsetAsync(h,   0, (size_t)BATCH * H_DIM * 4, stream);
    hipMemsetAsync(hbA, 0, (size_t)BATCH * H_DIM * 2, stream);
    hipMemsetAsync(bar, 0, 512, stream);

    // ---- one-time converts (all bf16) ----
    cvt_w4<<<(H3 * H_DIM / 4 + 255) / 256, blk, 0, stream>>>(enc_Whh, H_DIM, wWhh, H3, H_DIM);
    cvt_w4<<<(H3 * H_DIM / 4 + 255) / 256, blk, 0, stream>>>(dec_Wih, H_DIM, wDih, H3, H_DIM);
    cvt_w4<<<(H3 * H_DIM / 4 + 255) / 256, blk, 0, stream>>>(dec_Whh, H_DIM, wDhh, H3, H_DIM);
    cvt_w4<<<(H_DIM * H_DIM / 4 + 255) / 256, blk, 0, stream>>>(comb_W + H_DIM, 2 * H_DIM, wCc, H_DIM, H_DIM);
    cvt_w4<<<(H_DIM * H_DIM / 4 + 255) / 256, blk, 0, stream>>>(comb_W, 2 * H_DIM, wCx, H_DIM, H_DIM);
    cvt_w4<<<(O_DIM * H_DIM / 4 + 255) / 256, blk, 0, stream>>>(out_W, H_DIM, wO, O_DIM, H_DIM);
    cvt_w4<<<(S_LEN * H_DIM / 4 + 255) / 256, blk, 0, stream>>>(attn_W, 2 * H_DIM, wAx, S_LEN, H_DIM);
    cvt_attT<<<(S_LEN * H_DIM + 255) / 256, blk, 0, stream>>>(attn_W, wAhT);
    cvt_pad<<<((S_LEN * BATCH * INP) + 255) / 256, blk, 0, stream>>>(
        input, IN_DIM, xbp, INP, S_LEN * BATCH * INP);
    cvt_pad<<<((H3 * INP) + 255) / 256, blk, 0, stream>>>(
        enc_Wih, IN_DIM, wIhp, INP, H3 * INP);
    cvt_plain4<<<((T_LEN * BATCH * H_DIM / 4) + 255) / 256, blk, 0, stream>>>(
        target, targetb, T_LEN * BATCH * H_DIM / 4);

    const int MT = (T_LEN - 1) * BATCH;  // 15872
    // attnx = target @ attn_W[:, :H]^T + attn_b
    gemm_k<64, 64><<<dim3(1, MT / 64), blk, 0, stream>>>(
        targetb, H_DIM, wAx, H_DIM, attn_b,
        nullptr, nullptr, 0, nullptr, attnx, S_LEN, H_DIM, 1 | 32);
    // combx = target @ comb_W[:, :H]^T + comb_b  (128x128 tile, 992 blocks)
    gemm_k<128, 128><<<dim3(H_DIM / 128, MT / 128), blk, 0, stream>>>(
        targetb, H_DIM, wCx, H_DIM, comb_b,
        nullptr, nullptr, 0, nullptr, combx, H_DIM, H_DIM, 1 | 32);

    // ---------------- persistent encoder (64 steps, 1 launch) ----------------
    enc_persist<<<NB, 512, 0, stream>>>(
        xbp, wIhp, wWhh, enc_bih, enc_bhh, h, hbA, hbB, encb, bar);

    // ---------------- persistent decoder (31 steps, 1 launch) ----------------
    dec_persist<<<NB, 512, 0, stream>>>(
        wAhT, attnx, encb, combx, wCc, wDih, wDhh, dec_bih, dec_bhh,
        h, hbA, hbB, ctx, comb, bar + 64);

    // ---------------- output (final h is hbB after 31 decoder steps) --------
    gemm_k<32, 64><<<dim3(O_DIM / 64, BATCH / 32), blk, 0, stream>>>(
        hbB, H_DIM, wO, H_DIM, out_b,
        nullptr, nullptr, 0, out, nullptr, O_DIM, H_DIM, 1 | 16);
    log_softmax1024<<<BATCH, blk, 0, stream>>>(out);
}

// Round 4
// 3132.694 us; speedup vs baseline: 2.9381x; 1.8848x over previous
//
#include <hip/hip_runtime.h>
#include <hip/hip_bf16.h>
#include <math.h>

#define S_LEN 64
#define T_LEN 32
#define BATCH 512
#define IN_DIM 66
#define INP 128         // IN_DIM zero-padded to multiple of 64
#define H_DIM 1024
#define O_DIM 1024
#define H3 3072

typedef __attribute__((ext_vector_type(8))) short short8;
typedef __attribute__((ext_vector_type(4))) float f32x4;
typedef __attribute__((ext_vector_type(4))) unsigned short us4;

__device__ __forceinline__ unsigned short f2b(float f) {
    union { float f; unsigned u; } x; x.f = f;
    unsigned r = x.u + 0x7FFF + ((x.u >> 16) & 1);
    return (unsigned short)(r >> 16);
}
__device__ __forceinline__ float b2f(unsigned short s) {
    union { unsigned u; float f; } x; x.u = ((unsigned)s) << 16;
    return x.f;
}
// async global->LDS, 16B per lane; lds base must be wave-uniform
__device__ __forceinline__ void gll16(const void* g, const void* l) {
    __builtin_amdgcn_global_load_lds(
        (const __attribute__((address_space(1))) unsigned int*)g,
        (__attribute__((address_space(3))) unsigned int*)l, 16, 0, 0);
}

// ---------------------------------------------------------------------------
// MFMA GEMM, bf16: C[M,N] = A@W^T, tile TM x TN. lda/ldw mult of 8, K mult 32.
// Double-buffered: stage tile t+1 while computing tile t, ONE barrier/tile.
// flags: 1 bias, 2 add fp32, 4 add bf16, 8 relu, 16 store f32, 32 store bf16
// swz: XCD-chunked blockIdx remap (bid%8 ~ XCD): same-bn blocks co-locate on
//      one XCD so the weight slice is fetched into that L2 once, reused by
//      all bm-blocks. Supports gridDim.x == 8 (1 slice/XCD) or 16 (2 slices).
// ---------------------------------------------------------------------------
template<int TM, int TN>
__global__ __launch_bounds__(256) void gemm_k(
    const unsigned short* __restrict__ A, int lda,
    const unsigned short* __restrict__ W, int ldw,
    const float* __restrict__ bias,
    const float* __restrict__ addf, const unsigned short* __restrict__ addb,
    int ldadd,
    float* __restrict__ Cf,
    unsigned short* __restrict__ Cb, int ldc,
    int K, int flags, int swz)
{
    constexpr int IF = TM / 16;   // A frags per wave
    constexpr int JF = TN / 64;   // B frags per wave
    constexpr int NW = TN / 4;    // cols per wave
    constexpr int CA = TM * 4;    // 16B chunks in A tile
    constexpr int CW = TN * 4;
    __shared__ __align__(16) unsigned short As[2][TM * 32];
    __shared__ __align__(16) unsigned short Bs[2][TN * 32];

    int bxi = blockIdx.x, byi = blockIdx.y;
    if (swz) {
        int lin = byi * gridDim.x + bxi;
        int xcd = lin & 7, j = lin >> 3;
        if (gridDim.x == 8) { bxi = xcd;               byi = j;      }
        else                { bxi = xcd * 2 + (j & 1); byi = j >> 1; }
    }
    const int bm = byi * TM;
    const int bn = bxi * TN;
    const int t = threadIdx.x;
    const int lane = t & 63;
    const int wv = t >> 6;
    const int ln = lane & 15;
    const int quad = lane >> 4;

    f32x4 acc[IF][JF];
    #pragma unroll
    for (int i = 0; i < IF; i++)
        #pragma unroll
        for (int j = 0; j < JF; j++) {
            f32x4 z = {0.f, 0.f, 0.f, 0.f};
            acc[i][j] = z;
        }

    auto stage = [&](int buf, int k0) {
        if constexpr (CA >= 256) {
            #pragma unroll
            for (int j = 0; j < CA / 256; j++) {
                int ch = j * 256 + t;
                gll16(A + (size_t)(bm + (ch >> 2)) * lda + k0 + (ch & 3) * 8,
                      (const char*)As[buf] + (j * 4 + wv) * 1024);
            }
        } else {
            if (t < CA)
                gll16(A + (size_t)(bm + (t >> 2)) * lda + k0 + (t & 3) * 8,
                      (const char*)As[buf] + wv * 1024);
        }
        if constexpr (CW >= 256) {
            #pragma unroll
            for (int j = 0; j < CW / 256; j++) {
                int ch = j * 256 + t;
                gll16(W + (size_t)(bn + (ch >> 2)) * ldw + k0 + (ch & 3) * 8,
                      (const char*)Bs[buf] + (j * 4 + wv) * 1024);
            }
        } else {
            if (t < CW)
                gll16(W + (size_t)(bn + (t >> 2)) * ldw + k0 + (t & 3) * 8,
                      (const char*)Bs[buf] + wv * 1024);
        }
    };

    const int nt = K >> 5;
    stage(0, 0);
    __syncthreads();
    for (int i = 0; i < nt; ++i) {
        const int cur = i & 1;
        if (i + 1 < nt) stage(cur ^ 1, (i + 1) << 5);
        short8 af[IF], bf[JF];
        #pragma unroll
        for (int ii = 0; ii < IF; ii++)
            af[ii] = *(const short8*)&As[cur][(ii * 16 + ln) * 32 + quad * 8];
        #pragma unroll
        for (int j = 0; j < JF; j++)
            bf[j] = *(const short8*)&Bs[cur][(wv * NW + j * 16 + ln) * 32 + quad * 8];
        #pragma unroll
        for (int ii = 0; ii < IF; ii++)
            #pragma unroll
            for (int j = 0; j < JF; j++)
                acc[ii][j] = __builtin_amdgcn_mfma_f32_16x16x32_bf16(
                    af[ii], bf[j], acc[ii][j], 0, 0, 0);
        __syncthreads();   // drains next-tile loads; guards buffer reuse
    }

    #pragma unroll
    for (int i = 0; i < IF; i++) {
        #pragma unroll
        for (int j = 0; j < JF; j++) {
            #pragma unroll
            for (int r = 0; r < 4; r++) {
                int m = bm + i * 16 + quad * 4 + r;
                int n = bn + wv * NW + j * 16 + ln;
                float v = acc[i][j][r];
                if (flags & 1) v += bias[n];
                if (flags & 2) v += addf[(size_t)m * ldadd + n];
                if (flags & 4) v += b2f(addb[(size_t)m * ldadd + n]);
                if (flags & 8) v = fmaxf(v, 0.f);
                if (flags & 16) Cf[(size_t)m * ldc + n] = v;
                if (flags & 32) Cb[(size_t)m * ldc + n] = f2b(v);
            }
        }
    }
}

// ---------------------------------------------------------------------------
// GRU tile stage / compute, split for software pipelining.
// As_g: 2*32*32 shorts (4 KB), Ws_g: 3*2*64*32 shorts (24 KB) per buffer.
// ---------------------------------------------------------------------------
__device__ __forceinline__ void gru_stage(
    const unsigned short* __restrict__ A, int lda,
    const unsigned short* __restrict__ W, int ldw, int kb,
    unsigned short* As_g, unsigned short* Ws_g,
    int bm, int bn, int gt, int gwv)
{
    // A: 256 chunks: sub gt>>7, row (gt>>2)&31, kchunk gt&3
    {
        int s = gt >> 7, r = (gt >> 2) & 31, c = gt & 3;
        gll16(A + (size_t)(bm + r) * lda + kb + s * 32 + c * 8,
              (const char*)As_g + gwv * 1024);
    }
    // W: 1536 chunks (512/gate): ch -> gate ch>>9; ch2=ch&511: sub ch2>>8,
    // row (ch2>>2)&63, kchunk ch2&3
    #pragma unroll
    for (int j = 0; j < 6; j++) {
        int ch = j * 256 + gt;
        int g2 = ch >> 9, ch2 = ch & 511;
        int s = ch2 >> 8, r = (ch2 >> 2) & 63, c = ch2 & 3;
        gll16(W + (size_t)(g2 * H_DIM + bn + r) * ldw + kb + s * 32 + c * 8,
              (const char*)Ws_g + j * 4096 + gwv * 1024);
    }
}

__device__ __forceinline__ void gru_compute(
    const unsigned short* As_g, const unsigned short* Ws_g,
    int gwv, int ln, int quad,
    f32x4 (&accR)[2], f32x4 (&accZ)[2], f32x4 (&accN)[2])
{
    #pragma unroll
    for (int sub = 0; sub < 2; sub++) {
        short8 a[2], bw[3];
        #pragma unroll
        for (int i = 0; i < 2; i++)
            a[i] = *(const short8*)&As_g[sub * 1024 + (i * 16 + ln) * 32 + quad * 8];
        #pragma unroll
        for (int g = 0; g < 3; g++)
            bw[g] = *(const short8*)&Ws_g[g * 4096 + sub * 2048 + (gwv * 16 + ln) * 32 + quad * 8];
        #pragma unroll
        for (int i = 0; i < 2; i++) {
            accR[i] = __builtin_amdgcn_mfma_f32_16x16x32_bf16(a[i], bw[0], accR[i], 0, 0, 0);
            accZ[i] = __builtin_amdgcn_mfma_f32_16x16x32_bf16(a[i], bw[1], accZ[i], 0, 0, 0);
            accN[i] = __builtin_amdgcn_mfma_f32_16x16x32_bf16(a[i], bw[2], accN[i], 0, 0, 0);
        }
    }
}

// ---------------------------------------------------------------------------
// Fused GRU step, 512 threads: two 4-wave groups K-split the GEMMs
// (group g: k in [g*K/2, (g+1)*K/2) of both phases). Double-buffered LDS:
// tile t+1 staged while tile t computes, one barrier per tile.
// Tile 32 batch x 64 gate cols; grid 256 blocks, XCD-chunked mapping:
// xcd = lin%8 gets bn slices {2*xcd, 2*xcd+1} only -> weight slices L2-resident.
// K0 must be a multiple of 128; phase-1 K fixed at 1024.
// ---------------------------------------------------------------------------
__global__ __launch_bounds__(512) void gru_gemm(
    const unsigned short* __restrict__ A0, int lda0,
    const unsigned short* __restrict__ W0, int ldw0, int K0,
    const unsigned short* __restrict__ A1,   // hb_in [512,1024]
    const unsigned short* __restrict__ W1,   // Whh   [3072,1024]
    const float* __restrict__ bih, const float* __restrict__ bhh,
    const float* __restrict__ hf_in, float* __restrict__ hf_out,
    unsigned short* __restrict__ hb_out, unsigned short* __restrict__ slot)
{
    __shared__ __align__(16) unsigned short As2[2][2][2 * 32 * 32];      // 16 KB
    __shared__ __align__(16) unsigned short Ws2[2][2][3 * 2 * 64 * 32];  // 96 KB
    const int lin = blockIdx.y * gridDim.x + blockIdx.x;
    const int xcd = lin & 7, j = lin >> 3;
    const int bn = (xcd * 2 + (j & 1)) * 64;
    const int bm = (j >> 1) * 32;
    const int t = threadIdx.x;            // 0..511
    const int wg = t >> 8;                // wave-group
    const int gt = t & 255;
    const int lane = t & 63;
    const int gwv = gt >> 6;              // wave within group
    const int ln = lane & 15;
    const int quad = lane >> 4;

    f32x4 accR[2], accZ[2], accN0[2], accN1[2];
    #pragma unroll
    for (int i = 0; i < 2; i++) {
        f32x4 z = {0.f, 0.f, 0.f, 0.f};
        accR[i] = z; accZ[i] = z; accN0[i] = z; accN1[i] = z;
    }

    const int half0 = K0 >> 1;            // multiple of 64
    const int nt0 = half0 >> 6;           // phase-0 tiles per group
    const int nt = nt0 + 8;               // + phase-1 tiles (512/64)

    auto stg = [&](int i, int buf) {
        const unsigned short* A; int lda; const unsigned short* W; int ldw; int kb;
        if (i < nt0) { A = A0; lda = lda0; W = W0; ldw = ldw0; kb = wg * half0 + (i << 6); }
        else         { A = A1; lda = H_DIM; W = W1; ldw = H_DIM; kb = wg * 512 + ((i - nt0) << 6); }
        gru_stage(A, lda, W, ldw, kb, As2[wg][buf], Ws2[wg][buf], bm, bn, gt, gwv);
    };

    stg(0, 0);
    __syncthreads();
    for (int i = 0; i < nt; ++i) {
        const int cur = i & 1;
        if (i + 1 < nt) stg(i + 1, cur ^ 1);
        if (i < nt0)
            gru_compute(As2[wg][cur], Ws2[wg][cur], gwv, ln, quad, accR, accZ, accN0);
        else
            gru_compute(As2[wg][cur], Ws2[wg][cur], gwv, ln, quad, accR, accZ, accN1);
        __syncthreads();
    }

    // ---- cross-group reduction (stride 33 floats: conflict-free) ----
    float* red = (float*)Ws2;             // 96 KB scratch, needs 33.8 KB
    const int rb = (gwv * 64 + lane) * 33;
    if (wg == 1) {
        #pragma unroll
        for (int i = 0; i < 2; i++)
            #pragma unroll
            for (int r = 0; r < 4; r++) {
                red[rb + i * 4 + r]      = accR[i][r];
                red[rb + 8 + i * 4 + r]  = accZ[i][r];
                red[rb + 16 + i * 4 + r] = accN0[i][r];
                red[rb + 24 + i * 4 + r] = accN1[i][r];
            }
    }
    __syncthreads();
    if (wg == 0) {
        #pragma unroll
        for (int i = 0; i < 2; i++)
            #pragma unroll
            for (int r = 0; r < 4; r++) {
                accR[i][r]  += red[rb + i * 4 + r];
                accZ[i][r]  += red[rb + 8 + i * 4 + r];
                accN0[i][r] += red[rb + 16 + i * 4 + r];
                accN1[i][r] += red[rb + 24 + i * 4 + r];
            }
        const int n = bn + gwv * 16 + ln;
        const float br = bih[n] + bhh[n];
        const float bz = bih[H_DIM + n] + bhh[H_DIM + n];
        const float bi_n = bih[2 * H_DIM + n];
        const float bh_n = bhh[2 * H_DIM + n];
        #pragma unroll
        for (int i = 0; i < 2; i++) {
            #pragma unroll
            for (int r = 0; r < 4; r++) {
                const int m = bm + i * 16 + quad * 4 + r;
                const size_t idx = (size_t)m * H_DIM + n;
                float rg = 1.f / (1.f + __expf(-(accR[i][r] + br)));
                float zg = 1.f / (1.f + __expf(-(accZ[i][r] + bz)));
                float av = accN0[i][r] + bi_n + rg * (accN1[i][r] + bh_n);
                float e2 = __expf(-2.f * fabsf(av));
                float th = (1.f - e2) / (1.f + e2);
                th = av < 0.f ? -th : th;
                float o = (1.f - zg) * th + zg * hf_in[idx];
                hf_out[idx] = o;
                unsigned short ob = f2b(o);
                hb_out[idx] = ob;
                if (slot) slot[idx] = ob;
            }
        }
    }
}

// ---------------------------------------------------------------------------
// Fused attention: one block per batch row. scores = h.wAhT + attnx (bf16),
// softmax over 64, then ctx[b,:] = sum_l aw[l] * enc[l,b,:]. 512 blocks.
// ---------------------------------------------------------------------------
__global__ __launch_bounds__(256) void attn_ctx(
    const unsigned short* __restrict__ hb,     // [512,1024] bf16
    const unsigned short* __restrict__ wAhT,   // [1024][64] bf16 (k-major)
    const unsigned short* __restrict__ attnx_t,// [512,64] bf16 (incl bias)
    const unsigned short* __restrict__ encb,   // [64,512,1024] bf16
    unsigned short* __restrict__ ctx)          // [512,1024] bf16
{
    __shared__ float hf[H_DIM];
    __shared__ float part[4][S_LEN];
    __shared__ float awl[S_LEN];
    const int b = blockIdx.x, t = threadIdx.x;
    {
        us4 u = *(const us4*)(hb + ((size_t)b << 10) + t * 4);
        #pragma unroll
        for (int j = 0; j < 4; j++) hf[t * 4 + j] = b2f(u[j]);
    }
    __syncthreads();
    {
        const int c = t & 63, ks = (t >> 6) * 256;
        float s = 0.f;
        #pragma unroll 8
        for (int k = 0; k < 256; k++)
            s += hf[ks + k] * b2f(wAhT[(size_t)(ks + k) * S_LEN + c]);
        part[t >> 6][c] = s;
    }
    __syncthreads();
    if (t < 64) {
        float v = part[0][t] + part[1][t] + part[2][t] + part[3][t]
                + b2f(attnx_t[b * S_LEN + t]);
        float m = v;
        #pragma unroll
        for (int off = 32; off; off >>= 1) m = fmaxf(m, __shfl_xor(m, off));
        float e = __expf(v - m);
        float ss = e;
        #pragma unroll
        for (int off = 32; off; off >>= 1) ss += __shfl_xor(ss, off);
        awl[t] = e / ss;
    }
    __syncthreads();
    const int hq = t * 4;
    float s0 = 0.f, s1 = 0.f, s2 = 0.f, s3 = 0.f;
    #pragma unroll 4
    for (int l = 0; l < S_LEN; l++) {
        us4 u = *(const us4*)(encb + (((size_t)l * BATCH + b) << 10) + hq);
        float w = awl[l];
        s0 += w * b2f(u[0]); s1 += w * b2f(u[1]);
        s2 += w * b2f(u[2]); s3 += w * b2f(u[3]);
    }
    us4 o; o[0] = f2b(s0); o[1] = f2b(s1); o[2] = f2b(s2); o[3] = f2b(s3);
    *(us4*)(ctx + ((size_t)b << 10) + hq) = o;
}

// strided fp32 -> compact bf16 weight convert, 4 elems/thread (cols % 4 == 0)
__global__ void cvt_w4(const float* __restrict__ src, int ld,
                       unsigned short* __restrict__ dst, int rows, int cols)
{
    int idx = blockIdx.x * blockDim.x + threadIdx.x;
    int total4 = rows * cols / 4;
    if (idx >= total4) return;
    int e = idx * 4;
    int r = e / cols, c = e - r * cols;
    const float* s = src + (size_t)r * ld + c;
    us4 o;
    #pragma unroll
    for (int j = 0; j < 4; j++) o[j] = f2b(s[j]);
    *(us4*)(dst + e) = o;
}

// contiguous fp32 -> bf16, 4 elems/thread
__global__ void cvt_plain4(const float* __restrict__ src,
                           unsigned short* __restrict__ dst, int total4)
{
    int idx = blockIdx.x * blockDim.x + threadIdx.x;
    if (idx >= total4) return;
    f32x4 v = *(const f32x4*)(src + (size_t)idx * 4);
    us4 o;
    #pragma unroll
    for (int j = 0; j < 4; j++) o[j] = f2b(v[j]);
    *(us4*)(dst + (size_t)idx * 4) = o;
}

// fp32 [rows, scols] -> bf16 [rows, dcols] zero-padded
__global__ void cvt_pad(const float* __restrict__ src, int scols,
                        unsigned short* __restrict__ dst, int dcols, int total)
{
    int idx = blockIdx.x * blockDim.x + threadIdx.x;
    if (idx >= total) return;
    int r = idx / dcols, c = idx - r * dcols;
    dst[idx] = (c < scols) ? f2b(src[(size_t)r * scols + c]) : (unsigned short)0;
}

// attn_W[:, H:2H] fp32 [64, ld 2048] -> wAhT bf16 [k][c]
__global__ void cvt_attT(const float* __restrict__ attn_W,
                         unsigned short* __restrict__ dst)
{
    int idx = blockIdx.x * blockDim.x + threadIdx.x;
    if (idx >= S_LEN * H_DIM) return;
    int k = idx >> 6, c = idx & 63;
    dst[idx] = f2b(attn_W[(size_t)c * 2 * H_DIM + H_DIM + k]);
}

__global__ void log_softmax1024(float* __restrict__ x)
{
    __shared__ float red[256];
    float* xr = x + (size_t)blockIdx.x * O_DIM;
    int t = threadIdx.x;
    float m = -1e30f;
    for (int i = t; i < O_DIM; i += 256) m = fmaxf(m, xr[i]);
    red[t] = m; __syncthreads();
    for (int s2 = 128; s2 > 0; s2 >>= 1) {
        if (t < s2) red[t] = fmaxf(red[t], red[t + s2]);
        __syncthreads();
    }
    m = red[0];
    __syncthreads();
    float s = 0.f;
    for (int i = t; i < O_DIM; i += 256) s += expf(xr[i] - m);
    red[t] = s; __syncthreads();
    for (int s2 = 128; s2 > 0; s2 >>= 1) {
        if (t < s2) red[t] += red[t + s2];
        __syncthreads();
    }
    float lse = m + logf(red[0]);
    __syncthreads();
    for (int i = t; i < O_DIM; i += 256) xr[i] = xr[i] - lse;
}

// ---------------------------------------------------------------------------
extern "C" void kernel_launch(void* const* d_in, const int* in_sizes, int n_in,
                              void* d_out, int out_size, void* d_ws, size_t ws_size,
                              hipStream_t stream)
{
    const float* input   = (const float*)d_in[0];   // [S,B,IN]
    const float* target  = (const float*)d_in[1];   // [T,B,H]
    const float* enc_Wih = (const float*)d_in[2];
    const float* enc_Whh = (const float*)d_in[3];
    const float* enc_bih = (const float*)d_in[4];
    const float* enc_bhh = (const float*)d_in[5];
    const float* attn_W  = (const float*)d_in[6];   // [S,2H]
    const float* attn_b  = (const float*)d_in[7];
    const float* comb_W  = (const float*)d_in[8];   // [H,2H]
    const float* comb_b  = (const float*)d_in[9];
    const float* dec_Wih = (const float*)d_in[10];
    const float* dec_Whh = (const float*)d_in[11];
    const float* dec_bih = (const float*)d_in[12];
    const float* dec_bhh = (const float*)d_in[13];
    const float* out_W   = (const float*)d_in[14];
    const float* out_b   = (const float*)d_in[15];
    float* out = (float*)d_out;                     // [B,O] fp32

    // ---- workspace layout ----
    char* p = (char*)d_ws;
    auto alloc = [&](size_t bytes) {
        char* r = p; p += (bytes + 255) & ~(size_t)255; return r;
    };
    unsigned short* wWhh  = (unsigned short*)alloc((size_t)H3 * H_DIM * 2);
    unsigned short* wDih  = (unsigned short*)alloc((size_t)H3 * H_DIM * 2);
    unsigned short* wDhh  = (unsigned short*)alloc((size_t)H3 * H_DIM * 2);
    unsigned short* wCc   = (unsigned short*)alloc((size_t)H_DIM * H_DIM * 2);
    unsigned short* wCx   = (unsigned short*)alloc((size_t)H_DIM * H_DIM * 2);
    unsigned short* wO    = (unsigned short*)alloc((size_t)O_DIM * H_DIM * 2);
    unsigned short* wAhT  = (unsigned short*)alloc((size_t)H_DIM * S_LEN * 2);
    unsigned short* wAx   = (unsigned short*)alloc((size_t)S_LEN * H_DIM * 2);
    unsigned short* wIhp  = (unsigned short*)alloc((size_t)H3 * INP * 2);
    unsigned short* xbp   = (unsigned short*)alloc((size_t)S_LEN * BATCH * INP * 2);
    unsigned short* encb  = (unsigned short*)alloc((size_t)S_LEN * BATCH * H_DIM * 2);
    unsigned short* combx = (unsigned short*)alloc((size_t)(T_LEN - 1) * BATCH * H_DIM * 2);
    unsigned short* attnx = (unsigned short*)alloc((size_t)(T_LEN - 1) * BATCH * S_LEN * 2);
    float*          h     = (float*)alloc((size_t)BATCH * H_DIM * 4);
    unsigned short* hbA   = (unsigned short*)alloc((size_t)BATCH * H_DIM * 2);
    unsigned short* hbB   = (unsigned short*)alloc((size_t)BATCH * H_DIM * 2);
    unsigned short* ctx   = (unsigned short*)alloc((size_t)BATCH * H_DIM * 2);
    unsigned short* comb  = (unsigned short*)alloc((size_t)BATCH * H_DIM * 2);
    // targetb overlays encb: consumed (attnx/combx gemms) before encoder
    // writes encb. [32*512, 1024] bf16 = 33.5 MB inside encb's 64 MB.
    unsigned short* targetb = encb;

    const dim3 blk(256);

    hipMemsetAsync(h,   0, (size_t)BATCH * H_DIM * 4, stream);
    hipMemsetAsync(hbA, 0, (size_t)BATCH * H_DIM * 2, stream);

    // ---- one-time converts (all bf16) ----
    cvt_w4<<<(H3 * H_DIM / 4 + 255) / 256, blk, 0, stream>>>(enc_Whh, H_DIM, wWhh, H3, H_DIM);
    cvt_w4<<<(H3 * H_DIM / 4 + 255) / 256, blk, 0, stream>>>(dec_Wih, H_DIM, wDih, H3, H_DIM);
    cvt_w4<<<(H3 * H_DIM / 4 + 255) / 256, blk, 0, stream>>>(dec_Whh, H_DIM, wDhh, H3, H_DIM);
    cvt_w4<<<(H_DIM * H_DIM / 4 + 255) / 256, blk, 0, stream>>>(comb_W + H_DIM, 2 * H_DIM, wCc, H_DIM, H_DIM);
    cvt_w4<<<(H_DIM * H_DIM / 4 + 255) / 256, blk, 0, stream>>>(comb_W, 2 * H_DIM, wCx, H_DIM, H_DIM);
    cvt_w4<<<(O_DIM * H_DIM / 4 + 255) / 256, blk, 0, stream>>>(out_W, H_DIM, wO, O_DIM, H_DIM);
    cvt_w4<<<(S_LEN * H_DIM / 4 + 255) / 256, blk, 0, stream>>>(attn_W, 2 * H_DIM, wAx, S_LEN, H_DIM);
    cvt_attT<<<(S_LEN * H_DIM + 255) / 256, blk, 0, stream>>>(attn_W, wAhT);
    cvt_pad<<<((S_LEN * BATCH * INP) + 255) / 256, blk, 0, stream>>>(
        input, IN_DIM, xbp, INP, S_LEN * BATCH * INP);
    cvt_pad<<<((H3 * INP) + 255) / 256, blk, 0, stream>>>(
        enc_Wih, IN_DIM, wIhp, INP, H3 * INP);
    cvt_plain4<<<((T_LEN * BATCH * H_DIM / 4) + 255) / 256, blk, 0, stream>>>(
        target, targetb, T_LEN * BATCH * H_DIM / 4);

    const int MT = (T_LEN - 1) * BATCH;  // 15872
    // attnx = target @ attn_W[:, :H]^T + attn_b
    gemm_k<64, 64><<<dim3(1, MT / 64), blk, 0, stream>>>(
        targetb, H_DIM, wAx, H_DIM, attn_b,
        nullptr, nullptr, 0, nullptr, attnx, S_LEN, H_DIM, 1 | 32, 0);
    // combx = target @ comb_W[:, :H]^T + comb_b  (128x128 tile, 992 blocks)
    // swz: grid.x==8 -> each XCD owns ONE 128-col slice of wCx (L2-resident)
    gemm_k<128, 128><<<dim3(H_DIM / 128, MT / 128), blk, 0, stream>>>(
        targetb, H_DIM, wCx, H_DIM, comb_b,
        nullptr, nullptr, 0, nullptr, combx, H_DIM, H_DIM, 1 | 32, 1);

    const dim3 grid_gru(H_DIM / 64, BATCH / 32);   // 16 x 16 = 256 blocks
    const dim3 blk512(512);
    unsigned short* hcur = hbA;
    unsigned short* hnxt = hbB;

    // ---------------- encoder: one kernel per step ----------------
    for (int s = 0; s < S_LEN; s++) {
        gru_gemm<<<grid_gru, blk512, 0, stream>>>(
            xbp + (size_t)s * BATCH * INP, INP, wIhp, INP, INP,
            hcur, wWhh, enc_bih, enc_bhh, h, h, hnxt,
            encb + (size_t)s * BATCH * H_DIM);
        unsigned short* tmp = hcur; hcur = hnxt; hnxt = tmp;
    }

    // ---------------- decoder: three kernels per step ----------------
    for (int t = 0; t < T_LEN - 1; t++) {
        attn_ctx<<<BATCH, blk, 0, stream>>>(
            hcur, wAhT, attnx + (size_t)t * BATCH * S_LEN, encb, ctx);
        gemm_k<32, 64><<<dim3(H_DIM / 64, BATCH / 32), blk, 0, stream>>>(
            ctx, H_DIM, wCc, H_DIM, nullptr,
            nullptr, combx + (size_t)t * BATCH * H_DIM, H_DIM,
            nullptr, comb, H_DIM, H_DIM, 4 | 8 | 32, 1);
        gru_gemm<<<grid_gru, blk512, 0, stream>>>(
            comb, H_DIM, wDih, H_DIM, H_DIM,
            hcur, wDhh, dec_bih, dec_bhh, h, h, hnxt, nullptr);
        unsigned short* tmp = hcur; hcur = hnxt; hnxt = tmp;
    }

    // ---------------- output ----------------
    gemm_k<32, 64><<<dim3(O_DIM / 64, BATCH / 32), blk, 0, stream>>>(
        hcur, H_DIM, wO, H_DIM, out_b,
        nullptr, nullptr, 0, out, nullptr, O_DIM, H_DIM, 1 | 16, 1);
    log_softmax1024<<<BATCH, blk, 0, stream>>>(out);
}

// Round 5
// 3104.177 us; speedup vs baseline: 2.9651x; 1.0092x over previous
//
#include <hip/hip_runtime.h>
#include <hip/hip_bf16.h>
#include <math.h>

#define S_LEN 64
#define T_LEN 32
#define BATCH 512
#define IN_DIM 66
#define INP 128         // IN_DIM zero-padded to multiple of 64
#define H_DIM 1024
#define O_DIM 1024
#define H3 3072
#define NB 256          // persistent grid size (1 block/CU, LDS-limited)
#define AUX_SC 17       // cpol sc0|sc1: device-coherent, bypass L1/L2, LLC point

typedef __attribute__((ext_vector_type(8))) short short8;
typedef __attribute__((ext_vector_type(4))) float f32x4;
typedef __attribute__((ext_vector_type(4))) unsigned short us4;

__device__ __forceinline__ unsigned short f2b(float f) {
    union { float f; unsigned u; } x; x.f = f;
    unsigned r = x.u + 0x7FFF + ((x.u >> 16) & 1);
    return (unsigned short)(r >> 16);
}
__device__ __forceinline__ float b2f(unsigned short s) {
    union { unsigned u; float f; } x; x.u = ((unsigned)s) << 16;
    return x.f;
}
// async global->LDS, 16B per lane; lds base must be wave-uniform. AUX = cpol.
template<int AUX>
__device__ __forceinline__ void gll16x(const void* g, const void* l) {
    __builtin_amdgcn_global_load_lds(
        (const __attribute__((address_space(1))) unsigned int*)g,
        (__attribute__((address_space(3))) unsigned int*)l, 16, 0, AUX);
}
__device__ __forceinline__ void gll16(const void* g, const void* l) {
    gll16x<0>(g, l);
}
// device-coherent (LLC) store for cross-block data inside a persistent kernel
__device__ __forceinline__ void store_b16_sc(unsigned short* p, unsigned v) {
    asm volatile("global_store_short %0, %1, off sc0 sc1" :: "v"(p), "v"(v) : "memory");
}

// ---- fence-free grid barrier: relaxed agent atomics; visibility carried by
// ---- sc0/sc1 data ops + the vmcnt(0) drain inside __syncthreads (r3-proven).
__device__ __forceinline__ void gbar_arrive(unsigned* bar) {
    __hip_atomic_fetch_add(bar, 1u, __ATOMIC_RELAXED, __HIP_MEMORY_SCOPE_AGENT);
}
__device__ __forceinline__ void gbar_wait(unsigned* bar, unsigned target) {
    while (__hip_atomic_load(bar, __ATOMIC_RELAXED, __HIP_MEMORY_SCOPE_AGENT) < target)
        __builtin_amdgcn_s_sleep(2);
}

// ---------------------------------------------------------------------------
// MFMA GEMM, bf16: C[M,N] = A@W^T, tile TM x TN. lda/ldw mult of 8, K mult 32.
// Double-buffered: stage tile t+1 while computing tile t, ONE barrier/tile.
// flags: 1 bias, 2 add fp32, 4 add bf16, 8 relu, 16 store f32, 32 store bf16
// ---------------------------------------------------------------------------
template<int TM, int TN>
__global__ __launch_bounds__(256) void gemm_k(
    const unsigned short* __restrict__ A, int lda,
    const unsigned short* __restrict__ W, int ldw,
    const float* __restrict__ bias,
    const float* __restrict__ addf, const unsigned short* __restrict__ addb,
    int ldadd,
    float* __restrict__ Cf,
    unsigned short* __restrict__ Cb, int ldc,
    int K, int flags)
{
    constexpr int IF = TM / 16;   // A frags per wave
    constexpr int JF = TN / 64;   // B frags per wave
    constexpr int NW = TN / 4;    // cols per wave
    constexpr int CA = TM * 4;    // 16B chunks in A tile
    constexpr int CW = TN * 4;
    __shared__ __align__(16) unsigned short As[2][TM * 32];
    __shared__ __align__(16) unsigned short Bs[2][TN * 32];

    const int bm = blockIdx.y * TM;
    const int bn = blockIdx.x * TN;
    const int t = threadIdx.x;
    const int lane = t & 63;
    const int wv = t >> 6;
    const int ln = lane & 15;
    const int quad = lane >> 4;

    f32x4 acc[IF][JF];
    #pragma unroll
    for (int i = 0; i < IF; i++)
        #pragma unroll
        for (int j = 0; j < JF; j++) {
            f32x4 z = {0.f, 0.f, 0.f, 0.f};
            acc[i][j] = z;
        }

    auto stage = [&](int buf, int k0) {
        if constexpr (CA >= 256) {
            #pragma unroll
            for (int j = 0; j < CA / 256; j++) {
                int ch = j * 256 + t;
                gll16(A + (size_t)(bm + (ch >> 2)) * lda + k0 + (ch & 3) * 8,
                      (const char*)As[buf] + (j * 4 + wv) * 1024);
            }
        } else {
            if (t < CA)
                gll16(A + (size_t)(bm + (t >> 2)) * lda + k0 + (t & 3) * 8,
                      (const char*)As[buf] + wv * 1024);
        }
        if constexpr (CW >= 256) {
            #pragma unroll
            for (int j = 0; j < CW / 256; j++) {
                int ch = j * 256 + t;
                gll16(W + (size_t)(bn + (ch >> 2)) * ldw + k0 + (ch & 3) * 8,
                      (const char*)Bs[buf] + (j * 4 + wv) * 1024);
            }
        } else {
            if (t < CW)
                gll16(W + (size_t)(bn + (t >> 2)) * ldw + k0 + (t & 3) * 8,
                      (const char*)Bs[buf] + wv * 1024);
        }
    };

    const int nt = K >> 5;
    stage(0, 0);
    __syncthreads();
    for (int i = 0; i < nt; ++i) {
        const int cur = i & 1;
        if (i + 1 < nt) stage(cur ^ 1, (i + 1) << 5);
        short8 af[IF], bf[JF];
        #pragma unroll
        for (int ii = 0; ii < IF; ii++)
            af[ii] = *(const short8*)&As[cur][(ii * 16 + ln) * 32 + quad * 8];
        #pragma unroll
        for (int j = 0; j < JF; j++)
            bf[j] = *(const short8*)&Bs[cur][(wv * NW + j * 16 + ln) * 32 + quad * 8];
        #pragma unroll
        for (int ii = 0; ii < IF; ii++)
            #pragma unroll
            for (int j = 0; j < JF; j++)
                acc[ii][j] = __builtin_amdgcn_mfma_f32_16x16x32_bf16(
                    af[ii], bf[j], acc[ii][j], 0, 0, 0);
        __syncthreads();   // drains next-tile loads; guards buffer reuse
    }

    #pragma unroll
    for (int i = 0; i < IF; i++) {
        #pragma unroll
        for (int j = 0; j < JF; j++) {
            #pragma unroll
            for (int r = 0; r < 4; r++) {
                int m = bm + i * 16 + quad * 4 + r;
                int n = bn + wv * NW + j * 16 + ln;
                float v = acc[i][j][r];
                if (flags & 1) v += bias[n];
                if (flags & 2) v += addf[(size_t)m * ldadd + n];
                if (flags & 4) v += b2f(addb[(size_t)m * ldadd + n]);
                if (flags & 8) v = fmaxf(v, 0.f);
                if (flags & 16) Cf[(size_t)m * ldc + n] = v;
                if (flags & 32) Cb[(size_t)m * ldc + n] = f2b(v);
            }
        }
    }
}

// ---------------------------------------------------------------------------
// GRU tile stage / compute. As_g: 2*32*32 shorts (4 KB), Ws_g: 3*2*64*32
// shorts (24 KB) per buffer. AAUX: cpol for A staging (AUX_SC when A was
// written by peer blocks inside the same persistent kernel).
// ---------------------------------------------------------------------------
template<int AAUX>
__device__ __forceinline__ void gru_stage(
    const unsigned short* __restrict__ A, int lda,
    const unsigned short* __restrict__ W, int ldw, int kb,
    unsigned short* As_g, unsigned short* Ws_g,
    int bm, int bn, int gt, int gwv)
{
    {
        int s = gt >> 7, r = (gt >> 2) & 31, c = gt & 3;
        gll16x<AAUX>(A + (size_t)(bm + r) * lda + kb + s * 32 + c * 8,
                     (const char*)As_g + gwv * 1024);
    }
    #pragma unroll
    for (int j = 0; j < 6; j++) {
        int ch = j * 256 + gt;
        int g2 = ch >> 9, ch2 = ch & 511;
        int s = ch2 >> 8, r = (ch2 >> 2) & 63, c = ch2 & 3;
        gll16(W + (size_t)(g2 * H_DIM + bn + r) * ldw + kb + s * 32 + c * 8,
              (const char*)Ws_g + j * 4096 + gwv * 1024);
    }
}

__device__ __forceinline__ void gru_compute(
    const unsigned short* As_g, const unsigned short* Ws_g,
    int gwv, int ln, int quad,
    f32x4 (&accR)[2], f32x4 (&accZ)[2], f32x4 (&accN)[2])
{
    #pragma unroll
    for (int sub = 0; sub < 2; sub++) {
        short8 a[2], bw[3];
        #pragma unroll
        for (int i = 0; i < 2; i++)
            a[i] = *(const short8*)&As_g[sub * 1024 + (i * 16 + ln) * 32 + quad * 8];
        #pragma unroll
        for (int g = 0; g < 3; g++)
            bw[g] = *(const short8*)&Ws_g[g * 4096 + sub * 2048 + (gwv * 16 + ln) * 32 + quad * 8];
        #pragma unroll
        for (int i = 0; i < 2; i++) {
            accR[i] = __builtin_amdgcn_mfma_f32_16x16x32_bf16(a[i], bw[0], accR[i], 0, 0, 0);
            accZ[i] = __builtin_amdgcn_mfma_f32_16x16x32_bf16(a[i], bw[1], accZ[i], 0, 0, 0);
            accN[i] = __builtin_amdgcn_mfma_f32_16x16x32_bf16(a[i], bw[2], accN[i], 0, 0, 0);
        }
    }
}

// cross-group reduction + GRU elementwise epilogue. SC: hb stores go device-
// coherent (persistent-kernel producers); else plain cached stores.
template<bool SC>
__device__ __forceinline__ void gru_finish(
    f32x4 (&accR)[2], f32x4 (&accZ)[2], f32x4 (&accN0)[2], f32x4 (&accN1)[2],
    float* red, int wg, int gwv, int lane, int ln, int quad, int bm, int bn,
    const float* __restrict__ bih, const float* __restrict__ bhh,
    const float* __restrict__ hf_in, float* __restrict__ hf_out,
    unsigned short* __restrict__ hb_out, unsigned short* __restrict__ slot)
{
    const int rb = (gwv * 64 + lane) * 33;
    if (wg == 1) {
        #pragma unroll
        for (int i = 0; i < 2; i++)
            #pragma unroll
            for (int r = 0; r < 4; r++) {
                red[rb + i * 4 + r]      = accR[i][r];
                red[rb + 8 + i * 4 + r]  = accZ[i][r];
                red[rb + 16 + i * 4 + r] = accN0[i][r];
                red[rb + 24 + i * 4 + r] = accN1[i][r];
            }
    }
    __syncthreads();
    if (wg == 0) {
        #pragma unroll
        for (int i = 0; i < 2; i++)
            #pragma unroll
            for (int r = 0; r < 4; r++) {
                accR[i][r]  += red[rb + i * 4 + r];
                accZ[i][r]  += red[rb + 8 + i * 4 + r];
                accN0[i][r] += red[rb + 16 + i * 4 + r];
                accN1[i][r] += red[rb + 24 + i * 4 + r];
            }
        const int n = bn + gwv * 16 + ln;
        const float br = bih[n] + bhh[n];
        const float bz = bih[H_DIM + n] + bhh[H_DIM + n];
        const float bi_n = bih[2 * H_DIM + n];
        const float bh_n = bhh[2 * H_DIM + n];
        #pragma unroll
        for (int i = 0; i < 2; i++) {
            #pragma unroll
            for (int r = 0; r < 4; r++) {
                const int m = bm + i * 16 + quad * 4 + r;
                const size_t idx = (size_t)m * H_DIM + n;
                float rg = 1.f / (1.f + __expf(-(accR[i][r] + br)));
                float zg = 1.f / (1.f + __expf(-(accZ[i][r] + bz)));
                float av = accN0[i][r] + bi_n + rg * (accN1[i][r] + bh_n);
                float e2 = __expf(-2.f * fabsf(av));
                float th = (1.f - e2) / (1.f + e2);
                th = av < 0.f ? -th : th;
                float o = (1.f - zg) * th + zg * hf_in[idx];
                hf_out[idx] = o;
                unsigned short ob = f2b(o);
                if (SC) store_b16_sc(hb_out + idx, (unsigned)ob);
                else    hb_out[idx] = ob;
                if (slot) slot[idx] = ob;
            }
        }
    }
}

// ---------------------------------------------------------------------------
// Persistent encoder: 64 GRU steps in one launch, fence-free grid barrier
// (r3-proven). grid = NB x 512, 1 block/CU (112 KB LDS). Per step: phase0
// (x_s@Wih, h-independent, overlaps barrier wait), wait, phase1 (h@Whh, 8
// dbuf tiles), epilogue, arrive.
// ---------------------------------------------------------------------------
__global__ __launch_bounds__(512) void enc_persist(
    const unsigned short* __restrict__ xbp,   // [64,512,INP]
    const unsigned short* __restrict__ wIhp,  // [3072,INP]
    const unsigned short* __restrict__ wWhh,  // [3072,1024]
    const float* __restrict__ bih, const float* __restrict__ bhh,
    float* __restrict__ h,                    // [512,1024] fp32 (block-private)
    unsigned short* __restrict__ hb0,
    unsigned short* __restrict__ hb1,
    unsigned short* __restrict__ encb,        // [64,512,1024]
    unsigned* __restrict__ bar)
{
    __shared__ __align__(16) unsigned short As2[2][2][2048];      // 16 KB
    __shared__ __align__(16) unsigned short Ws2[2][2][12288];     // 96 KB

    const int bid = blockIdx.x;
    const int xcd = bid & 7, sb = bid >> 3;
    const int bn = (xcd * 2 + (sb >> 4)) * 64;
    const int bm = (sb & 15) * 32;
    const int t = threadIdx.x;
    const int wg = t >> 8;
    const int gt = t & 255;
    const int lane = t & 63;
    const int gwv = gt >> 6;
    const int ln = lane & 15;
    const int quad = lane >> 4;

    unsigned short* hb[2] = {hb0, hb1};

    for (int s = 0; s < S_LEN; ++s) {
        f32x4 accR[2], accZ[2], accN0[2], accN1[2];
        #pragma unroll
        for (int i = 0; i < 2; i++) {
            f32x4 z = {0.f, 0.f, 0.f, 0.f};
            accR[i] = z; accZ[i] = z; accN0[i] = z; accN1[i] = z;
        }
        // phase0: x_s @ Wih^T (K=128, 64 per group) -> buf0; h-independent
        gru_stage<0>(xbp + (size_t)s * BATCH * INP, INP, wIhp, INP, wg * 64,
                     As2[wg][0], Ws2[wg][0], bm, bn, gt, gwv);
        __syncthreads();
        gru_compute(As2[wg][0], Ws2[wg][0], gwv, ln, quad, accR, accZ, accN0);
        // wait for h of step s (released at end of step s-1)
        if (t == 0 && s > 0) gbar_wait(bar, (unsigned)(s * NB));
        __syncthreads();
        // phase1: h @ Whh^T, 8 tiles double-buffered starting buf1
        const unsigned short* A1 = hb[s & 1];
        gru_stage<AUX_SC>(A1, H_DIM, wWhh, H_DIM, wg * 512,
                          As2[wg][1], Ws2[wg][1], bm, bn, gt, gwv);
        __syncthreads();
        for (int i = 0; i < 8; ++i) {
            const int cur = (i + 1) & 1;
            if (i + 1 < 8)
                gru_stage<AUX_SC>(A1, H_DIM, wWhh, H_DIM, wg * 512 + ((i + 1) << 6),
                                  As2[wg][cur ^ 1], Ws2[wg][cur ^ 1], bm, bn, gt, gwv);
            gru_compute(As2[wg][cur], Ws2[wg][cur], gwv, ln, quad, accR, accZ, accN1);
            __syncthreads();
        }
        gru_finish<true>(accR, accZ, accN0, accN1, (float*)Ws2, wg, gwv, lane,
                         ln, quad, bm, bn, bih, bhh, h, h, hb[(s + 1) & 1],
                         encb + (size_t)s * BATCH * H_DIM);
        __syncthreads();   // vmcnt(0) drain: sc1 stores committed to LLC
        if (t == 0 && s < S_LEN - 1) gbar_arrive(bar);
    }
}

// ---------------------------------------------------------------------------
// Multi-launch decoder GRU step (known-good r1/r4 structure).
// ---------------------------------------------------------------------------
__global__ __launch_bounds__(512) void gru_gemm(
    const unsigned short* __restrict__ A0, int lda0,
    const unsigned short* __restrict__ W0, int ldw0, int K0,
    const unsigned short* __restrict__ A1,   // hb_in [512,1024]
    const unsigned short* __restrict__ W1,   // Whh   [3072,1024]
    const float* __restrict__ bih, const float* __restrict__ bhh,
    const float* __restrict__ hf_in, float* __restrict__ hf_out,
    unsigned short* __restrict__ hb_out, unsigned short* __restrict__ slot)
{
    __shared__ __align__(16) unsigned short As2[2][2][2 * 32 * 32];      // 16 KB
    __shared__ __align__(16) unsigned short Ws2[2][2][3 * 2 * 64 * 32];  // 96 KB
    const int lin = blockIdx.y * gridDim.x + blockIdx.x;
    const int xcd = lin & 7, j = lin >> 3;
    const int bn = (xcd * 2 + (j & 1)) * 64;
    const int bm = (j >> 1) * 32;
    const int t = threadIdx.x;            // 0..511
    const int wg = t >> 8;                // wave-group
    const int gt = t & 255;
    const int lane = t & 63;
    const int gwv = gt >> 6;              // wave within group
    const int ln = lane & 15;
    const int quad = lane >> 4;

    f32x4 accR[2], accZ[2], accN0[2], accN1[2];
    #pragma unroll
    for (int i = 0; i < 2; i++) {
        f32x4 z = {0.f, 0.f, 0.f, 0.f};
        accR[i] = z; accZ[i] = z; accN0[i] = z; accN1[i] = z;
    }

    const int half0 = K0 >> 1;            // multiple of 64
    const int nt0 = half0 >> 6;           // phase-0 tiles per group
    const int nt = nt0 + 8;               // + phase-1 tiles (512/64)

    auto stg = [&](int i, int buf) {
        const unsigned short* A; int lda; const unsigned short* W; int ldw; int kb;
        if (i < nt0) { A = A0; lda = lda0; W = W0; ldw = ldw0; kb = wg * half0 + (i << 6); }
        else         { A = A1; lda = H_DIM; W = W1; ldw = H_DIM; kb = wg * 512 + ((i - nt0) << 6); }
        gru_stage<0>(A, lda, W, ldw, kb, As2[wg][buf], Ws2[wg][buf], bm, bn, gt, gwv);
    };

    stg(0, 0);
    __syncthreads();
    for (int i = 0; i < nt; ++i) {
        const int cur = i & 1;
        if (i + 1 < nt) stg(i + 1, cur ^ 1);
        if (i < nt0)
            gru_compute(As2[wg][cur], Ws2[wg][cur], gwv, ln, quad, accR, accZ, accN0);
        else
            gru_compute(As2[wg][cur], Ws2[wg][cur], gwv, ln, quad, accR, accZ, accN1);
        __syncthreads();
    }

    gru_finish<false>(accR, accZ, accN0, accN1, (float*)Ws2, wg, gwv, lane,
                      ln, quad, bm, bn, bih, bhh, hf_in, hf_out, hb_out, slot);
}

// ---------------------------------------------------------------------------
// Fused attention: one block per batch row (512 blocks).
// ---------------------------------------------------------------------------
__global__ __launch_bounds__(256) void attn_ctx(
    const unsigned short* __restrict__ hb,     // [512,1024] bf16
    const unsigned short* __restrict__ wAhT,   // [1024][64] bf16 (k-major)
    const unsigned short* __restrict__ attnx_t,// [512,64] bf16 (incl bias)
    const unsigned short* __restrict__ encb,   // [64,512,1024] bf16
    unsigned short* __restrict__ ctx)          // [512,1024] bf16
{
    __shared__ float hf[H_DIM];
    __shared__ float part[4][S_LEN];
    __shared__ float awl[S_LEN];
    const int b = blockIdx.x, t = threadIdx.x;
    {
        us4 u = *(const us4*)(hb + ((size_t)b << 10) + t * 4);
        #pragma unroll
        for (int j = 0; j < 4; j++) hf[t * 4 + j] = b2f(u[j]);
    }
    __syncthreads();
    {
        const int c = t & 63, ks = (t >> 6) * 256;
        float s = 0.f;
        #pragma unroll 8
        for (int k = 0; k < 256; k++)
            s += hf[ks + k] * b2f(wAhT[(size_t)(ks + k) * S_LEN + c]);
        part[t >> 6][c] = s;
    }
    __syncthreads();
    if (t < 64) {
        float v = part[0][t] + part[1][t] + part[2][t] + part[3][t]
                + b2f(attnx_t[b * S_LEN + t]);
        float m = v;
        #pragma unroll
        for (int off = 32; off; off >>= 1) m = fmaxf(m, __shfl_xor(m, off));
        float e = __expf(v - m);
        float ss = e;
        #pragma unroll
        for (int off = 32; off; off >>= 1) ss += __shfl_xor(ss, off);
        awl[t] = e / ss;
    }
    __syncthreads();
    const int hq = t * 4;
    float s0 = 0.f, s1 = 0.f, s2 = 0.f, s3 = 0.f;
    #pragma unroll 4
    for (int l = 0; l < S_LEN; l++) {
        us4 u = *(const us4*)(encb + (((size_t)l * BATCH + b) << 10) + hq);
        float w = awl[l];
        s0 += w * b2f(u[0]); s1 += w * b2f(u[1]);
        s2 += w * b2f(u[2]); s3 += w * b2f(u[3]);
    }
    us4 o; o[0] = f2b(s0); o[1] = f2b(s1); o[2] = f2b(s2); o[3] = f2b(s3);
    *(us4*)(ctx + ((size_t)b << 10) + hq) = o;
}

// ---------------------------------------------------------------------------
// One fused convert kernel: all fp32->bf16 weight/input preprocessing in a
// single grid-strided launch (replaces ~11 small launches). Unit = 4 elems.
// ---------------------------------------------------------------------------
__global__ __launch_bounds__(256) void cvt_all(
    const float* __restrict__ enc_Whh, const float* __restrict__ dec_Wih,
    const float* __restrict__ dec_Whh, const float* __restrict__ comb_W,
    const float* __restrict__ out_W,   const float* __restrict__ attn_W,
    const float* __restrict__ enc_Wih, const float* __restrict__ input,
    const float* __restrict__ target,
    unsigned short* __restrict__ wWhh, unsigned short* __restrict__ wDih,
    unsigned short* __restrict__ wDhh, unsigned short* __restrict__ wCc,
    unsigned short* __restrict__ wCx,  unsigned short* __restrict__ wO,
    unsigned short* __restrict__ wAx,  unsigned short* __restrict__ wAhT,
    unsigned short* __restrict__ wIhp, unsigned short* __restrict__ xbp,
    unsigned short* __restrict__ targetb)
{
    const unsigned nW = H3 * H_DIM / 4;       // 786432 (x3 plain weights)
    const unsigned nH = H_DIM * H_DIM / 4;    // 262144 (wCc, wCx, wO)
    const unsigned nA = S_LEN * H_DIM / 4;    // 16384  (wAx, wAhT)
    const unsigned nI = H3 * INP / 4;         // 98304  (wIhp pad)
    const unsigned nX = S_LEN * BATCH * INP / 4;      // 1048576 (xbp pad)
    const unsigned nT = T_LEN * BATCH * H_DIM / 4;    // 4194304 (targetb)
    const unsigned total = 3 * nW + 3 * nH + 2 * nA + nI + nX + nT;

    auto plain4 = [](const float* s, unsigned short* d, unsigned i) {
        f32x4 v = *(const f32x4*)(s + (size_t)i * 4);
        us4 o;
        #pragma unroll
        for (int j = 0; j < 4; j++) o[j] = f2b(v[j]);
        *(us4*)(d + (size_t)i * 4) = o;
    };
    auto strided4 = [](const float* s, int ld, int off, int c4s,
                       unsigned short* d, unsigned i) {
        int r = i / c4s, c4 = i - r * c4s;
        f32x4 v = *(const f32x4*)(s + (size_t)r * ld + off + c4 * 4);
        us4 o;
        #pragma unroll
        for (int j = 0; j < 4; j++) o[j] = f2b(v[j]);
        *(us4*)(d + (size_t)i * 4) = o;
    };
    auto pad4 = [](const float* s, unsigned short* d, unsigned i) {
        // dst [r][128] from src [r][66]
        int r = i >> 5, c = (i & 31) * 4;
        us4 o;
        #pragma unroll
        for (int j = 0; j < 4; j++) {
            int cc = c + j;
            o[j] = (cc < IN_DIM) ? f2b(s[(size_t)r * IN_DIM + cc]) : (unsigned short)0;
        }
        *(us4*)(d + (size_t)r * INP + c) = o;
    };

    for (unsigned q = blockIdx.x * blockDim.x + threadIdx.x; q < total;
         q += gridDim.x * blockDim.x) {
        unsigned i = q;
        if (i < nW) { plain4(enc_Whh, wWhh, i); continue; }  i -= nW;
        if (i < nW) { plain4(dec_Wih, wDih, i); continue; }  i -= nW;
        if (i < nW) { plain4(dec_Whh, wDhh, i); continue; }  i -= nW;
        if (i < nH) { strided4(comb_W, 2 * H_DIM, H_DIM, H_DIM / 4, wCc, i); continue; }  i -= nH;
        if (i < nH) { strided4(comb_W, 2 * H_DIM, 0, H_DIM / 4, wCx, i); continue; }  i -= nH;
        if (i < nH) { plain4(out_W, wO, i); continue; }  i -= nH;
        if (i < nA) { strided4(attn_W, 2 * H_DIM, 0, H_DIM / 4, wAx, i); continue; }  i -= nA;
        if (i < nA) {
            // wAhT[k][c] = attn_W[c][H + k]; 4 consecutive c per unit
            int idx = i * 4, k = idx >> 6, c = idx & 63;
            us4 o;
            #pragma unroll
            for (int j = 0; j < 4; j++)
                o[j] = f2b(attn_W[(size_t)(c + j) * 2 * H_DIM + H_DIM + k]);
            *(us4*)(wAhT + idx) = o;
            continue;
        }  i -= nA;
        if (i < nI) { pad4(enc_Wih, wIhp, i); continue; }  i -= nI;
        if (i < nX) { pad4(input, xbp, i); continue; }  i -= nX;
        plain4(target, targetb, i);
    }
}

__global__ void log_softmax1024(float* __restrict__ x)
{
    __shared__ float red[256];
    float* xr = x + (size_t)blockIdx.x * O_DIM;
    int t = threadIdx.x;
    float m = -1e30f;
    for (int i = t; i < O_DIM; i += 256) m = fmaxf(m, xr[i]);
    red[t] = m; __syncthreads();
    for (int s2 = 128; s2 > 0; s2 >>= 1) {
        if (t < s2) red[t] = fmaxf(red[t], red[t + s2]);
        __syncthreads();
    }
    m = red[0];
    __syncthreads();
    float s = 0.f;
    for (int i = t; i < O_DIM; i += 256) s += expf(xr[i] - m);
    red[t] = s; __syncthreads();
    for (int s2 = 128; s2 > 0; s2 >>= 1) {
        if (t < s2) red[t] += red[t + s2];
        __syncthreads();
    }
    float lse = m + logf(red[0]);
    __syncthreads();
    for (int i = t; i < O_DIM; i += 256) xr[i] = xr[i] - lse;
}

// ---------------------------------------------------------------------------
extern "C" void kernel_launch(void* const* d_in, const int* in_sizes, int n_in,
                              void* d_out, int out_size, void* d_ws, size_t ws_size,
                              hipStream_t stream)
{
    const float* input   = (const float*)d_in[0];   // [S,B,IN]
    const float* target  = (const float*)d_in[1];   // [T,B,H]
    const float* enc_Wih = (const float*)d_in[2];
    const float* enc_Whh = (const float*)d_in[3];
    const float* enc_bih = (const float*)d_in[4];
    const float* enc_bhh = (const float*)d_in[5];
    const float* attn_W  = (const float*)d_in[6];   // [S,2H]
    const float* attn_b  = (const float*)d_in[7];
    const float* comb_W  = (const float*)d_in[8];   // [H,2H]
    const float* comb_b  = (const float*)d_in[9];
    const float* dec_Wih = (const float*)d_in[10];
    const float* dec_Whh = (const float*)d_in[11];
    const float* dec_bih = (const float*)d_in[12];
    const float* dec_bhh = (const float*)d_in[13];
    const float* out_W   = (const float*)d_in[14];
    const float* out_b   = (const float*)d_in[15];
    float* out = (float*)d_out;                     // [B,O] fp32

    // ---- workspace layout ----
    char* p = (char*)d_ws;
    auto alloc = [&](size_t bytes) {
        char* r = p; p += (bytes + 255) & ~(size_t)255; return r;
    };
    unsigned short* wWhh  = (unsigned short*)alloc((size_t)H3 * H_DIM * 2);
    unsigned short* wDih  = (unsigned short*)alloc((size_t)H3 * H_DIM * 2);
    unsigned short* wDhh  = (unsigned short*)alloc((size_t)H3 * H_DIM * 2);
    unsigned short* wCc   = (unsigned short*)alloc((size_t)H_DIM * H_DIM * 2);
    unsigned short* wCx   = (unsigned short*)alloc((size_t)H_DIM * H_DIM * 2);
    unsigned short* wO    = (unsigned short*)alloc((size_t)O_DIM * H_DIM * 2);
    unsigned short* wAhT  = (unsigned short*)alloc((size_t)H_DIM * S_LEN * 2);
    unsigned short* wAx   = (unsigned short*)alloc((size_t)S_LEN * H_DIM * 2);
    unsigned short* wIhp  = (unsigned short*)alloc((size_t)H3 * INP * 2);
    unsigned short* xbp   = (unsigned short*)alloc((size_t)S_LEN * BATCH * INP * 2);
    unsigned short* encb  = (unsigned short*)alloc((size_t)S_LEN * BATCH * H_DIM * 2);
    unsigned short* combx = (unsigned short*)alloc((size_t)(T_LEN - 1) * BATCH * H_DIM * 2);
    unsigned short* attnx = (unsigned short*)alloc((size_t)(T_LEN - 1) * BATCH * S_LEN * 2);
    float*          h     = (float*)alloc((size_t)BATCH * H_DIM * 4);
    unsigned short* hbA   = (unsigned short*)alloc((size_t)BATCH * H_DIM * 2);
    unsigned short* hbB   = (unsigned short*)alloc((size_t)BATCH * H_DIM * 2);
    unsigned short* ctx   = (unsigned short*)alloc((size_t)BATCH * H_DIM * 2);
    unsigned short* comb  = (unsigned short*)alloc((size_t)BATCH * H_DIM * 2);
    unsigned*       bar   = (unsigned*)alloc(512);
    // targetb overlays encb: consumed (attnx/combx gemms) before encoder
    // writes encb. [32*512, 1024] bf16 = 33.5 MB inside encb's 64 MB.
    unsigned short* targetb = encb;

    const dim3 blk(256);

    hipMemsetAsync(h,   0, (size_t)BATCH * H_DIM * 4, stream);
    hipMemsetAsync(hbA, 0, (size_t)BATCH * H_DIM * 2, stream);
    hipMemsetAsync(bar, 0, 512, stream);

    // ---- one fused convert launch ----
    cvt_all<<<2048, blk, 0, stream>>>(
        enc_Whh, dec_Wih, dec_Whh, comb_W, out_W, attn_W, enc_Wih, input, target,
        wWhh, wDih, wDhh, wCc, wCx, wO, wAx, wAhT, wIhp, xbp, targetb);

    const int MT = (T_LEN - 1) * BATCH;  // 15872
    // attnx = target @ attn_W[:, :H]^T + attn_b
    gemm_k<64, 64><<<dim3(1, MT / 64), blk, 0, stream>>>(
        targetb, H_DIM, wAx, H_DIM, attn_b,
        nullptr, nullptr, 0, nullptr, attnx, S_LEN, H_DIM, 1 | 32);
    // combx = target @ comb_W[:, :H]^T + comb_b
    gemm_k<128, 128><<<dim3(H_DIM / 128, MT / 128), blk, 0, stream>>>(
        targetb, H_DIM, wCx, H_DIM, comb_b,
        nullptr, nullptr, 0, nullptr, combx, H_DIM, H_DIM, 1 | 32);

    // ---------------- persistent encoder (64 steps, 1 launch) ----------------
    enc_persist<<<NB, 512, 0, stream>>>(
        xbp, wIhp, wWhh, enc_bih, enc_bhh, h, hbA, hbB, encb, bar);
    // final encoder h: fp32 in h, bf16 in hb[(63+1)&1] = hbA

    // ---------------- decoder: three kernels per step (multi-launch) --------
    const dim3 grid_gru(H_DIM / 64, BATCH / 32);   // 256 blocks
    const dim3 blk512(512);
    unsigned short* hcur = hbA;
    unsigned short* hnxt = hbB;
    for (int t = 0; t < T_LEN - 1; t++) {
        attn_ctx<<<BATCH, blk, 0, stream>>>(
            hcur, wAhT, attnx + (size_t)t * BATCH * S_LEN, encb, ctx);
        gemm_k<32, 64><<<dim3(H_DIM / 64, BATCH / 32), blk, 0, stream>>>(
            ctx, H_DIM, wCc, H_DIM, nullptr,
            nullptr, combx + (size_t)t * BATCH * H_DIM, H_DIM,
            nullptr, comb, H_DIM, H_DIM, 4 | 8 | 32);
        gru_gemm<<<grid_gru, blk512, 0, stream>>>(
            comb, H_DIM, wDih, H_DIM, H_DIM,
            hcur, wDhh, dec_bih, dec_bhh, h, h, hnxt, nullptr);
        unsigned short* tmp = hcur; hcur = hnxt; hnxt = tmp;
    }

    // ---------------- output ----------------
    gemm_k<32, 64><<<dim3(O_DIM / 64, BATCH / 32), blk, 0, stream>>>(
        hcur, H_DIM, wO, H_DIM, out_b,
        nullptr, nullptr, 0, out, nullptr, O_DIM, H_DIM, 1 | 16);
    log_softmax1024<<<BATCH, blk, 0, stream>>>(out);
}

// Round 6
// 3002.107 us; speedup vs baseline: 3.0659x; 1.0340x over previous
//
#include <hip/hip_runtime.h>
#include <hip/hip_bf16.h>
#include <math.h>

#define S_LEN 64
#define T_LEN 32
#define BATCH 512
#define IN_DIM 66
#define INP 128         // IN_DIM zero-padded to multiple of 64
#define H_DIM 1024
#define O_DIM 1024
#define H3 3072

typedef __attribute__((ext_vector_type(8))) short short8;
typedef __attribute__((ext_vector_type(4))) float f32x4;
typedef __attribute__((ext_vector_type(4))) unsigned short us4;

__device__ __forceinline__ unsigned short f2b(float f) {
    union { float f; unsigned u; } x; x.f = f;
    unsigned r = x.u + 0x7FFF + ((x.u >> 16) & 1);
    return (unsigned short)(r >> 16);
}
__device__ __forceinline__ float b2f(unsigned short s) {
    union { unsigned u; float f; } x; x.u = ((unsigned)s) << 16;
    return x.f;
}
// async global->LDS, 16B per lane; lds base must be wave-uniform
__device__ __forceinline__ void gll16(const void* g, const void* l) {
    __builtin_amdgcn_global_load_lds(
        (const __attribute__((address_space(1))) unsigned int*)g,
        (__attribute__((address_space(3))) unsigned int*)l, 16, 0, 0);
}

// ---------------------------------------------------------------------------
// MFMA GEMM, bf16: C[M,N] = A@W^T, tile TM x TN. lda/ldw mult of 8, K mult 32.
// Double-buffered: stage tile t+1 while computing tile t, ONE barrier/tile.
// flags: 1 bias, 2 add fp32, 4 add bf16, 8 relu, 16 store f32, 32 store bf16
// ---------------------------------------------------------------------------
template<int TM, int TN>
__global__ __launch_bounds__(256) void gemm_k(
    const unsigned short* __restrict__ A, int lda,
    const unsigned short* __restrict__ W, int ldw,
    const float* __restrict__ bias,
    const float* __restrict__ addf, const unsigned short* __restrict__ addb,
    int ldadd,
    float* __restrict__ Cf,
    unsigned short* __restrict__ Cb, int ldc,
    int K, int flags)
{
    constexpr int IF = TM / 16;   // A frags per wave
    constexpr int JF = TN / 64;   // B frags per wave
    constexpr int NW = TN / 4;    // cols per wave
    constexpr int CA = TM * 4;    // 16B chunks in A tile
    constexpr int CW = TN * 4;
    __shared__ __align__(16) unsigned short As[2][TM * 32];
    __shared__ __align__(16) unsigned short Bs[2][TN * 32];

    const int bm = blockIdx.y * TM;
    const int bn = blockIdx.x * TN;
    const int t = threadIdx.x;
    const int lane = t & 63;
    const int wv = t >> 6;
    const int ln = lane & 15;
    const int quad = lane >> 4;

    f32x4 acc[IF][JF];
    #pragma unroll
    for (int i = 0; i < IF; i++)
        #pragma unroll
        for (int j = 0; j < JF; j++) {
            f32x4 z = {0.f, 0.f, 0.f, 0.f};
            acc[i][j] = z;
        }

    auto stage = [&](int buf, int k0) {
        if constexpr (CA >= 256) {
            #pragma unroll
            for (int j = 0; j < CA / 256; j++) {
                int ch = j * 256 + t;
                gll16(A + (size_t)(bm + (ch >> 2)) * lda + k0 + (ch & 3) * 8,
                      (const char*)As[buf] + (j * 4 + wv) * 1024);
            }
        } else {
            if (t < CA)
                gll16(A + (size_t)(bm + (t >> 2)) * lda + k0 + (t & 3) * 8,
                      (const char*)As[buf] + wv * 1024);
        }
        if constexpr (CW >= 256) {
            #pragma unroll
            for (int j = 0; j < CW / 256; j++) {
                int ch = j * 256 + t;
                gll16(W + (size_t)(bn + (ch >> 2)) * ldw + k0 + (ch & 3) * 8,
                      (const char*)Bs[buf] + (j * 4 + wv) * 1024);
            }
        } else {
            if (t < CW)
                gll16(W + (size_t)(bn + (t >> 2)) * ldw + k0 + (t & 3) * 8,
                      (const char*)Bs[buf] + wv * 1024);
        }
    };

    const int nt = K >> 5;
    stage(0, 0);
    __syncthreads();
    for (int i = 0; i < nt; ++i) {
        const int cur = i & 1;
        if (i + 1 < nt) stage(cur ^ 1, (i + 1) << 5);
        short8 af[IF], bf[JF];
        #pragma unroll
        for (int ii = 0; ii < IF; ii++)
            af[ii] = *(const short8*)&As[cur][(ii * 16 + ln) * 32 + quad * 8];
        #pragma unroll
        for (int j = 0; j < JF; j++)
            bf[j] = *(const short8*)&Bs[cur][(wv * NW + j * 16 + ln) * 32 + quad * 8];
        #pragma unroll
        for (int ii = 0; ii < IF; ii++)
            #pragma unroll
            for (int j = 0; j < JF; j++)
                acc[ii][j] = __builtin_amdgcn_mfma_f32_16x16x32_bf16(
                    af[ii], bf[j], acc[ii][j], 0, 0, 0);
        __syncthreads();   // drains next-tile loads; guards buffer reuse
    }

    #pragma unroll
    for (int i = 0; i < IF; i++) {
        #pragma unroll
        for (int j = 0; j < JF; j++) {
            #pragma unroll
            for (int r = 0; r < 4; r++) {
                int m = bm + i * 16 + quad * 4 + r;
                int n = bn + wv * NW + j * 16 + ln;
                float v = acc[i][j][r];
                if (flags & 1) v += bias[n];
                if (flags & 2) v += addf[(size_t)m * ldadd + n];
                if (flags & 4) v += b2f(addb[(size_t)m * ldadd + n]);
                if (flags & 8) v = fmaxf(v, 0.f);
                if (flags & 16) Cf[(size_t)m * ldc + n] = v;
                if (flags & 32) Cb[(size_t)m * ldc + n] = f2b(v);
            }
        }
    }
}

// ---------------------------------------------------------------------------
// GRU tile stage/compute for the 32x32-tile, 256-thread, 2-group K-split
// kernel. Per group (128 threads) per buffer: As_g 4 KB ([sub2][row32][k32]),
// Ws_g 12 KB ([gate3][sub2][col32][k32]). Linear chunk->LDS mapping.
// ---------------------------------------------------------------------------
__device__ __forceinline__ void gru_stage(
    const unsigned short* __restrict__ A, int lda,
    const unsigned short* __restrict__ W, int ldw, int kb,
    unsigned short* As_g, unsigned short* Ws_g,
    int bm, int bn, int gt)
{
    const int gwv = gt >> 6;
    // A: 256 chunks (2/thread): ch -> sub ch>>7, row (ch>>2)&31, kchunk ch&3
    #pragma unroll
    for (int j = 0; j < 2; j++) {
        int ch = j * 128 + gt;
        int s = ch >> 7, r = (ch >> 2) & 31, c = ch & 3;
        gll16(A + (size_t)(bm + r) * lda + kb + s * 32 + c * 8,
              (const char*)As_g + j * 2048 + gwv * 1024);
    }
    // W: 768 chunks (6/thread): ch -> gate ch>>8; ch2=ch&255: sub ch2>>7,
    // col (ch2>>2)&31, kchunk ch2&3
    #pragma unroll
    for (int j = 0; j < 6; j++) {
        int ch = j * 128 + gt;
        int g = ch >> 8, ch2 = ch & 255;
        int s = ch2 >> 7, w = (ch2 >> 2) & 31, c = ch2 & 3;
        gll16(W + (size_t)(g * H_DIM + bn + w) * ldw + kb + s * 32 + c * 8,
              (const char*)Ws_g + j * 2048 + gwv * 1024);
    }
}

__device__ __forceinline__ void gru_compute(
    const unsigned short* As_g, const unsigned short* Ws_g,
    int gwv, int ln, int quad,
    f32x4 (&accR)[2], f32x4 (&accZ)[2], f32x4 (&accN)[2])
{
    #pragma unroll
    for (int sub = 0; sub < 2; sub++) {
        short8 a[2], bw[3];
        #pragma unroll
        for (int i = 0; i < 2; i++)
            a[i] = *(const short8*)&As_g[sub * 1024 + (i * 16 + ln) * 32 + quad * 8];
        #pragma unroll
        for (int g = 0; g < 3; g++)
            bw[g] = *(const short8*)&Ws_g[g * 2048 + sub * 1024 + (gwv * 16 + ln) * 32 + quad * 8];
        #pragma unroll
        for (int i = 0; i < 2; i++) {
            accR[i] = __builtin_amdgcn_mfma_f32_16x16x32_bf16(a[i], bw[0], accR[i], 0, 0, 0);
            accZ[i] = __builtin_amdgcn_mfma_f32_16x16x32_bf16(a[i], bw[1], accZ[i], 0, 0, 0);
            accN[i] = __builtin_amdgcn_mfma_f32_16x16x32_bf16(a[i], bw[2], accN[i], 0, 0, 0);
        }
    }
}

// ---------------------------------------------------------------------------
// Fused GRU step, 256 threads (2 K-split groups x 2 waves), tile 32 batch x
// 32 gate cols, 64 KB LDS -> TWO blocks/CU (independent barrier domains: one
// block computes while the other drains its vmcnt barrier). Grid (32,16) =
// 512 blocks = 2/CU. Default dispatch co-locates same-bx blocks per XCD
// (32 % 8 == 0) -> weight slices (4 x 196 KB/XCD) stay L2-resident.
// K0 multiple of 128; phase-1 K fixed at 1024.
// ---------------------------------------------------------------------------
__global__ __launch_bounds__(256) void gru_gemm(
    const unsigned short* __restrict__ A0, int lda0,
    const unsigned short* __restrict__ W0, int ldw0, int K0,
    const unsigned short* __restrict__ A1,   // hb_in [512,1024]
    const unsigned short* __restrict__ W1,   // Whh   [3072,1024]
    const float* __restrict__ bih, const float* __restrict__ bhh,
    const float* __restrict__ hf_in, float* __restrict__ hf_out,
    unsigned short* __restrict__ hb_out, unsigned short* __restrict__ slot)
{
    __shared__ __align__(16) unsigned short As2[2][2][2048];   // 16 KB
    __shared__ __align__(16) unsigned short Ws2[2][2][6144];   // 48 KB
    const int bn = blockIdx.x * 32;
    const int bm = blockIdx.y * 32;
    const int t = threadIdx.x;            // 0..255
    const int wg = t >> 7;                // K-split group
    const int gt = t & 127;               // thread in group
    const int lane = t & 63;
    const int gwv = gt >> 6;              // wave within group (0,1)
    const int ln = lane & 15;
    const int quad = lane >> 4;

    f32x4 accR[2], accZ[2], accN0[2], accN1[2];
    #pragma unroll
    for (int i = 0; i < 2; i++) {
        f32x4 z = {0.f, 0.f, 0.f, 0.f};
        accR[i] = z; accZ[i] = z; accN0[i] = z; accN1[i] = z;
    }

    const int half0 = K0 >> 1;            // multiple of 64
    const int nt0 = half0 >> 6;           // phase-0 tiles per group
    const int nt = nt0 + 8;               // + phase-1 tiles (512/64)

    auto stg = [&](int i, int buf) {
        const unsigned short* A; int lda; const unsigned short* W; int ldw; int kb;
        if (i < nt0) { A = A0; lda = lda0; W = W0; ldw = ldw0; kb = wg * half0 + (i << 6); }
        else         { A = A1; lda = H_DIM; W = W1; ldw = H_DIM; kb = wg * 512 + ((i - nt0) << 6); }
        gru_stage(A, lda, W, ldw, kb, As2[wg][buf], Ws2[wg][buf], bm, bn, gt);
    };

    stg(0, 0);
    __syncthreads();
    for (int i = 0; i < nt; ++i) {
        const int cur = i & 1;
        if (i + 1 < nt) stg(i + 1, cur ^ 1);
        if (i < nt0)
            gru_compute(As2[wg][cur], Ws2[wg][cur], gwv, ln, quad, accR, accZ, accN0);
        else
            gru_compute(As2[wg][cur], Ws2[wg][cur], gwv, ln, quad, accR, accZ, accN1);
        __syncthreads();
    }

    // ---- cross-group reduction (stride 33 floats: conflict-free) ----
    float* red = (float*)Ws2;             // 48 KB scratch, needs ~17 KB
    const int rb = (gwv * 64 + lane) * 33;
    if (wg == 1) {
        #pragma unroll
        for (int i = 0; i < 2; i++)
            #pragma unroll
            for (int r = 0; r < 4; r++) {
                red[rb + i * 4 + r]      = accR[i][r];
                red[rb + 8 + i * 4 + r]  = accZ[i][r];
                red[rb + 16 + i * 4 + r] = accN0[i][r];
                red[rb + 24 + i * 4 + r] = accN1[i][r];
            }
    }
    __syncthreads();
    if (wg == 0) {
        #pragma unroll
        for (int i = 0; i < 2; i++)
            #pragma unroll
            for (int r = 0; r < 4; r++) {
                accR[i][r]  += red[rb + i * 4 + r];
                accZ[i][r]  += red[rb + 8 + i * 4 + r];
                accN0[i][r] += red[rb + 16 + i * 4 + r];
                accN1[i][r] += red[rb + 24 + i * 4 + r];
            }
        const int n = bn + gwv * 16 + ln;
        const float br = bih[n] + bhh[n];
        const float bz = bih[H_DIM + n] + bhh[H_DIM + n];
        const float bi_n = bih[2 * H_DIM + n];
        const float bh_n = bhh[2 * H_DIM + n];
        #pragma unroll
        for (int i = 0; i < 2; i++) {
            #pragma unroll
            for (int r = 0; r < 4; r++) {
                const int m = bm + i * 16 + quad * 4 + r;
                const size_t idx = (size_t)m * H_DIM + n;
                float rg = 1.f / (1.f + __expf(-(accR[i][r] + br)));
                float zg = 1.f / (1.f + __expf(-(accZ[i][r] + bz)));
                float av = accN0[i][r] + bi_n + rg * (accN1[i][r] + bh_n);
                float e2 = __expf(-2.f * fabsf(av));
                float th = (1.f - e2) / (1.f + e2);
                th = av < 0.f ? -th : th;
                float o = (1.f - zg) * th + zg * hf_in[idx];
                hf_out[idx] = o;
                unsigned short ob = f2b(o);
                hb_out[idx] = ob;
                if (slot) slot[idx] = ob;
            }
        }
    }
}

// ---------------------------------------------------------------------------
// Fused attention: one block per batch row (512 blocks).
// ---------------------------------------------------------------------------
__global__ __launch_bounds__(256) void attn_ctx(
    const unsigned short* __restrict__ hb,     // [512,1024] bf16
    const unsigned short* __restrict__ wAhT,   // [1024][64] bf16 (k-major)
    const unsigned short* __restrict__ attnx_t,// [512,64] bf16 (incl bias)
    const unsigned short* __restrict__ encb,   // [64,512,1024] bf16
    unsigned short* __restrict__ ctx)          // [512,1024] bf16
{
    __shared__ float hf[H_DIM];
    __shared__ float part[4][S_LEN];
    __shared__ float awl[S_LEN];
    const int b = blockIdx.x, t = threadIdx.x;
    {
        us4 u = *(const us4*)(hb + ((size_t)b << 10) + t * 4);
        #pragma unroll
        for (int j = 0; j < 4; j++) hf[t * 4 + j] = b2f(u[j]);
    }
    __syncthreads();
    {
        const int c = t & 63, ks = (t >> 6) * 256;
        float s = 0.f;
        #pragma unroll 8
        for (int k = 0; k < 256; k++)
            s += hf[ks + k] * b2f(wAhT[(size_t)(ks + k) * S_LEN + c]);
        part[t >> 6][c] = s;
    }
    __syncthreads();
    if (t < 64) {
        float v = part[0][t] + part[1][t] + part[2][t] + part[3][t]
                + b2f(attnx_t[b * S_LEN + t]);
        float m = v;
        #pragma unroll
        for (int off = 32; off; off >>= 1) m = fmaxf(m, __shfl_xor(m, off));
        float e = __expf(v - m);
        float ss = e;
        #pragma unroll
        for (int off = 32; off; off >>= 1) ss += __shfl_xor(ss, off);
        awl[t] = e / ss;
    }
    __syncthreads();
    const int hq = t * 4;
    float s0 = 0.f, s1 = 0.f, s2 = 0.f, s3 = 0.f;
    #pragma unroll 4
    for (int l = 0; l < S_LEN; l++) {
        us4 u = *(const us4*)(encb + (((size_t)l * BATCH + b) << 10) + hq);
        float w = awl[l];
        s0 += w * b2f(u[0]); s1 += w * b2f(u[1]);
        s2 += w * b2f(u[2]); s3 += w * b2f(u[3]);
    }
    us4 o; o[0] = f2b(s0); o[1] = f2b(s1); o[2] = f2b(s2); o[3] = f2b(s3);
    *(us4*)(ctx + ((size_t)b << 10) + hq) = o;
}

// ---------------------------------------------------------------------------
// One fused convert kernel: all fp32->bf16 weight/input preprocessing in a
// single grid-strided launch. Unit = 4 elems.
// ---------------------------------------------------------------------------
__global__ __launch_bounds__(256) void cvt_all(
    const float* __restrict__ enc_Whh, const float* __restrict__ dec_Wih,
    const float* __restrict__ dec_Whh, const float* __restrict__ comb_W,
    const float* __restrict__ out_W,   const float* __restrict__ attn_W,
    const float* __restrict__ enc_Wih, const float* __restrict__ input,
    const float* __restrict__ target,
    unsigned short* __restrict__ wWhh, unsigned short* __restrict__ wDih,
    unsigned short* __restrict__ wDhh, unsigned short* __restrict__ wCc,
    unsigned short* __restrict__ wCx,  unsigned short* __restrict__ wO,
    unsigned short* __restrict__ wAx,  unsigned short* __restrict__ wAhT,
    unsigned short* __restrict__ wIhp, unsigned short* __restrict__ xbp,
    unsigned short* __restrict__ targetb)
{
    const unsigned nW = H3 * H_DIM / 4;
    const unsigned nH = H_DIM * H_DIM / 4;
    const unsigned nA = S_LEN * H_DIM / 4;
    const unsigned nI = H3 * INP / 4;
    const unsigned nX = S_LEN * BATCH * INP / 4;
    const unsigned nT = T_LEN * BATCH * H_DIM / 4;
    const unsigned total = 3 * nW + 3 * nH + 2 * nA + nI + nX + nT;

    auto plain4 = [](const float* s, unsigned short* d, unsigned i) {
        f32x4 v = *(const f32x4*)(s + (size_t)i * 4);
        us4 o;
        #pragma unroll
        for (int j = 0; j < 4; j++) o[j] = f2b(v[j]);
        *(us4*)(d + (size_t)i * 4) = o;
    };
    auto strided4 = [](const float* s, int ld, int off, int c4s,
                       unsigned short* d, unsigned i) {
        int r = i / c4s, c4 = i - r * c4s;
        f32x4 v = *(const f32x4*)(s + (size_t)r * ld + off + c4 * 4);
        us4 o;
        #pragma unroll
        for (int j = 0; j < 4; j++) o[j] = f2b(v[j]);
        *(us4*)(d + (size_t)i * 4) = o;
    };
    auto pad4 = [](const float* s, unsigned short* d, unsigned i) {
        int r = i >> 5, c = (i & 31) * 4;
        us4 o;
        #pragma unroll
        for (int j = 0; j < 4; j++) {
            int cc = c + j;
            o[j] = (cc < IN_DIM) ? f2b(s[(size_t)r * IN_DIM + cc]) : (unsigned short)0;
        }
        *(us4*)(d + (size_t)r * INP + c) = o;
    };

    for (unsigned q = blockIdx.x * blockDim.x + threadIdx.x; q < total;
         q += gridDim.x * blockDim.x) {
        unsigned i = q;
        if (i < nW) { plain4(enc_Whh, wWhh, i); continue; }  i -= nW;
        if (i < nW) { plain4(dec_Wih, wDih, i); continue; }  i -= nW;
        if (i < nW) { plain4(dec_Whh, wDhh, i); continue; }  i -= nW;
        if (i < nH) { strided4(comb_W, 2 * H_DIM, H_DIM, H_DIM / 4, wCc, i); continue; }  i -= nH;
        if (i < nH) { strided4(comb_W, 2 * H_DIM, 0, H_DIM / 4, wCx, i); continue; }  i -= nH;
        if (i < nH) { plain4(out_W, wO, i); continue; }  i -= nH;
        if (i < nA) { strided4(attn_W, 2 * H_DIM, 0, H_DIM / 4, wAx, i); continue; }  i -= nA;
        if (i < nA) {
            int idx = i * 4, k = idx >> 6, c = idx & 63;
            us4 o;
            #pragma unroll
            for (int j = 0; j < 4; j++)
                o[j] = f2b(attn_W[(size_t)(c + j) * 2 * H_DIM + H_DIM + k]);
            *(us4*)(wAhT + idx) = o;
            continue;
        }  i -= nA;
        if (i < nI) { pad4(enc_Wih, wIhp, i); continue; }  i -= nI;
        if (i < nX) { pad4(input, xbp, i); continue; }  i -= nX;
        plain4(target, targetb, i);
    }
}

__global__ void log_softmax1024(float* __restrict__ x)
{
    __shared__ float red[256];
    float* xr = x + (size_t)blockIdx.x * O_DIM;
    int t = threadIdx.x;
    float m = -1e30f;
    for (int i = t; i < O_DIM; i += 256) m = fmaxf(m, xr[i]);
    red[t] = m; __syncthreads();
    for (int s2 = 128; s2 > 0; s2 >>= 1) {
        if (t < s2) red[t] = fmaxf(red[t], red[t + s2]);
        __syncthreads();
    }
    m = red[0];
    __syncthreads();
    float s = 0.f;
    for (int i = t; i < O_DIM; i += 256) s += expf(xr[i] - m);
    red[t] = s; __syncthreads();
    for (int s2 = 128; s2 > 0; s2 >>= 1) {
        if (t < s2) red[t] += red[t + s2];
        __syncthreads();
    }
    float lse = m + logf(red[0]);
    __syncthreads();
    for (int i = t; i < O_DIM; i += 256) xr[i] = xr[i] - lse;
}

// ---------------------------------------------------------------------------
extern "C" void kernel_launch(void* const* d_in, const int* in_sizes, int n_in,
                              void* d_out, int out_size, void* d_ws, size_t ws_size,
                              hipStream_t stream)
{
    const float* input   = (const float*)d_in[0];   // [S,B,IN]
    const float* target  = (const float*)d_in[1];   // [T,B,H]
    const float* enc_Wih = (const float*)d_in[2];
    const float* enc_Whh = (const float*)d_in[3];
    const float* enc_bih = (const float*)d_in[4];
    const float* enc_bhh = (const float*)d_in[5];
    const float* attn_W  = (const float*)d_in[6];   // [S,2H]
    const float* attn_b  = (const float*)d_in[7];
    const float* comb_W  = (const float*)d_in[8];   // [H,2H]
    const float* comb_b  = (const float*)d_in[9];
    const float* dec_Wih = (const float*)d_in[10];
    const float* dec_Whh = (const float*)d_in[11];
    const float* dec_bih = (const float*)d_in[12];
    const float* dec_bhh = (const float*)d_in[13];
    const float* out_W   = (const float*)d_in[14];
    const float* out_b   = (const float*)d_in[15];
    float* out = (float*)d_out;                     // [B,O] fp32

    // ---- workspace layout ----
    char* p = (char*)d_ws;
    auto alloc = [&](size_t bytes) {
        char* r = p; p += (bytes + 255) & ~(size_t)255; return r;
    };
    unsigned short* wWhh  = (unsigned short*)alloc((size_t)H3 * H_DIM * 2);
    unsigned short* wDih  = (unsigned short*)alloc((size_t)H3 * H_DIM * 2);
    unsigned short* wDhh  = (unsigned short*)alloc((size_t)H3 * H_DIM * 2);
    unsigned short* wCc   = (unsigned short*)alloc((size_t)H_DIM * H_DIM * 2);
    unsigned short* wCx   = (unsigned short*)alloc((size_t)H_DIM * H_DIM * 2);
    unsigned short* wO    = (unsigned short*)alloc((size_t)O_DIM * H_DIM * 2);
    unsigned short* wAhT  = (unsigned short*)alloc((size_t)H_DIM * S_LEN * 2);
    unsigned short* wAx   = (unsigned short*)alloc((size_t)S_LEN * H_DIM * 2);
    unsigned short* wIhp  = (unsigned short*)alloc((size_t)H3 * INP * 2);
    unsigned short* xbp   = (unsigned short*)alloc((size_t)S_LEN * BATCH * INP * 2);
    unsigned short* encb  = (unsigned short*)alloc((size_t)S_LEN * BATCH * H_DIM * 2);
    unsigned short* combx = (unsigned short*)alloc((size_t)(T_LEN - 1) * BATCH * H_DIM * 2);
    unsigned short* attnx = (unsigned short*)alloc((size_t)(T_LEN - 1) * BATCH * S_LEN * 2);
    float*          h     = (float*)alloc((size_t)BATCH * H_DIM * 4);
    unsigned short* hbA   = (unsigned short*)alloc((size_t)BATCH * H_DIM * 2);
    unsigned short* hbB   = (unsigned short*)alloc((size_t)BATCH * H_DIM * 2);
    unsigned short* ctx   = (unsigned short*)alloc((size_t)BATCH * H_DIM * 2);
    unsigned short* comb  = (unsigned short*)alloc((size_t)BATCH * H_DIM * 2);
    // targetb overlays encb: consumed (attnx/combx gemms) before encoder
    // writes encb. [32*512, 1024] bf16 = 33.5 MB inside encb's 64 MB.
    unsigned short* targetb = encb;

    const dim3 blk(256);

    hipMemsetAsync(h,   0, (size_t)BATCH * H_DIM * 4, stream);
    hipMemsetAsync(hbA, 0, (size_t)BATCH * H_DIM * 2, stream);

    // ---- one fused convert launch ----
    cvt_all<<<2048, blk, 0, stream>>>(
        enc_Whh, dec_Wih, dec_Whh, comb_W, out_W, attn_W, enc_Wih, input, target,
        wWhh, wDih, wDhh, wCc, wCx, wO, wAx, wAhT, wIhp, xbp, targetb);

    const int MT = (T_LEN - 1) * BATCH;  // 15872
    // attnx = target @ attn_W[:, :H]^T + attn_b
    gemm_k<64, 64><<<dim3(1, MT / 64), blk, 0, stream>>>(
        targetb, H_DIM, wAx, H_DIM, attn_b,
        nullptr, nullptr, 0, nullptr, attnx, S_LEN, H_DIM, 1 | 32);
    // combx = target @ comb_W[:, :H]^T + comb_b
    gemm_k<128, 128><<<dim3(H_DIM / 128, MT / 128), blk, 0, stream>>>(
        targetb, H_DIM, wCx, H_DIM, comb_b,
        nullptr, nullptr, 0, nullptr, combx, H_DIM, H_DIM, 1 | 32);

    const dim3 grid_gru(H_DIM / 32, BATCH / 32);   // 32 x 16 = 512 blocks
    unsigned short* hcur = hbA;
    unsigned short* hnxt = hbB;

    // ---------------- encoder: one kernel per step ----------------
    for (int s = 0; s < S_LEN; s++) {
        gru_gemm<<<grid_gru, blk, 0, stream>>>(
            xbp + (size_t)s * BATCH * INP, INP, wIhp, INP, INP,
            hcur, wWhh, enc_bih, enc_bhh, h, h, hnxt,
            encb + (size_t)s * BATCH * H_DIM);
        unsigned short* tmp = hcur; hcur = hnxt; hnxt = tmp;
    }

    // ---------------- decoder: three kernels per step ----------------
    for (int t = 0; t < T_LEN - 1; t++) {
        attn_ctx<<<BATCH, blk, 0, stream>>>(
            hcur, wAhT, attnx + (size_t)t * BATCH * S_LEN, encb, ctx);
        gemm_k<32, 64><<<dim3(H_DIM / 64, BATCH / 32), blk, 0, stream>>>(
            ctx, H_DIM, wCc, H_DIM, nullptr,
            nullptr, combx + (size_t)t * BATCH * H_DIM, H_DIM,
            nullptr, comb, H_DIM, H_DIM, 4 | 8 | 32);
        gru_gemm<<<grid_gru, blk, 0, stream>>>(
            comb, H_DIM, wDih, H_DIM, H_DIM,
            hcur, wDhh, dec_bih, dec_bhh, h, h, hnxt, nullptr);
        unsigned short* tmp = hcur; hcur = hnxt; hnxt = tmp;
    }

    // ---------------- output ----------------
    gemm_k<32, 64><<<dim3(O_DIM / 64, BATCH / 32), blk, 0, stream>>>(
        hcur, H_DIM, wO, H_DIM, out_b,
        nullptr, nullptr, 0, out, nullptr, O_DIM, H_DIM, 1 | 16);
    log_softmax1024<<<BATCH, blk, 0, stream>>>(out);
}

// Round 7
// 2997.278 us; speedup vs baseline: 3.0709x; 1.0016x over previous
//
#include <hip/hip_runtime.h>
#include <hip/hip_bf16.h>
#include <math.h>

#define S_LEN 64
#define T_LEN 32
#define BATCH 512
#define IN_DIM 66
#define INP 128         // IN_DIM zero-padded to multiple of 64
#define H_DIM 1024
#define O_DIM 1024
#define H3 3072

typedef __attribute__((ext_vector_type(8))) short short8;
typedef __attribute__((ext_vector_type(4))) float f32x4;
typedef __attribute__((ext_vector_type(4))) unsigned short us4;

__device__ __forceinline__ unsigned short f2b(float f) {
    union { float f; unsigned u; } x; x.f = f;
    unsigned r = x.u + 0x7FFF + ((x.u >> 16) & 1);
    return (unsigned short)(r >> 16);
}
__device__ __forceinline__ float b2f(unsigned short s) {
    union { unsigned u; float f; } x; x.u = ((unsigned)s) << 16;
    return x.f;
}
// async global->LDS, 16B per lane; lds base must be wave-uniform
__device__ __forceinline__ void gll16(const void* g, const void* l) {
    __builtin_amdgcn_global_load_lds(
        (const __attribute__((address_space(1))) unsigned int*)g,
        (__attribute__((address_space(3))) unsigned int*)l, 16, 0, 0);
}
// counted vmcnt wait (T4): wait until outstanding VMEM <= N for this wave
template<int N>
__device__ __forceinline__ void vmwait() {
    if constexpr (N == 0) asm volatile("s_waitcnt vmcnt(0)" ::: "memory");
    else if constexpr (N == 2) asm volatile("s_waitcnt vmcnt(2)" ::: "memory");
    else if constexpr (N == 4) asm volatile("s_waitcnt vmcnt(4)" ::: "memory");
    else if constexpr (N == 8) asm volatile("s_waitcnt vmcnt(8)" ::: "memory");
}
__device__ __forceinline__ void sbar() { __builtin_amdgcn_s_barrier(); }
__device__ __forceinline__ void schedbar() { __builtin_amdgcn_sched_barrier(0); }

// ---------------------------------------------------------------------------
// MFMA GEMM, bf16: C[M,N] = A@W^T, tile TM x TN. lda/ldw mult of 8, K mult 32.
// PIPE path (uniform staging): counted-vmcnt pipeline -- stage(i+1) stays in
// flight across the barrier (never vmcnt(0) in loop). Legacy path otherwise.
// flags: 1 bias, 2 add fp32, 4 add bf16, 8 relu, 16 store f32, 32 store bf16
// ---------------------------------------------------------------------------
template<int TM, int TN>
__global__ __launch_bounds__(256) void gemm_k(
    const unsigned short* __restrict__ A, int lda,
    const unsigned short* __restrict__ W, int ldw,
    const float* __restrict__ bias,
    const float* __restrict__ addf, const unsigned short* __restrict__ addb,
    int ldadd,
    float* __restrict__ Cf,
    unsigned short* __restrict__ Cb, int ldc,
    int K, int flags)
{
    constexpr int IF = TM / 16;   // A frags per wave
    constexpr int JF = TN / 64;   // B frags per wave
    constexpr int NW = TN / 4;    // cols per wave
    constexpr int CA = TM * 4;    // 16B chunks in A tile
    constexpr int CW = TN * 4;
    constexpr bool PIPE = (CA >= 256) && (CW >= 256);  // uniform loads/thread
    constexpr int PT = (CA + CW) / 256;                // loads per thread per tile
    __shared__ __align__(16) unsigned short As[2][TM * 32];
    __shared__ __align__(16) unsigned short Bs[2][TN * 32];

    const int bm = blockIdx.y * TM;
    const int bn = blockIdx.x * TN;
    const int t = threadIdx.x;
    const int lane = t & 63;
    const int wv = t >> 6;
    const int ln = lane & 15;
    const int quad = lane >> 4;

    f32x4 acc[IF][JF];
    #pragma unroll
    for (int i = 0; i < IF; i++)
        #pragma unroll
        for (int j = 0; j < JF; j++) {
            f32x4 z = {0.f, 0.f, 0.f, 0.f};
            acc[i][j] = z;
        }

    auto stage = [&](int buf, int k0) {
        if constexpr (CA >= 256) {
            #pragma unroll
            for (int j = 0; j < CA / 256; j++) {
                int ch = j * 256 + t;
                gll16(A + (size_t)(bm + (ch >> 2)) * lda + k0 + (ch & 3) * 8,
                      (const char*)As[buf] + (j * 4 + wv) * 1024);
            }
        } else {
            if (t < CA)
                gll16(A + (size_t)(bm + (t >> 2)) * lda + k0 + (t & 3) * 8,
                      (const char*)As[buf] + wv * 1024);
        }
        if constexpr (CW >= 256) {
            #pragma unroll
            for (int j = 0; j < CW / 256; j++) {
                int ch = j * 256 + t;
                gll16(W + (size_t)(bn + (ch >> 2)) * ldw + k0 + (ch & 3) * 8,
                      (const char*)Bs[buf] + (j * 4 + wv) * 1024);
            }
        } else {
            if (t < CW)
                gll16(W + (size_t)(bn + (t >> 2)) * ldw + k0 + (t & 3) * 8,
                      (const char*)Bs[buf] + wv * 1024);
        }
    };

    auto comp = [&](int cur) {
        short8 af[IF], bf[JF];
        #pragma unroll
        for (int ii = 0; ii < IF; ii++)
            af[ii] = *(const short8*)&As[cur][(ii * 16 + ln) * 32 + quad * 8];
        #pragma unroll
        for (int j = 0; j < JF; j++)
            bf[j] = *(const short8*)&Bs[cur][(wv * NW + j * 16 + ln) * 32 + quad * 8];
        #pragma unroll
        for (int ii = 0; ii < IF; ii++)
            #pragma unroll
            for (int j = 0; j < JF; j++)
                acc[ii][j] = __builtin_amdgcn_mfma_f32_16x16x32_bf16(
                    af[ii], bf[j], acc[ii][j], 0, 0, 0);
    };

    const int nt = K >> 5;
    if constexpr (PIPE) {
        stage(0, 0);
        for (int i = 0; i < nt; ++i) {
            const int cur = i & 1;
            if (i + 1 < nt) { stage(cur ^ 1, (i + 1) << 5); vmwait<PT>(); }
            else            { vmwait<0>(); }
            schedbar();
            sbar();               // all waves: tile i complete in LDS
            schedbar();
            comp(cur);
            schedbar();
            sbar();               // all waves done computing tile i (buf reusable)
        }
    } else {
        stage(0, 0);
        __syncthreads();
        for (int i = 0; i < nt; ++i) {
            const int cur = i & 1;
            if (i + 1 < nt) stage(cur ^ 1, (i + 1) << 5);
            comp(cur);
            __syncthreads();
        }
    }

    #pragma unroll
    for (int i = 0; i < IF; i++) {
        #pragma unroll
        for (int j = 0; j < JF; j++) {
            #pragma unroll
            for (int r = 0; r < 4; r++) {
                int m = bm + i * 16 + quad * 4 + r;
                int n = bn + wv * NW + j * 16 + ln;
                float v = acc[i][j][r];
                if (flags & 1) v += bias[n];
                if (flags & 2) v += addf[(size_t)m * ldadd + n];
                if (flags & 4) v += b2f(addb[(size_t)m * ldadd + n]);
                if (flags & 8) v = fmaxf(v, 0.f);
                if (flags & 16) Cf[(size_t)m * ldc + n] = v;
                if (flags & 32) Cb[(size_t)m * ldc + n] = f2b(v);
            }
        }
    }
}

// ---------------------------------------------------------------------------
// GRU tile stage/compute for the 32x32-tile, 256-thread, 2-group K-split
// kernel. Per group (128 threads) per buffer: As_g 4 KB, Ws_g 12 KB.
// Uniform 8 gll16 per thread per tile (2 A + 6 W) -> counted vmcnt sound.
// ---------------------------------------------------------------------------
__device__ __forceinline__ void gru_stage(
    const unsigned short* __restrict__ A, int lda,
    const unsigned short* __restrict__ W, int ldw, int kb,
    unsigned short* As_g, unsigned short* Ws_g,
    int bm, int bn, int gt)
{
    const int gwv = gt >> 6;
    #pragma unroll
    for (int j = 0; j < 2; j++) {
        int ch = j * 128 + gt;
        int s = ch >> 7, r = (ch >> 2) & 31, c = ch & 3;
        gll16(A + (size_t)(bm + r) * lda + kb + s * 32 + c * 8,
              (const char*)As_g + j * 2048 + gwv * 1024);
    }
    #pragma unroll
    for (int j = 0; j < 6; j++) {
        int ch = j * 128 + gt;
        int g = ch >> 8, ch2 = ch & 255;
        int s = ch2 >> 7, w = (ch2 >> 2) & 31, c = ch2 & 3;
        gll16(W + (size_t)(g * H_DIM + bn + w) * ldw + kb + s * 32 + c * 8,
              (const char*)Ws_g + j * 2048 + gwv * 1024);
    }
}

__device__ __forceinline__ void gru_compute(
    const unsigned short* As_g, const unsigned short* Ws_g,
    int gwv, int ln, int quad,
    f32x4 (&accR)[2], f32x4 (&accZ)[2], f32x4 (&accN)[2])
{
    #pragma unroll
    for (int sub = 0; sub < 2; sub++) {
        short8 a[2], bw[3];
        #pragma unroll
        for (int i = 0; i < 2; i++)
            a[i] = *(const short8*)&As_g[sub * 1024 + (i * 16 + ln) * 32 + quad * 8];
        #pragma unroll
        for (int g = 0; g < 3; g++)
            bw[g] = *(const short8*)&Ws_g[g * 2048 + sub * 1024 + (gwv * 16 + ln) * 32 + quad * 8];
        #pragma unroll
        for (int i = 0; i < 2; i++) {
            accR[i] = __builtin_amdgcn_mfma_f32_16x16x32_bf16(a[i], bw[0], accR[i], 0, 0, 0);
            accZ[i] = __builtin_amdgcn_mfma_f32_16x16x32_bf16(a[i], bw[1], accZ[i], 0, 0, 0);
            accN[i] = __builtin_amdgcn_mfma_f32_16x16x32_bf16(a[i], bw[2], accN[i], 0, 0, 0);
        }
    }
}

// ---------------------------------------------------------------------------
// Fused GRU step, 256 threads (2 K-split groups x 2 waves), tile 32x32,
// 64 KB LDS -> 2 blocks/CU. Counted-vmcnt pipeline (T4): prefetch tile i+1
// stays in flight across the barriers; per-wave vmwait<8> covers its own 8
// loads of tile i, barrier 1 makes that block-wide, barrier 2 guards buffer
// reuse (stage(i+2) overwrites buf only after all waves computed tile i).
// Grid (32,16) = 512 blocks. K0 multiple of 128; phase-1 K fixed at 1024.
// ---------------------------------------------------------------------------
__global__ __launch_bounds__(256) void gru_gemm(
    const unsigned short* __restrict__ A0, int lda0,
    const unsigned short* __restrict__ W0, int ldw0, int K0,
    const unsigned short* __restrict__ A1,   // hb_in [512,1024]
    const unsigned short* __restrict__ W1,   // Whh   [3072,1024]
    const float* __restrict__ bih, const float* __restrict__ bhh,
    const float* __restrict__ hf_in, float* __restrict__ hf_out,
    unsigned short* __restrict__ hb_out, unsigned short* __restrict__ slot)
{
    __shared__ __align__(16) unsigned short As2[2][2][2048];   // 16 KB
    __shared__ __align__(16) unsigned short Ws2[2][2][6144];   // 48 KB
    const int bn = blockIdx.x * 32;
    const int bm = blockIdx.y * 32;
    const int t = threadIdx.x;            // 0..255
    const int wg = t >> 7;                // K-split group
    const int gt = t & 127;               // thread in group
    const int lane = t & 63;
    const int gwv = gt >> 6;              // wave within group (0,1)
    const int ln = lane & 15;
    const int quad = lane >> 4;

    f32x4 accR[2], accZ[2], accN0[2], accN1[2];
    #pragma unroll
    for (int i = 0; i < 2; i++) {
        f32x4 z = {0.f, 0.f, 0.f, 0.f};
        accR[i] = z; accZ[i] = z; accN0[i] = z; accN1[i] = z;
    }

    const int half0 = K0 >> 1;            // multiple of 64
    const int nt0 = half0 >> 6;           // phase-0 tiles per group
    const int nt = nt0 + 8;               // + phase-1 tiles (512/64)

    auto stg = [&](int i, int buf) {
        const unsigned short* A; int lda; const unsigned short* W; int ldw; int kb;
        if (i < nt0) { A = A0; lda = lda0; W = W0; ldw = ldw0; kb = wg * half0 + (i << 6); }
        else         { A = A1; lda = H_DIM; W = W1; ldw = H_DIM; kb = wg * 512 + ((i - nt0) << 6); }
        gru_stage(A, lda, W, ldw, kb, As2[wg][buf], Ws2[wg][buf], bm, bn, gt);
    };

    stg(0, 0);
    for (int i = 0; i < nt; ++i) {
        const int cur = i & 1;
        if (i + 1 < nt) { stg(i + 1, cur ^ 1); vmwait<8>(); }
        else            { vmwait<0>(); }
        schedbar();
        sbar();                 // all waves: tile i complete in LDS
        schedbar();
        if (i < nt0)
            gru_compute(As2[wg][cur], Ws2[wg][cur], gwv, ln, quad, accR, accZ, accN0);
        else
            gru_compute(As2[wg][cur], Ws2[wg][cur], gwv, ln, quad, accR, accZ, accN1);
        schedbar();
        sbar();                 // all waves done computing tile i
    }

    // ---- cross-group reduction (stride 33 floats: conflict-free) ----
    float* red = (float*)Ws2;             // 48 KB scratch, needs ~17 KB
    const int rb = (gwv * 64 + lane) * 33;
    if (wg == 1) {
        #pragma unroll
        for (int i = 0; i < 2; i++)
            #pragma unroll
            for (int r = 0; r < 4; r++) {
                red[rb + i * 4 + r]      = accR[i][r];
                red[rb + 8 + i * 4 + r]  = accZ[i][r];
                red[rb + 16 + i * 4 + r] = accN0[i][r];
                red[rb + 24 + i * 4 + r] = accN1[i][r];
            }
    }
    __syncthreads();
    if (wg == 0) {
        #pragma unroll
        for (int i = 0; i < 2; i++)
            #pragma unroll
            for (int r = 0; r < 4; r++) {
                accR[i][r]  += red[rb + i * 4 + r];
                accZ[i][r]  += red[rb + 8 + i * 4 + r];
                accN0[i][r] += red[rb + 16 + i * 4 + r];
                accN1[i][r] += red[rb + 24 + i * 4 + r];
            }
        const int n = bn + gwv * 16 + ln;
        const float br = bih[n] + bhh[n];
        const float bz = bih[H_DIM + n] + bhh[H_DIM + n];
        const float bi_n = bih[2 * H_DIM + n];
        const float bh_n = bhh[2 * H_DIM + n];
        #pragma unroll
        for (int i = 0; i < 2; i++) {
            #pragma unroll
            for (int r = 0; r < 4; r++) {
                const int m = bm + i * 16 + quad * 4 + r;
                const size_t idx = (size_t)m * H_DIM + n;
                float rg = 1.f / (1.f + __expf(-(accR[i][r] + br)));
                float zg = 1.f / (1.f + __expf(-(accZ[i][r] + bz)));
                float av = accN0[i][r] + bi_n + rg * (accN1[i][r] + bh_n);
                float e2 = __expf(-2.f * fabsf(av));
                float th = (1.f - e2) / (1.f + e2);
                th = av < 0.f ? -th : th;
                float o = (1.f - zg) * th + zg * hf_in[idx];
                hf_out[idx] = o;
                unsigned short ob = f2b(o);
                hb_out[idx] = ob;
                if (slot) slot[idx] = ob;
            }
        }
    }
}

// ---------------------------------------------------------------------------
// Fused attention: one block per batch row (512 blocks).
// ---------------------------------------------------------------------------
__global__ __launch_bounds__(256) void attn_ctx(
    const unsigned short* __restrict__ hb,     // [512,1024] bf16
    const unsigned short* __restrict__ wAhT,   // [1024][64] bf16 (k-major)
    const unsigned short* __restrict__ attnx_t,// [512,64] bf16 (incl bias)
    const unsigned short* __restrict__ encb,   // [64,512,1024] bf16
    unsigned short* __restrict__ ctx)          // [512,1024] bf16
{
    __shared__ float hf[H_DIM];
    __shared__ float part[4][S_LEN];
    __shared__ float awl[S_LEN];
    const int b = blockIdx.x, t = threadIdx.x;
    {
        us4 u = *(const us4*)(hb + ((size_t)b << 10) + t * 4);
        #pragma unroll
        for (int j = 0; j < 4; j++) hf[t * 4 + j] = b2f(u[j]);
    }
    __syncthreads();
    {
        const int c = t & 63, ks = (t >> 6) * 256;
        float s = 0.f;
        #pragma unroll 8
        for (int k = 0; k < 256; k++)
            s += hf[ks + k] * b2f(wAhT[(size_t)(ks + k) * S_LEN + c]);
        part[t >> 6][c] = s;
    }
    __syncthreads();
    if (t < 64) {
        float v = part[0][t] + part[1][t] + part[2][t] + part[3][t]
                + b2f(attnx_t[b * S_LEN + t]);
        float m = v;
        #pragma unroll
        for (int off = 32; off; off >>= 1) m = fmaxf(m, __shfl_xor(m, off));
        float e = __expf(v - m);
        float ss = e;
        #pragma unroll
        for (int off = 32; off; off >>= 1) ss += __shfl_xor(ss, off);
        awl[t] = e / ss;
    }
    __syncthreads();
    const int hq = t * 4;
    float s0 = 0.f, s1 = 0.f, s2 = 0.f, s3 = 0.f;
    #pragma unroll 4
    for (int l = 0; l < S_LEN; l++) {
        us4 u = *(const us4*)(encb + (((size_t)l * BATCH + b) << 10) + hq);
        float w = awl[l];
        s0 += w * b2f(u[0]); s1 += w * b2f(u[1]);
        s2 += w * b2f(u[2]); s3 += w * b2f(u[3]);
    }
    us4 o; o[0] = f2b(s0); o[1] = f2b(s1); o[2] = f2b(s2); o[3] = f2b(s3);
    *(us4*)(ctx + ((size_t)b << 10) + hq) = o;
}

// ---------------------------------------------------------------------------
// One fused convert kernel: all fp32->bf16 weight/input preprocessing in a
// single grid-strided launch. Unit = 4 elems.
// ---------------------------------------------------------------------------
__global__ __launch_bounds__(256) void cvt_all(
    const float* __restrict__ enc_Whh, const float* __restrict__ dec_Wih,
    const float* __restrict__ dec_Whh, const float* __restrict__ comb_W,
    const float* __restrict__ out_W,   const float* __restrict__ attn_W,
    const float* __restrict__ enc_Wih, const float* __restrict__ input,
    const float* __restrict__ target,
    unsigned short* __restrict__ wWhh, unsigned short* __restrict__ wDih,
    unsigned short* __restrict__ wDhh, unsigned short* __restrict__ wCc,
    unsigned short* __restrict__ wCx,  unsigned short* __restrict__ wO,
    unsigned short* __restrict__ wAx,  unsigned short* __restrict__ wAhT,
    unsigned short* __restrict__ wIhp, unsigned short* __restrict__ xbp,
    unsigned short* __restrict__ targetb)
{
    const unsigned nW = H3 * H_DIM / 4;
    const unsigned nH = H_DIM * H_DIM / 4;
    const unsigned nA = S_LEN * H_DIM / 4;
    const unsigned nI = H3 * INP / 4;
    const unsigned nX = S_LEN * BATCH * INP / 4;
    const unsigned nT = T_LEN * BATCH * H_DIM / 4;
    const unsigned total = 3 * nW + 3 * nH + 2 * nA + nI + nX + nT;

    auto plain4 = [](const float* s, unsigned short* d, unsigned i) {
        f32x4 v = *(const f32x4*)(s + (size_t)i * 4);
        us4 o;
        #pragma unroll
        for (int j = 0; j < 4; j++) o[j] = f2b(v[j]);
        *(us4*)(d + (size_t)i * 4) = o;
    };
    auto strided4 = [](const float* s, int ld, int off, int c4s,
                       unsigned short* d, unsigned i) {
        int r = i / c4s, c4 = i - r * c4s;
        f32x4 v = *(const f32x4*)(s + (size_t)r * ld + off + c4 * 4);
        us4 o;
        #pragma unroll
        for (int j = 0; j < 4; j++) o[j] = f2b(v[j]);
        *(us4*)(d + (size_t)i * 4) = o;
    };
    auto pad4 = [](const float* s, unsigned short* d, unsigned i) {
        int r = i >> 5, c = (i & 31) * 4;
        us4 o;
        #pragma unroll
        for (int j = 0; j < 4; j++) {
            int cc = c + j;
            o[j] = (cc < IN_DIM) ? f2b(s[(size_t)r * IN_DIM + cc]) : (unsigned short)0;
        }
        *(us4*)(d + (size_t)r * INP + c) = o;
    };

    for (unsigned q = blockIdx.x * blockDim.x + threadIdx.x; q < total;
         q += gridDim.x * blockDim.x) {
        unsigned i = q;
        if (i < nW) { plain4(enc_Whh, wWhh, i); continue; }  i -= nW;
        if (i < nW) { plain4(dec_Wih, wDih, i); continue; }  i -= nW;
        if (i < nW) { plain4(dec_Whh, wDhh, i); continue; }  i -= nW;
        if (i < nH) { strided4(comb_W, 2 * H_DIM, H_DIM, H_DIM / 4, wCc, i); continue; }  i -= nH;
        if (i < nH) { strided4(comb_W, 2 * H_DIM, 0, H_DIM / 4, wCx, i); continue; }  i -= nH;
        if (i < nH) { plain4(out_W, wO, i); continue; }  i -= nH;
        if (i < nA) { strided4(attn_W, 2 * H_DIM, 0, H_DIM / 4, wAx, i); continue; }  i -= nA;
        if (i < nA) {
            int idx = i * 4, k = idx >> 6, c = idx & 63;
            us4 o;
            #pragma unroll
            for (int j = 0; j < 4; j++)
                o[j] = f2b(attn_W[(size_t)(c + j) * 2 * H_DIM + H_DIM + k]);
            *(us4*)(wAhT + idx) = o;
            continue;
        }  i -= nA;
        if (i < nI) { pad4(enc_Wih, wIhp, i); continue; }  i -= nI;
        if (i < nX) { pad4(input, xbp, i); continue; }  i -= nX;
        plain4(target, targetb, i);
    }
}

__global__ void log_softmax1024(float* __restrict__ x)
{
    __shared__ float red[256];
    float* xr = x + (size_t)blockIdx.x * O_DIM;
    int t = threadIdx.x;
    float m = -1e30f;
    for (int i = t; i < O_DIM; i += 256) m = fmaxf(m, xr[i]);
    red[t] = m; __syncthreads();
    for (int s2 = 128; s2 > 0; s2 >>= 1) {
        if (t < s2) red[t] = fmaxf(red[t], red[t + s2]);
        __syncthreads();
    }
    m = red[0];
    __syncthreads();
    float s = 0.f;
    for (int i = t; i < O_DIM; i += 256) s += expf(xr[i] - m);
    red[t] = s; __syncthreads();
    for (int s2 = 128; s2 > 0; s2 >>= 1) {
        if (t < s2) red[t] += red[t + s2];
        __syncthreads();
    }
    float lse = m + logf(red[0]);
    __syncthreads();
    for (int i = t; i < O_DIM; i += 256) xr[i] = xr[i] - lse;
}

// ---------------------------------------------------------------------------
extern "C" void kernel_launch(void* const* d_in, const int* in_sizes, int n_in,
                              void* d_out, int out_size, void* d_ws, size_t ws_size,
                              hipStream_t stream)
{
    const float* input   = (const float*)d_in[0];   // [S,B,IN]
    const float* target  = (const float*)d_in[1];   // [T,B,H]
    const float* enc_Wih = (const float*)d_in[2];
    const float* enc_Whh = (const float*)d_in[3];
    const float* enc_bih = (const float*)d_in[4];
    const float* enc_bhh = (const float*)d_in[5];
    const float* attn_W  = (const float*)d_in[6];   // [S,2H]
    const float* attn_b  = (const float*)d_in[7];
    const float* comb_W  = (const float*)d_in[8];   // [H,2H]
    const float* comb_b  = (const float*)d_in[9];
    const float* dec_Wih = (const float*)d_in[10];
    const float* dec_Whh = (const float*)d_in[11];
    const float* dec_bih = (const float*)d_in[12];
    const float* dec_bhh = (const float*)d_in[13];
    const float* out_W   = (const float*)d_in[14];
    const float* out_b   = (const float*)d_in[15];
    float* out = (float*)d_out;                     // [B,O] fp32

    // ---- workspace layout ----
    char* p = (char*)d_ws;
    auto alloc = [&](size_t bytes) {
        char* r = p; p += (bytes + 255) & ~(size_t)255; return r;
    };
    unsigned short* wWhh  = (unsigned short*)alloc((size_t)H3 * H_DIM * 2);
    unsigned short* wDih  = (unsigned short*)alloc((size_t)H3 * H_DIM * 2);
    unsigned short* wDhh  = (unsigned short*)alloc((size_t)H3 * H_DIM * 2);
    unsigned short* wCc   = (unsigned short*)alloc((size_t)H_DIM * H_DIM * 2);
    unsigned short* wCx   = (unsigned short*)alloc((size_t)H_DIM * H_DIM * 2);
    unsigned short* wO    = (unsigned short*)alloc((size_t)O_DIM * H_DIM * 2);
    unsigned short* wAhT  = (unsigned short*)alloc((size_t)H_DIM * S_LEN * 2);
    unsigned short* wAx   = (unsigned short*)alloc((size_t)S_LEN * H_DIM * 2);
    unsigned short* wIhp  = (unsigned short*)alloc((size_t)H3 * INP * 2);
    unsigned short* xbp   = (unsigned short*)alloc((size_t)S_LEN * BATCH * INP * 2);
    unsigned short* encb  = (unsigned short*)alloc((size_t)S_LEN * BATCH * H_DIM * 2);
    unsigned short* combx = (unsigned short*)alloc((size_t)(T_LEN - 1) * BATCH * H_DIM * 2);
    unsigned short* attnx = (unsigned short*)alloc((size_t)(T_LEN - 1) * BATCH * S_LEN * 2);
    float*          h     = (float*)alloc((size_t)BATCH * H_DIM * 4);
    unsigned short* hbA   = (unsigned short*)alloc((size_t)BATCH * H_DIM * 2);
    unsigned short* hbB   = (unsigned short*)alloc((size_t)BATCH * H_DIM * 2);
    unsigned short* ctx   = (unsigned short*)alloc((size_t)BATCH * H_DIM * 2);
    unsigned short* comb  = (unsigned short*)alloc((size_t)BATCH * H_DIM * 2);
    // targetb overlays encb: consumed (attnx/combx gemms) before encoder
    // writes encb. [32*512, 1024] bf16 = 33.5 MB inside encb's 64 MB.
    unsigned short* targetb = encb;

    const dim3 blk(256);

    hipMemsetAsync(h,   0, (size_t)BATCH * H_DIM * 4, stream);
    hipMemsetAsync(hbA, 0, (size_t)BATCH * H_DIM * 2, stream);

    // ---- one fused convert launch ----
    cvt_all<<<2048, blk, 0, stream>>>(
        enc_Whh, dec_Wih, dec_Whh, comb_W, out_W, attn_W, enc_Wih, input, target,
        wWhh, wDih, wDhh, wCc, wCx, wO, wAx, wAhT, wIhp, xbp, targetb);

    const int MT = (T_LEN - 1) * BATCH;  // 15872
    // attnx = target @ attn_W[:, :H]^T + attn_b
    gemm_k<64, 64><<<dim3(1, MT / 64), blk, 0, stream>>>(
        targetb, H_DIM, wAx, H_DIM, attn_b,
        nullptr, nullptr, 0, nullptr, attnx, S_LEN, H_DIM, 1 | 32);
    // combx = target @ comb_W[:, :H]^T + comb_b
    gemm_k<128, 128><<<dim3(H_DIM / 128, MT / 128), blk, 0, stream>>>(
        targetb, H_DIM, wCx, H_DIM, comb_b,
        nullptr, nullptr, 0, nullptr, combx, H_DIM, H_DIM, 1 | 32);

    const dim3 grid_gru(H_DIM / 32, BATCH / 32);   // 32 x 16 = 512 blocks
    unsigned short* hcur = hbA;
    unsigned short* hnxt = hbB;

    // ---------------- encoder: one kernel per step ----------------
    for (int s = 0; s < S_LEN; s++) {
        gru_gemm<<<grid_gru, blk, 0, stream>>>(
            xbp + (size_t)s * BATCH * INP, INP, wIhp, INP, INP,
            hcur, wWhh, enc_bih, enc_bhh, h, h, hnxt,
            encb + (size_t)s * BATCH * H_DIM);
        unsigned short* tmp = hcur; hcur = hnxt; hnxt = tmp;
    }

    // ---------------- decoder: three kernels per step ----------------
    for (int t = 0; t < T_LEN - 1; t++) {
        attn_ctx<<<BATCH, blk, 0, stream>>>(
            hcur, wAhT, attnx + (size_t)t * BATCH * S_LEN, encb, ctx);
        gemm_k<32, 64><<<dim3(H_DIM / 64, BATCH / 32), blk, 0, stream>>>(
            ctx, H_DIM, wCc, H_DIM, nullptr,
            nullptr, combx + (size_t)t * BATCH * H_DIM, H_DIM,
            nullptr, comb, H_DIM, H_DIM, 4 | 8 | 32);
        gru_gemm<<<grid_gru, blk, 0, stream>>>(
            comb, H_DIM, wDih, H_DIM, H_DIM,
            hcur, wDhh, dec_bih, dec_bhh, h, h, hnxt, nullptr);
        unsigned short* tmp = hcur; hcur = hnxt; hnxt = tmp;
    }

    // ---------------- output ----------------
    gemm_k<32, 64><<<dim3(O_DIM / 64, BATCH / 32), blk, 0, stream>>>(
        hcur, H_DIM, wO, H_DIM, out_b,
        nullptr, nullptr, 0, out, nullptr, O_DIM, H_DIM, 1 | 16);
    log_softmax1024<<<BATCH, blk, 0, stream>>>(out);
}

// Round 8
// 2651.302 us; speedup vs baseline: 3.4716x; 1.1305x over previous
//
#include <hip/hip_runtime.h>
#include <hip/hip_bf16.h>
#include <math.h>

#define S_LEN 64
#define T_LEN 32
#define BATCH 512
#define IN_DIM 66
#define INP 128         // IN_DIM zero-padded to multiple of 64
#define H_DIM 1024
#define O_DIM 1024
#define H3 3072

typedef __attribute__((ext_vector_type(8))) short short8;
typedef __attribute__((ext_vector_type(4))) float f32x4;
typedef __attribute__((ext_vector_type(4))) unsigned short us4;

__device__ __forceinline__ unsigned short f2b(float f) {
    union { float f; unsigned u; } x; x.f = f;
    unsigned r = x.u + 0x7FFF + ((x.u >> 16) & 1);
    return (unsigned short)(r >> 16);
}
__device__ __forceinline__ float b2f(unsigned short s) {
    union { unsigned u; float f; } x; x.u = ((unsigned)s) << 16;
    return x.f;
}
// async global->LDS, 16B per lane; lds base must be wave-uniform
__device__ __forceinline__ void gll16(const void* g, const void* l) {
    __builtin_amdgcn_global_load_lds(
        (const __attribute__((address_space(1))) unsigned int*)g,
        (__attribute__((address_space(3))) unsigned int*)l, 16, 0, 0);
}
template<int N>
__device__ __forceinline__ void vmwait() {
    if constexpr (N == 0) asm volatile("s_waitcnt vmcnt(0)" ::: "memory");
    else if constexpr (N == 2) asm volatile("s_waitcnt vmcnt(2)" ::: "memory");
    else if constexpr (N == 4) asm volatile("s_waitcnt vmcnt(4)" ::: "memory");
    else if constexpr (N == 8) asm volatile("s_waitcnt vmcnt(8)" ::: "memory");
}
__device__ __forceinline__ void sbar() { __builtin_amdgcn_s_barrier(); }
__device__ __forceinline__ void schedbar() { __builtin_amdgcn_sched_barrier(0); }

// ---------------------------------------------------------------------------
// MFMA GEMM, bf16: C[M,N] = A@W^T, tile TM x TN. lda/ldw mult of 8, K mult 32.
// flags: 1 bias, 2 add fp32, 4 add bf16, 8 relu, 16 store f32, 32 store bf16
// ---------------------------------------------------------------------------
template<int TM, int TN>
__global__ __launch_bounds__(256) void gemm_k(
    const unsigned short* __restrict__ A, int lda,
    const unsigned short* __restrict__ W, int ldw,
    const float* __restrict__ bias,
    const float* __restrict__ addf, const unsigned short* __restrict__ addb,
    int ldadd,
    float* __restrict__ Cf,
    unsigned short* __restrict__ Cb, int ldc,
    int K, int flags)
{
    constexpr int IF = TM / 16;   // A frags per wave
    constexpr int JF = TN / 64;   // B frags per wave
    constexpr int NW = TN / 4;    // cols per wave
    constexpr int CA = TM * 4;    // 16B chunks in A tile
    constexpr int CW = TN * 4;
    constexpr bool PIPE = (CA >= 256) && (CW >= 256);  // uniform loads/thread
    constexpr int PT = (CA + CW) / 256;                // loads per thread per tile
    __shared__ __align__(16) unsigned short As[2][TM * 32];
    __shared__ __align__(16) unsigned short Bs[2][TN * 32];

    const int bm = blockIdx.y * TM;
    const int bn = blockIdx.x * TN;
    const int t = threadIdx.x;
    const int lane = t & 63;
    const int wv = t >> 6;
    const int ln = lane & 15;
    const int quad = lane >> 4;

    f32x4 acc[IF][JF];
    #pragma unroll
    for (int i = 0; i < IF; i++)
        #pragma unroll
        for (int j = 0; j < JF; j++) {
            f32x4 z = {0.f, 0.f, 0.f, 0.f};
            acc[i][j] = z;
        }

    auto stage = [&](int buf, int k0) {
        if constexpr (CA >= 256) {
            #pragma unroll
            for (int j = 0; j < CA / 256; j++) {
                int ch = j * 256 + t;
                gll16(A + (size_t)(bm + (ch >> 2)) * lda + k0 + (ch & 3) * 8,
                      (const char*)As[buf] + (j * 4 + wv) * 1024);
            }
        } else {
            if (t < CA)
                gll16(A + (size_t)(bm + (t >> 2)) * lda + k0 + (t & 3) * 8,
                      (const char*)As[buf] + wv * 1024);
        }
        if constexpr (CW >= 256) {
            #pragma unroll
            for (int j = 0; j < CW / 256; j++) {
                int ch = j * 256 + t;
                gll16(W + (size_t)(bn + (ch >> 2)) * ldw + k0 + (ch & 3) * 8,
                      (const char*)Bs[buf] + (j * 4 + wv) * 1024);
            }
        } else {
            if (t < CW)
                gll16(W + (size_t)(bn + (t >> 2)) * ldw + k0 + (t & 3) * 8,
                      (const char*)Bs[buf] + wv * 1024);
        }
    };

    auto comp = [&](int cur) {
        short8 af[IF], bf[JF];
        #pragma unroll
        for (int ii = 0; ii < IF; ii++)
            af[ii] = *(const short8*)&As[cur][(ii * 16 + ln) * 32 + quad * 8];
        #pragma unroll
        for (int j = 0; j < JF; j++)
            bf[j] = *(const short8*)&Bs[cur][(wv * NW + j * 16 + ln) * 32 + quad * 8];
        #pragma unroll
        for (int ii = 0; ii < IF; ii++)
            #pragma unroll
            for (int j = 0; j < JF; j++)
                acc[ii][j] = __builtin_amdgcn_mfma_f32_16x16x32_bf16(
                    af[ii], bf[j], acc[ii][j], 0, 0, 0);
    };

    const int nt = K >> 5;
    if constexpr (PIPE) {
        stage(0, 0);
        for (int i = 0; i < nt; ++i) {
            const int cur = i & 1;
            if (i + 1 < nt) { stage(cur ^ 1, (i + 1) << 5); vmwait<PT>(); }
            else            { vmwait<0>(); }
            schedbar();
            sbar();
            schedbar();
            comp(cur);
            schedbar();
            sbar();
        }
    } else {
        stage(0, 0);
        __syncthreads();
        for (int i = 0; i < nt; ++i) {
            const int cur = i & 1;
            if (i + 1 < nt) stage(cur ^ 1, (i + 1) << 5);
            comp(cur);
            __syncthreads();
        }
    }

    #pragma unroll
    for (int i = 0; i < IF; i++) {
        #pragma unroll
        for (int j = 0; j < JF; j++) {
            #pragma unroll
            for (int r = 0; r < 4; r++) {
                int m = bm + i * 16 + quad * 4 + r;
                int n = bn + wv * NW + j * 16 + ln;
                float v = acc[i][j][r];
                if (flags & 1) v += bias[n];
                if (flags & 2) v += addf[(size_t)m * ldadd + n];
                if (flags & 4) v += b2f(addb[(size_t)m * ldadd + n]);
                if (flags & 8) v = fmaxf(v, 0.f);
                if (flags & 16) Cf[(size_t)m * ldc + n] = v;
                if (flags & 32) Cb[(size_t)m * ldc + n] = f2b(v);
            }
        }
    }
}

// ---------------------------------------------------------------------------
// GRU tile stage/compute (32x32 tile, 256 threads, 2-group K-split).
// ---------------------------------------------------------------------------
__device__ __forceinline__ void gru_stage(
    const unsigned short* __restrict__ A, int lda,
    const unsigned short* __restrict__ W, int ldw, int kb,
    unsigned short* As_g, unsigned short* Ws_g,
    int bm, int bn, int gt)
{
    const int gwv = gt >> 6;
    #pragma unroll
    for (int j = 0; j < 2; j++) {
        int ch = j * 128 + gt;
        int s = ch >> 7, r = (ch >> 2) & 31, c = ch & 3;
        gll16(A + (size_t)(bm + r) * lda + kb + s * 32 + c * 8,
              (const char*)As_g + j * 2048 + gwv * 1024);
    }
    #pragma unroll
    for (int j = 0; j < 6; j++) {
        int ch = j * 128 + gt;
        int g = ch >> 8, ch2 = ch & 255;
        int s = ch2 >> 7, w = (ch2 >> 2) & 31, c = ch2 & 3;
        gll16(W + (size_t)(g * H_DIM + bn + w) * ldw + kb + s * 32 + c * 8,
              (const char*)Ws_g + j * 2048 + gwv * 1024);
    }
}

__device__ __forceinline__ void gru_compute(
    const unsigned short* As_g, const unsigned short* Ws_g,
    int gwv, int ln, int quad,
    f32x4 (&accR)[2], f32x4 (&accZ)[2], f32x4 (&accN)[2])
{
    #pragma unroll
    for (int sub = 0; sub < 2; sub++) {
        short8 a[2], bw[3];
        #pragma unroll
        for (int i = 0; i < 2; i++)
            a[i] = *(const short8*)&As_g[sub * 1024 + (i * 16 + ln) * 32 + quad * 8];
        #pragma unroll
        for (int g = 0; g < 3; g++)
            bw[g] = *(const short8*)&Ws_g[g * 2048 + sub * 1024 + (gwv * 16 + ln) * 32 + quad * 8];
        #pragma unroll
        for (int i = 0; i < 2; i++) {
            accR[i] = __builtin_amdgcn_mfma_f32_16x16x32_bf16(a[i], bw[0], accR[i], 0, 0, 0);
            accZ[i] = __builtin_amdgcn_mfma_f32_16x16x32_bf16(a[i], bw[1], accZ[i], 0, 0, 0);
            accN[i] = __builtin_amdgcn_mfma_f32_16x16x32_bf16(a[i], bw[2], accN[i], 0, 0, 0);
        }
    }
}

// ---------------------------------------------------------------------------
// Fused GRU step, 256 threads, tile 32x32, 64 KB LDS -> 2 blocks/CU.
// Counted-vmcnt pipeline. Grid (32,16) = 512 blocks.
// ---------------------------------------------------------------------------
__global__ __launch_bounds__(256) void gru_gemm(
    const unsigned short* __restrict__ A0, int lda0,
    const unsigned short* __restrict__ W0, int ldw0, int K0,
    const unsigned short* __restrict__ A1,   // hb_in [512,1024]
    const unsigned short* __restrict__ W1,   // Whh   [3072,1024]
    const float* __restrict__ bih, const float* __restrict__ bhh,
    const float* __restrict__ hf_in, float* __restrict__ hf_out,
    unsigned short* __restrict__ hb_out, unsigned short* __restrict__ slot)
{
    __shared__ __align__(16) unsigned short As2[2][2][2048];   // 16 KB
    __shared__ __align__(16) unsigned short Ws2[2][2][6144];   // 48 KB
    const int bn = blockIdx.x * 32;
    const int bm = blockIdx.y * 32;
    const int t = threadIdx.x;            // 0..255
    const int wg = t >> 7;                // K-split group
    const int gt = t & 127;               // thread in group
    const int lane = t & 63;
    const int gwv = gt >> 6;              // wave within group (0,1)
    const int ln = lane & 15;
    const int quad = lane >> 4;

    f32x4 accR[2], accZ[2], accN0[2], accN1[2];
    #pragma unroll
    for (int i = 0; i < 2; i++) {
        f32x4 z = {0.f, 0.f, 0.f, 0.f};
        accR[i] = z; accZ[i] = z; accN0[i] = z; accN1[i] = z;
    }

    const int half0 = K0 >> 1;            // multiple of 64
    const int nt0 = half0 >> 6;           // phase-0 tiles per group
    const int nt = nt0 + 8;               // + phase-1 tiles (512/64)

    auto stg = [&](int i, int buf) {
        const unsigned short* A; int lda; const unsigned short* W; int ldw; int kb;
        if (i < nt0) { A = A0; lda = lda0; W = W0; ldw = ldw0; kb = wg * half0 + (i << 6); }
        else         { A = A1; lda = H_DIM; W = W1; ldw = H_DIM; kb = wg * 512 + ((i - nt0) << 6); }
        gru_stage(A, lda, W, ldw, kb, As2[wg][buf], Ws2[wg][buf], bm, bn, gt);
    };

    stg(0, 0);
    for (int i = 0; i < nt; ++i) {
        const int cur = i & 1;
        if (i + 1 < nt) { stg(i + 1, cur ^ 1); vmwait<8>(); }
        else            { vmwait<0>(); }
        schedbar();
        sbar();
        schedbar();
        if (i < nt0)
            gru_compute(As2[wg][cur], Ws2[wg][cur], gwv, ln, quad, accR, accZ, accN0);
        else
            gru_compute(As2[wg][cur], Ws2[wg][cur], gwv, ln, quad, accR, accZ, accN1);
        schedbar();
        sbar();
    }

    // ---- cross-group reduction (stride 33 floats: conflict-free) ----
    float* red = (float*)Ws2;
    const int rb = (gwv * 64 + lane) * 33;
    if (wg == 1) {
        #pragma unroll
        for (int i = 0; i < 2; i++)
            #pragma unroll
            for (int r = 0; r < 4; r++) {
                red[rb + i * 4 + r]      = accR[i][r];
                red[rb + 8 + i * 4 + r]  = accZ[i][r];
                red[rb + 16 + i * 4 + r] = accN0[i][r];
                red[rb + 24 + i * 4 + r] = accN1[i][r];
            }
    }
    __syncthreads();
    if (wg == 0) {
        #pragma unroll
        for (int i = 0; i < 2; i++)
            #pragma unroll
            for (int r = 0; r < 4; r++) {
                accR[i][r]  += red[rb + i * 4 + r];
                accZ[i][r]  += red[rb + 8 + i * 4 + r];
                accN0[i][r] += red[rb + 16 + i * 4 + r];
                accN1[i][r] += red[rb + 24 + i * 4 + r];
            }
        const int n = bn + gwv * 16 + ln;
        const float br = bih[n] + bhh[n];
        const float bz = bih[H_DIM + n] + bhh[H_DIM + n];
        const float bi_n = bih[2 * H_DIM + n];
        const float bh_n = bhh[2 * H_DIM + n];
        #pragma unroll
        for (int i = 0; i < 2; i++) {
            #pragma unroll
            for (int r = 0; r < 4; r++) {
                const int m = bm + i * 16 + quad * 4 + r;
                const size_t idx = (size_t)m * H_DIM + n;
                float rg = 1.f / (1.f + __expf(-(accR[i][r] + br)));
                float zg = 1.f / (1.f + __expf(-(accZ[i][r] + bz)));
                float av = accN0[i][r] + bi_n + rg * (accN1[i][r] + bh_n);
                float e2 = __expf(-2.f * fabsf(av));
                float th = (1.f - e2) / (1.f + e2);
                th = av < 0.f ? -th : th;
                float o = (1.f - zg) * th + zg * hf_in[idx];
                hf_out[idx] = o;
                unsigned short ob = f2b(o);
                hb_out[idx] = ob;
                if (slot) slot[idx] = ob;
            }
        }
    }
}

// ---------------------------------------------------------------------------
// Fused attention + comb (decoder step, 2 kernels/step path):
// scores = h@wAhT + attnx -> softmax -> comb = relu(sum_l aw[l]*encWc[l,b,:]
// + combx[td,b,:]). Uses precomputed encWc[l] = encb[l]@Wcc^T (linearity of
// the comb GEMM in ctx). One block per batch row (512 blocks).
// ---------------------------------------------------------------------------
__global__ __launch_bounds__(256) void attn_comb(
    const unsigned short* __restrict__ hb,     // [512,1024] bf16
    const unsigned short* __restrict__ wAhT,   // [1024][64] bf16 (k-major)
    const unsigned short* __restrict__ attnx_t,// [512,64] bf16 (incl bias)
    const unsigned short* __restrict__ encWc,  // [64,512,1024] bf16
    const unsigned short* __restrict__ combx_t,// [512,1024] bf16 (incl bias)
    unsigned short* __restrict__ comb)         // [512,1024] bf16
{
    __shared__ float hf[H_DIM];
    __shared__ float part[4][S_LEN];
    __shared__ float awl[S_LEN];
    const int b = blockIdx.x, t = threadIdx.x;
    {
        us4 u = *(const us4*)(hb + ((size_t)b << 10) + t * 4);
        #pragma unroll
        for (int j = 0; j < 4; j++) hf[t * 4 + j] = b2f(u[j]);
    }
    __syncthreads();
    {
        const int c = t & 63, ks = (t >> 6) * 256;
        float s = 0.f;
        #pragma unroll 8
        for (int k = 0; k < 256; k++)
            s += hf[ks + k] * b2f(wAhT[(size_t)(ks + k) * S_LEN + c]);
        part[t >> 6][c] = s;
    }
    __syncthreads();
    if (t < 64) {
        float v = part[0][t] + part[1][t] + part[2][t] + part[3][t]
                + b2f(attnx_t[b * S_LEN + t]);
        float m = v;
        #pragma unroll
        for (int off = 32; off; off >>= 1) m = fmaxf(m, __shfl_xor(m, off));
        float e = __expf(v - m);
        float ss = e;
        #pragma unroll
        for (int off = 32; off; off >>= 1) ss += __shfl_xor(ss, off);
        awl[t] = e / ss;
    }
    __syncthreads();
    const int hq = t * 4;
    float s0 = 0.f, s1 = 0.f, s2 = 0.f, s3 = 0.f;
    #pragma unroll 4
    for (int l = 0; l < S_LEN; l++) {
        us4 u = *(const us4*)(encWc + (((size_t)l * BATCH + b) << 10) + hq);
        float w = awl[l];
        s0 += w * b2f(u[0]); s1 += w * b2f(u[1]);
        s2 += w * b2f(u[2]); s3 += w * b2f(u[3]);
    }
    us4 cx = *(const us4*)(combx_t + ((size_t)b << 10) + hq);
    s0 = fmaxf(s0 + b2f(cx[0]), 0.f);
    s1 = fmaxf(s1 + b2f(cx[1]), 0.f);
    s2 = fmaxf(s2 + b2f(cx[2]), 0.f);
    s3 = fmaxf(s3 + b2f(cx[3]), 0.f);
    us4 o; o[0] = f2b(s0); o[1] = f2b(s1); o[2] = f2b(s2); o[3] = f2b(s3);
    *(us4*)(comb + ((size_t)b << 10) + hq) = o;
}

// Fallback: plain attention -> ctx (3-kernel decoder path, if ws too small)
__global__ __launch_bounds__(256) void attn_ctx(
    const unsigned short* __restrict__ hb,
    const unsigned short* __restrict__ wAhT,
    const unsigned short* __restrict__ attnx_t,
    const unsigned short* __restrict__ encb,
    unsigned short* __restrict__ ctx)
{
    __shared__ float hf[H_DIM];
    __shared__ float part[4][S_LEN];
    __shared__ float awl[S_LEN];
    const int b = blockIdx.x, t = threadIdx.x;
    {
        us4 u = *(const us4*)(hb + ((size_t)b << 10) + t * 4);
        #pragma unroll
        for (int j = 0; j < 4; j++) hf[t * 4 + j] = b2f(u[j]);
    }
    __syncthreads();
    {
        const int c = t & 63, ks = (t >> 6) * 256;
        float s = 0.f;
        #pragma unroll 8
        for (int k = 0; k < 256; k++)
            s += hf[ks + k] * b2f(wAhT[(size_t)(ks + k) * S_LEN + c]);
        part[t >> 6][c] = s;
    }
    __syncthreads();
    if (t < 64) {
        float v = part[0][t] + part[1][t] + part[2][t] + part[3][t]
                + b2f(attnx_t[b * S_LEN + t]);
        float m = v;
        #pragma unroll
        for (int off = 32; off; off >>= 1) m = fmaxf(m, __shfl_xor(m, off));
        float e = __expf(v - m);
        float ss = e;
        #pragma unroll
        for (int off = 32; off; off >>= 1) ss += __shfl_xor(ss, off);
        awl[t] = e / ss;
    }
    __syncthreads();
    const int hq = t * 4;
    float s0 = 0.f, s1 = 0.f, s2 = 0.f, s3 = 0.f;
    #pragma unroll 4
    for (int l = 0; l < S_LEN; l++) {
        us4 u = *(const us4*)(encb + (((size_t)l * BATCH + b) << 10) + hq);
        float w = awl[l];
        s0 += w * b2f(u[0]); s1 += w * b2f(u[1]);
        s2 += w * b2f(u[2]); s3 += w * b2f(u[3]);
    }
    us4 o; o[0] = f2b(s0); o[1] = f2b(s1); o[2] = f2b(s2); o[3] = f2b(s3);
    *(us4*)(ctx + ((size_t)b << 10) + hq) = o;
}

// ---------------------------------------------------------------------------
// One fused convert kernel: all fp32->bf16 preprocessing, grid-strided.
// ---------------------------------------------------------------------------
__global__ __launch_bounds__(256) void cvt_all(
    const float* __restrict__ enc_Whh, const float* __restrict__ dec_Wih,
    const float* __restrict__ dec_Whh, const float* __restrict__ comb_W,
    const float* __restrict__ out_W,   const float* __restrict__ attn_W,
    const float* __restrict__ enc_Wih, const float* __restrict__ input,
    const float* __restrict__ target,
    unsigned short* __restrict__ wWhh, unsigned short* __restrict__ wDih,
    unsigned short* __restrict__ wDhh, unsigned short* __restrict__ wCc,
    unsigned short* __restrict__ wCx,  unsigned short* __restrict__ wO,
    unsigned short* __restrict__ wAx,  unsigned short* __restrict__ wAhT,
    unsigned short* __restrict__ wIhp, unsigned short* __restrict__ xbp,
    unsigned short* __restrict__ targetb)
{
    const unsigned nW = H3 * H_DIM / 4;
    const unsigned nH = H_DIM * H_DIM / 4;
    const unsigned nA = S_LEN * H_DIM / 4;
    const unsigned nI = H3 * INP / 4;
    const unsigned nX = S_LEN * BATCH * INP / 4;
    const unsigned nT = T_LEN * BATCH * H_DIM / 4;
    const unsigned total = 3 * nW + 3 * nH + 2 * nA + nI + nX + nT;

    auto plain4 = [](const float* s, unsigned short* d, unsigned i) {
        f32x4 v = *(const f32x4*)(s + (size_t)i * 4);
        us4 o;
        #pragma unroll
        for (int j = 0; j < 4; j++) o[j] = f2b(v[j]);
        *(us4*)(d + (size_t)i * 4) = o;
    };
    auto strided4 = [](const float* s, int ld, int off, int c4s,
                       unsigned short* d, unsigned i) {
        int r = i / c4s, c4 = i - r * c4s;
        f32x4 v = *(const f32x4*)(s + (size_t)r * ld + off + c4 * 4);
        us4 o;
        #pragma unroll
        for (int j = 0; j < 4; j++) o[j] = f2b(v[j]);
        *(us4*)(d + (size_t)i * 4) = o;
    };
    auto pad4 = [](const float* s, unsigned short* d, unsigned i) {
        int r = i >> 5, c = (i & 31) * 4;
        us4 o;
        #pragma unroll
        for (int j = 0; j < 4; j++) {
            int cc = c + j;
            o[j] = (cc < IN_DIM) ? f2b(s[(size_t)r * IN_DIM + cc]) : (unsigned short)0;
        }
        *(us4*)(d + (size_t)r * INP + c) = o;
    };

    for (unsigned q = blockIdx.x * blockDim.x + threadIdx.x; q < total;
         q += gridDim.x * blockDim.x) {
        unsigned i = q;
        if (i < nW) { plain4(enc_Whh, wWhh, i); continue; }  i -= nW;
        if (i < nW) { plain4(dec_Wih, wDih, i); continue; }  i -= nW;
        if (i < nW) { plain4(dec_Whh, wDhh, i); continue; }  i -= nW;
        if (i < nH) { strided4(comb_W, 2 * H_DIM, H_DIM, H_DIM / 4, wCc, i); continue; }  i -= nH;
        if (i < nH) { strided4(comb_W, 2 * H_DIM, 0, H_DIM / 4, wCx, i); continue; }  i -= nH;
        if (i < nH) { plain4(out_W, wO, i); continue; }  i -= nH;
        if (i < nA) { strided4(attn_W, 2 * H_DIM, 0, H_DIM / 4, wAx, i); continue; }  i -= nA;
        if (i < nA) {
            int idx = i * 4, k = idx >> 6, c = idx & 63;
            us4 o;
            #pragma unroll
            for (int j = 0; j < 4; j++)
                o[j] = f2b(attn_W[(size_t)(c + j) * 2 * H_DIM + H_DIM + k]);
            *(us4*)(wAhT + idx) = o;
            continue;
        }  i -= nA;
        if (i < nI) { pad4(enc_Wih, wIhp, i); continue; }  i -= nI;
        if (i < nX) { pad4(input, xbp, i); continue; }  i -= nX;
        plain4(target, targetb, i);
    }
}

__global__ void log_softmax1024(float* __restrict__ x)
{
    __shared__ float red[256];
    float* xr = x + (size_t)blockIdx.x * O_DIM;
    int t = threadIdx.x;
    float m = -1e30f;
    for (int i = t; i < O_DIM; i += 256) m = fmaxf(m, xr[i]);
    red[t] = m; __syncthreads();
    for (int s2 = 128; s2 > 0; s2 >>= 1) {
        if (t < s2) red[t] = fmaxf(red[t], red[t + s2]);
        __syncthreads();
    }
    m = red[0];
    __syncthreads();
    float s = 0.f;
    for (int i = t; i < O_DIM; i += 256) s += expf(xr[i] - m);
    red[t] = s; __syncthreads();
    for (int s2 = 128; s2 > 0; s2 >>= 1) {
        if (t < s2) red[t] += red[t + s2];
        __syncthreads();
    }
    float lse = m + logf(red[0]);
    __syncthreads();
    for (int i = t; i < O_DIM; i += 256) xr[i] = xr[i] - lse;
}

// ---------------------------------------------------------------------------
extern "C" void kernel_launch(void* const* d_in, const int* in_sizes, int n_in,
                              void* d_out, int out_size, void* d_ws, size_t ws_size,
                              hipStream_t stream)
{
    const float* input   = (const float*)d_in[0];   // [S,B,IN]
    const float* target  = (const float*)d_in[1];   // [T,B,H]
    const float* enc_Wih = (const float*)d_in[2];
    const float* enc_Whh = (const float*)d_in[3];
    const float* enc_bih = (const float*)d_in[4];
    const float* enc_bhh = (const float*)d_in[5];
    const float* attn_W  = (const float*)d_in[6];   // [S,2H]
    const float* attn_b  = (const float*)d_in[7];
    const float* comb_W  = (const float*)d_in[8];   // [H,2H]
    const float* comb_b  = (const float*)d_in[9];
    const float* dec_Wih = (const float*)d_in[10];
    const float* dec_Whh = (const float*)d_in[11];
    const float* dec_bih = (const float*)d_in[12];
    const float* dec_bhh = (const float*)d_in[13];
    const float* out_W   = (const float*)d_in[14];
    const float* out_b   = (const float*)d_in[15];
    float* out = (float*)d_out;                     // [B,O] fp32

    // ---- workspace layout ----
    char* p = (char*)d_ws;
    auto alloc = [&](size_t bytes) {
        char* r = p; p += (bytes + 255) & ~(size_t)255; return r;
    };
    unsigned short* wWhh  = (unsigned short*)alloc((size_t)H3 * H_DIM * 2);
    unsigned short* wDih  = (unsigned short*)alloc((size_t)H3 * H_DIM * 2);
    unsigned short* wDhh  = (unsigned short*)alloc((size_t)H3 * H_DIM * 2);
    unsigned short* wCc   = (unsigned short*)alloc((size_t)H_DIM * H_DIM * 2);
    unsigned short* wCx   = (unsigned short*)alloc((size_t)H_DIM * H_DIM * 2);
    unsigned short* wO    = (unsigned short*)alloc((size_t)O_DIM * H_DIM * 2);
    unsigned short* wAhT  = (unsigned short*)alloc((size_t)H_DIM * S_LEN * 2);
    unsigned short* wAx   = (unsigned short*)alloc((size_t)S_LEN * H_DIM * 2);
    unsigned short* wIhp  = (unsigned short*)alloc((size_t)H3 * INP * 2);
    unsigned short* xbp   = (unsigned short*)alloc((size_t)S_LEN * BATCH * INP * 2);
    unsigned short* encb  = (unsigned short*)alloc((size_t)S_LEN * BATCH * H_DIM * 2);
    unsigned short* combx = (unsigned short*)alloc((size_t)(T_LEN - 1) * BATCH * H_DIM * 2);
    unsigned short* attnx = (unsigned short*)alloc((size_t)(T_LEN - 1) * BATCH * S_LEN * 2);
    float*          h     = (float*)alloc((size_t)BATCH * H_DIM * 4);
    unsigned short* hbA   = (unsigned short*)alloc((size_t)BATCH * H_DIM * 2);
    unsigned short* hbB   = (unsigned short*)alloc((size_t)BATCH * H_DIM * 2);
    unsigned short* ctx   = (unsigned short*)alloc((size_t)BATCH * H_DIM * 2);
    unsigned short* comb  = (unsigned short*)alloc((size_t)BATCH * H_DIM * 2);
    unsigned short* encWc = (unsigned short*)alloc((size_t)S_LEN * BATCH * H_DIM * 2);
    const bool fuse = ((size_t)(p - (char*)d_ws) <= ws_size);
    // targetb overlays encb: consumed (attnx/combx gemms) before encoder
    // writes encb.
    unsigned short* targetb = encb;

    const dim3 blk(256);

    hipMemsetAsync(h,   0, (size_t)BATCH * H_DIM * 4, stream);
    hipMemsetAsync(hbA, 0, (size_t)BATCH * H_DIM * 2, stream);

    // ---- one fused convert launch ----
    cvt_all<<<2048, blk, 0, stream>>>(
        enc_Whh, dec_Wih, dec_Whh, comb_W, out_W, attn_W, enc_Wih, input, target,
        wWhh, wDih, wDhh, wCc, wCx, wO, wAx, wAhT, wIhp, xbp, targetb);

    const int MT = (T_LEN - 1) * BATCH;  // 15872
    // attnx = target @ attn_W[:, :H]^T + attn_b
    gemm_k<64, 64><<<dim3(1, MT / 64), blk, 0, stream>>>(
        targetb, H_DIM, wAx, H_DIM, attn_b,
        nullptr, nullptr, 0, nullptr, attnx, S_LEN, H_DIM, 1 | 32);
    // combx = target @ comb_W[:, :H]^T + comb_b
    gemm_k<128, 128><<<dim3(H_DIM / 128, MT / 128), blk, 0, stream>>>(
        targetb, H_DIM, wCx, H_DIM, comb_b,
        nullptr, nullptr, 0, nullptr, combx, H_DIM, H_DIM, 1 | 32);

    const dim3 grid_gru(H_DIM / 32, BATCH / 32);   // 32 x 16 = 512 blocks
    unsigned short* hcur = hbA;
    unsigned short* hnxt = hbB;

    // ---------------- encoder: one kernel per step ----------------
    for (int s = 0; s < S_LEN; s++) {
        gru_gemm<<<grid_gru, blk, 0, stream>>>(
            xbp + (size_t)s * BATCH * INP, INP, wIhp, INP, INP,
            hcur, wWhh, enc_bih, enc_bhh, h, h, hnxt,
            encb + (size_t)s * BATCH * H_DIM);
        unsigned short* tmp = hcur; hcur = hnxt; hnxt = tmp;
    }

    if (fuse) {
        // encWc[l] = encb[l] @ wCc^T  (one parallel GEMM, M = 64*512)
        gemm_k<128, 128><<<dim3(H_DIM / 128, S_LEN * BATCH / 128), blk, 0, stream>>>(
            encb, H_DIM, wCc, H_DIM, nullptr,
            nullptr, nullptr, 0, nullptr, encWc, H_DIM, H_DIM, 32);
        // ---------------- decoder: TWO kernels per step ----------------
        for (int t = 0; t < T_LEN - 1; t++) {
            attn_comb<<<BATCH, blk, 0, stream>>>(
                hcur, wAhT, attnx + (size_t)t * BATCH * S_LEN, encWc,
                combx + (size_t)t * BATCH * H_DIM, comb);
            gru_gemm<<<grid_gru, blk, 0, stream>>>(
                comb, H_DIM, wDih, H_DIM, H_DIM,
                hcur, wDhh, dec_bih, dec_bhh, h, h, hnxt, nullptr);
            unsigned short* tmp = hcur; hcur = hnxt; hnxt = tmp;
        }
    } else {
        // fallback: 3 kernels per step (no encWc buffer)
        for (int t = 0; t < T_LEN - 1; t++) {
            attn_ctx<<<BATCH, blk, 0, stream>>>(
                hcur, wAhT, attnx + (size_t)t * BATCH * S_LEN, encb, ctx);
            gemm_k<32, 64><<<dim3(H_DIM / 64, BATCH / 32), blk, 0, stream>>>(
                ctx, H_DIM, wCc, H_DIM, nullptr,
                nullptr, combx + (size_t)t * BATCH * H_DIM, H_DIM,
                nullptr, comb, H_DIM, H_DIM, 4 | 8 | 32);
            gru_gemm<<<grid_gru, blk, 0, stream>>>(
                comb, H_DIM, wDih, H_DIM, H_DIM,
                hcur, wDhh, dec_bih, dec_bhh, h, h, hnxt, nullptr);
            unsigned short* tmp = hcur; hcur = hnxt; hnxt = tmp;
        }
    }

    // ---------------- output ----------------
    gemm_k<32, 64><<<dim3(O_DIM / 64, BATCH / 32), blk, 0, stream>>>(
        hcur, H_DIM, wO, H_DIM, out_b,
        nullptr, nullptr, 0, out, nullptr, O_DIM, H_DIM, 1 | 16);
    log_softmax1024<<<BATCH, blk, 0, stream>>>(out);
}